// Round 3
// baseline (734.589 us; speedup 1.0000x reference)
//
#include <hip/hip_runtime.h>
#include <math.h>

#define C_   128
#define HU_  128
#define WU_  192
#define HD_  64
#define WD_  96
#define HWD_ (HD_ * WD_)

typedef unsigned short u16;
typedef __attribute__((ext_vector_type(8))) short s8v;   // 8 bf16 = 4 VGPRs
typedef __attribute__((ext_vector_type(4))) float f4v;   // MFMA C/D

// ---- workspace layout (u16 units) ----
#define OFF_Q   0        // 2 layers x 16384
#define OFF_K   32768
#define OFF_V   65536
#define OFF_O   98304
#define OFF_F1  131072   // 2 layers x 65536
#define OFF_F2  262144
#define OFF_XC  393216   // 49152 (out1 Wa+Wc, 128x384)
#define OFF_CC  442368   // 49152 (out1 Wb-Wc, 128x384)
#define OFF_NRM 491520   // normalized ctx bf16: (B,HD,WD,C) = 1572864 u16

#define SLOT 2176        // u16 per LDS tile slot (16 rows x 136)

__device__ __forceinline__ u16 f2bf(float f) {
    unsigned u = __float_as_uint(f);
    unsigned r = (u + 0x7FFFu + ((u >> 16) & 1u)) >> 16;   // RNE
    return (u16)r;
}
__device__ __forceinline__ float bfu(u16 h) { return __uint_as_float(((unsigned)h) << 16); }

__device__ __forceinline__ float gelu_tanh(float x) {
    float u = 1.5957691216057308f * (x + 0.044715f * x * x * x);
    float e = __expf(u);
    float th = 1.0f - 2.0f / (1.0f + e);
    return 0.5f * x * (1.0f + th);
}
__device__ __forceinline__ float fast_erf(float x) {
    float z = fabsf(x);
    float t = 1.0f / (1.0f + 0.3275911f * z);
    float p = t * (0.254829592f + t * (-0.284496736f + t * (1.421413741f +
              t * (-1.453152027f + t * 1.061405429f))));
    float r = 1.0f - p * __expf(-z * z);
    return copysignf(r, x);
}
__device__ __forceinline__ float gelu_erf(float x) {
    return 0.5f * x * (1.0f + fast_erf(x * 0.7071067811865476f));
}

// ---------------- prologue 1: all weight swizzles (+ out1 folding) ----------------
__global__ __launch_bounds__(256) void swz_all(
    const float* __restrict__ q_w, const float* __restrict__ k_w,
    const float* __restrict__ v_w, const float* __restrict__ o_w,
    const float* __restrict__ f1w, const float* __restrict__ f2w,
    const float* __restrict__ o1w, u16* __restrict__ ws)
{
    int tid = blockIdx.x * 256 + threadIdx.x;
    int f = tid >> 6, lane = tid & 63;
    int rq = 8 * (lane >> 4), cq = lane & 15;
    const float* src; const float* src2 = nullptr; float sgn = 1.f;
    int NT, N, dstoff, lf;
    if (f < 64)       { src = q_w;  NT = 8;  N = 128; dstoff = OFF_Q;  lf = f; }
    else if (f < 128) { src = k_w;  NT = 8;  N = 128; dstoff = OFF_K;  lf = f - 64; }
    else if (f < 192) { src = v_w;  NT = 8;  N = 128; dstoff = OFF_V;  lf = f - 128; }
    else if (f < 256) { src = o_w;  NT = 8;  N = 128; dstoff = OFF_O;  lf = f - 192; }
    else if (f < 512) { src = f1w;  NT = 32; N = 512; dstoff = OFF_F1; lf = f - 256; }
    else if (f < 768) { src = f2w;  NT = 8;  N = 128; dstoff = OFF_F2; lf = f - 512; }
    else if (f < 864) { src = o1w;             src2 = o1w + 256 * 384; sgn =  1.f;
                        NT = 24; N = 384; dstoff = OFF_XC; lf = f - 768; }
    else              { src = o1w + 128 * 384; src2 = o1w + 256 * 384; sgn = -1.f;
                        NT = 24; N = 384; dstoff = OFF_CC; lf = f - 864; }
    int kt = lf / NT, nt = lf - kt * NT;
    int row0 = kt * 32 + rq, col = nt * 16 + cq;
    s8v o;
#pragma unroll
    for (int j = 0; j < 8; ++j) {
        float v = src[(size_t)(row0 + j) * N + col];
        if (src2) v += sgn * src2[(size_t)(row0 + j) * N + col];
        o[j] = (short)f2bf(v);
    }
    *(s8v*)(ws + dstoff + (size_t)lf * 512 + (size_t)lane * 8) = o;
}

// ---------------- prologue 2: per-down-pixel LN of feat_map (eps 1e-5) ----------------
__global__ __launch_bounds__(256) void norm_kernel(const float* __restrict__ fm,
                                                   u16* __restrict__ dst) {
    int row = blockIdx.x;          // b*HD + y
    int b = row >> 6, y = row & 63;
    __shared__ float tile[128 * 97];
    __shared__ float smean[96], srst[96];
    for (int idx = threadIdx.x; idx < 128 * 96; idx += 256) {
        int c = idx / 96, w = idx - c * 96;
        tile[c * 97 + w] = fm[(((size_t)b * 128 + c) * 64 + y) * 96 + w];
    }
    __syncthreads();
    if (threadIdx.x < 96) {
        int w = threadIdx.x;
        float s = 0.f, ss = 0.f;
        for (int c = 0; c < 128; ++c) { float v = tile[c * 97 + w]; s += v; ss += v * v; }
        float mn = s * (1.f / 128.f);
        smean[w] = mn;
        srst[w]  = rsqrtf(ss * (1.f / 128.f) - mn * mn + 1e-5f);
    }
    __syncthreads();
    for (int idx = threadIdx.x; idx < 96 * 16; idx += 256) {
        int w = idx >> 4, cg = idx & 15;
        float mn = smean[w], iv = srst[w];
        s8v o;
#pragma unroll
        for (int j = 0; j < 8; ++j)
            o[j] = (short)f2bf((tile[(8 * cg + j) * 97 + w] - mn) * iv);
        *(s8v*)(dst + ((size_t)row * 96 + w) * 128 + 8 * cg) = o;
    }
}

// ---------------- main fused kernel: 1 wave = 16 pixels ----------------
// R2: launch_bounds (64,3)->(64,2). The 3-wave min squeezed VGPR to 84 and
// spilled a_cn/acf to scratch: rocprof showed WRITE_SIZE 302MB / FETCH 291MB
// (ideal ~35MB fetch, ~1MB write) — pure scratch round-trip through HBM.
// Cap 256 keeps all fragments in regs; LDS 10.2KB still allows 15 blocks/CU,
// VGPR ~170 -> ~12 blocks/CU runtime occupancy.
__global__ __launch_bounds__(64, 2) void fused_kernel(
    const u16*  __restrict__ nrmb, const float* __restrict__ fmu,
    const u16*  __restrict__ wsb,
    const float* __restrict__ ctx_g, const float* __restrict__ ctx_b,
    const float* __restrict__ qb, const float* __restrict__ vb,
    const float* __restrict__ ob,
    const float* __restrict__ f1b, const float* __restrict__ f2b,
    const float* __restrict__ o1b, const float* __restrict__ o2w,
    const float* __restrict__ o2b,
    float* __restrict__ out)
{
    const int lane = threadIdx.x;
    const int cidx = lane & 15, quad = lane >> 4;
    const int n0 = blockIdx.x * 16;
    const int b  = n0 / (HU_ * WU_);
    const int rem = n0 - b * (HU_ * WU_);
    const int hu  = rem / WU_;
    const int wu0 = rem - hu * WU_;

    __shared__ u16 arena[2 * SLOT];     // 8704 B: slot0 xn/q/oT/hn, slot1 ffn acts / head hx
    __shared__ float s_at[272];
    float* s_rs = s_at;

    // residual x: row p = 4*quad+r, ch = 16*nt+cidx
    float xacc[8][4];
#pragma unroll
    for (int nt = 0; nt < 8; ++nt) {
        int ch = 16 * nt + cidx;
        float4 v = *(const float4*)(fmu + ((size_t)(b * C_ + ch) * HU_ + hu) * WU_ + wu0 + 4 * quad);
        xacc[nt][0] = v.x; xacc[nt][1] = v.y; xacc[nt][2] = v.z; xacc[nt][3] = v.w;
    }

    const float slopes[4] = {0.451801007f, 0.204124145f, 0.092223264f, 0.041666668f};
    const int ry0 = min(hu >> 1, HD_ - 1);
    const int ry1 = min((hu >> 1) + 1, HD_ - 1);
    const float dyv0 = -(float)abs(hu - 2 * ry0);
    const float dyv1 = -(float)abs(hu - 2 * ry1);

    const int k2l = cidx & 3;
    const int ryl = (k2l >> 1) ? ry1 : ry0;
    int cbase[4];
#pragma unroll
    for (int mt = 0; mt < 4; ++mt) {
        int p = 4 * mt + (cidx >> 2);
        int rxv = min(((wu0 + p) >> 1) + (k2l & 1), WD_ - 1);
        cbase[mt] = ((b * HD_ + ryl) * WD_ + rxv) * 128;
    }

#pragma unroll 1
    for (int ly = 0; ly < 2; ++ly) {
        const u16* Wq = wsb + OFF_Q  + ly * 16384;
        const u16* Wk = wsb + OFF_K  + ly * 16384;
        const u16* Wv = wsb + OFF_V  + ly * 16384;
        const u16* Wo = wsb + OFF_O  + ly * 16384;
        const u16* W1 = wsb + OFF_F1 + ly * 65536;
        const u16* W2 = wsb + OFF_F2 + ly * 65536;
        const float* gv = ctx_g + ly * C_;
        const float* bv = ctx_b + ly * C_;

        // ---- cn A-fragments: direct global load + affine in regs (no LDS) ----
        s8v a_cn[4][4];
#pragma unroll
        for (int kt = 0; kt < 4; ++kt) {
            float4 g0 = *(const float4*)&gv[kt * 32 + 8 * quad];
            float4 g1 = *(const float4*)&gv[kt * 32 + 8 * quad + 4];
            float4 b0 = *(const float4*)&bv[kt * 32 + 8 * quad];
            float4 b1 = *(const float4*)&bv[kt * 32 + 8 * quad + 4];
#pragma unroll
            for (int mt = 0; mt < 4; ++mt) {
                s8v raw = *(const s8v*)(nrmb + cbase[mt] + kt * 32 + 8 * quad);
                s8v o;
                o[0] = (short)f2bf(fmaf(bfu((u16)raw[0]), g0.x, b0.x));
                o[1] = (short)f2bf(fmaf(bfu((u16)raw[1]), g0.y, b0.y));
                o[2] = (short)f2bf(fmaf(bfu((u16)raw[2]), g0.z, b0.z));
                o[3] = (short)f2bf(fmaf(bfu((u16)raw[3]), g0.w, b0.w));
                o[4] = (short)f2bf(fmaf(bfu((u16)raw[4]), g1.x, b1.x));
                o[5] = (short)f2bf(fmaf(bfu((u16)raw[5]), g1.y, b1.y));
                o[6] = (short)f2bf(fmaf(bfu((u16)raw[6]), g1.z, b1.z));
                o[7] = (short)f2bf(fmaf(bfu((u16)raw[7]), g1.w, b1.w));
                a_cn[kt][mt] = o;
            }
        }

        // ---- xn = LN(x,1e-6) -> slot0 ----
        {
            float mo[4], io[4];
#pragma unroll
            for (int r = 0; r < 4; ++r) {
                float s = 0.f, ss = 0.f;
#pragma unroll
                for (int nt = 0; nt < 8; ++nt) { float v = xacc[nt][r]; s += v; ss += v * v; }
#pragma unroll
                for (int m = 1; m <= 8; m <<= 1) { s += __shfl_xor(s, m, 64); ss += __shfl_xor(ss, m, 64); }
                float mn = s * (1.f / 128.f);
                mo[r] = mn; io[r] = rsqrtf(ss * (1.f / 128.f) - mn * mn + 1e-6f);
            }
#pragma unroll
            for (int nt = 0; nt < 8; ++nt)
#pragma unroll
                for (int r = 0; r < 4; ++r)
                    arena[(4 * quad + r) * 136 + 16 * nt + cidx] =
                        f2bf((xacc[nt][r] - mo[r]) * io[r]);
        }
        __syncthreads();
        s8v a_xn[4];
#pragma unroll
        for (int kt = 0; kt < 4; ++kt)
            a_xn[kt] = *(const s8v*)(arena + cidx * 136 + kt * 32 + 8 * quad);

        // ---- q = xn @ Wq + qb -> slot0 bf16 (overwrites xn) ----
        {
            f4v qa[8];
#pragma unroll
            for (int nt = 0; nt < 8; ++nt) {
                float bvv = qb[ly * C_ + 16 * nt + cidx];
                f4v t = {bvv, bvv, bvv, bvv}; qa[nt] = t;
            }
#pragma unroll
            for (int kt = 0; kt < 4; ++kt)
#pragma unroll
                for (int nt = 0; nt < 8; ++nt) {
                    s8v w = *(const s8v*)(Wq + ((size_t)((kt * 8 + nt) * 64 + lane)) * 8);
                    qa[nt] = __builtin_amdgcn_mfma_f32_16x16x32_bf16(a_xn[kt], w, qa[nt], 0, 0, 0);
                }
#pragma unroll
            for (int nt = 0; nt < 8; ++nt)
#pragma unroll
                for (int r = 0; r < 4; ++r)
                    arena[(4 * quad + r) * 136 + 16 * nt + cidx] = f2bf(qa[nt][r]);
        }
        __syncthreads();

        // ---- k GEMM + fused raw scores -> s_at ----
        // k bias dropped: q·kb is constant over the softmax axis (K2) and
        // cancels exactly under max-subtracted softmax.
#pragma unroll 1
        for (int h = 0; h < 4; ++h) {
            float part[4][4];
#pragma unroll
            for (int mt = 0; mt < 4; ++mt)
#pragma unroll
                for (int r = 0; r < 4; ++r) part[mt][r] = 0.f;
#pragma unroll
            for (int ntp = 0; ntp < 2; ++ntp) {
                int nt = 2 * h + ntp;
                f4v ka[4];
#pragma unroll
                for (int mt = 0; mt < 4; ++mt) { f4v t = {0.f, 0.f, 0.f, 0.f}; ka[mt] = t; }
#pragma unroll
                for (int kt = 0; kt < 4; ++kt) {
                    s8v w = *(const s8v*)(Wk + ((size_t)((kt * 8 + nt) * 64 + lane)) * 8);
#pragma unroll
                    for (int mt = 0; mt < 4; ++mt)
                        ka[mt] = __builtin_amdgcn_mfma_f32_16x16x32_bf16(a_cn[kt][mt], w, ka[mt], 0, 0, 0);
                }
#pragma unroll
                for (int mt = 0; mt < 4; ++mt) {
                    float qv = bfu(arena[(4 * mt + quad) * 136 + 16 * nt + cidx]);
#pragma unroll
                    for (int r = 0; r < 4; ++r) part[mt][r] = fmaf(qv, ka[mt][r], part[mt][r]);
                }
            }
#pragma unroll
            for (int mt = 0; mt < 4; ++mt)
#pragma unroll
                for (int r = 0; r < 4; ++r) {
#pragma unroll
                    for (int m = 1; m <= 8; m <<= 1) part[mt][r] += __shfl_xor(part[mt][r], m, 64);
                }
            if (cidx == 0) {
#pragma unroll
                for (int mt = 0; mt < 4; ++mt) {
                    float4 t = {part[mt][0], part[mt][1], part[mt][2], part[mt][3]};
                    *(float4*)&s_at[(4 * mt + quad) * 16 + 4 * h] = t;
                }
            }
        }
        __syncthreads();

        // ---- softmax in place ----
        {
            int p = lane >> 2, h = lane & 3;
            float4 sc = *(float4*)&s_at[p * 16 + 4 * h];
            int pw = wu0 + p;
            float sim[4] = {sc.x, sc.y, sc.z, sc.w};
#pragma unroll
            for (int r = 0; r < 4; ++r) {
                int rxv = min((pw >> 1) + (r & 1), WD_ - 1);
                float cd = ((r >> 1) ? dyv1 : dyv0) - (float)abs(pw - 2 * rxv);
                sim[r] = sim[r] * 0.17677669529663687f + slopes[h] * cd;
            }
            float mx = fmaxf(fmaxf(sim[0], sim[1]), fmaxf(sim[2], sim[3]));
            float e0 = __expf(sim[0] - mx), e1 = __expf(sim[1] - mx);
            float e2 = __expf(sim[2] - mx), e3 = __expf(sim[3] - mx);
            float si = 1.f / (e0 + e1 + e2 + e3);
            float4 at = {e0 * si, e1 * si, e2 * si, e3 * si};
            *(float4*)&s_at[p * 16 + 4 * h] = at;
        }
        __syncthreads();

        // ---- v GEMM (frag-once) + fused o = attn@v -> oT (slot0, q dead) ----
#pragma unroll 1
        for (int nt = 0; nt < 8; ++nt) {
            f4v va[4];
            float vbb = vb[ly * C_ + 16 * nt + cidx];
#pragma unroll
            for (int mt = 0; mt < 4; ++mt) { f4v t = {vbb, vbb, vbb, vbb}; va[mt] = t; }
#pragma unroll
            for (int kt = 0; kt < 4; ++kt) {
                s8v w = *(const s8v*)(Wv + ((size_t)((kt * 8 + nt) * 64 + lane)) * 8);
#pragma unroll
                for (int mt = 0; mt < 4; ++mt)
                    va[mt] = __builtin_amdgcn_mfma_f32_16x16x32_bf16(a_cn[kt][mt], w, va[mt], 0, 0, 0);
            }
            int h = nt >> 1;
#pragma unroll
            for (int mt = 0; mt < 4; ++mt) {
                float4 at = *(float4*)&s_at[(4 * mt + quad) * 16 + 4 * h];
                float ov = at.x * va[mt][0] + at.y * va[mt][1] + at.z * va[mt][2] + at.w * va[mt][3];
                arena[(4 * mt + quad) * 136 + 16 * nt + cidx] = f2bf(ov);
            }
        }
        __syncthreads();

        // ---- x += o @ Wo + ob ----
        {
            s8v a_o[4];
#pragma unroll
            for (int kt = 0; kt < 4; ++kt)
                a_o[kt] = *(const s8v*)(arena + cidx * 136 + kt * 32 + 8 * quad);
            f4v oa[8];
#pragma unroll
            for (int nt = 0; nt < 8; ++nt) {
                float bvv = ob[ly * C_ + 16 * nt + cidx];
                f4v t = {bvv, bvv, bvv, bvv}; oa[nt] = t;
            }
#pragma unroll
            for (int kt = 0; kt < 4; ++kt)
#pragma unroll
                for (int nt = 0; nt < 8; ++nt) {
                    s8v w = *(const s8v*)(Wo + ((size_t)((kt * 8 + nt) * 64 + lane)) * 8);
                    oa[nt] = __builtin_amdgcn_mfma_f32_16x16x32_bf16(a_o[kt], w, oa[nt], 0, 0, 0);
                }
#pragma unroll
            for (int nt = 0; nt < 8; ++nt)
#pragma unroll
                for (int r = 0; r < 4; ++r) xacc[nt][r] += oa[nt][r];
        }
        __syncthreads();

        // ---- hn = LN(x,1e-6) -> slot0 ----
        {
            float mo[4], io[4];
#pragma unroll
            for (int r = 0; r < 4; ++r) {
                float s = 0.f, ss = 0.f;
#pragma unroll
                for (int nt = 0; nt < 8; ++nt) { float v = xacc[nt][r]; s += v; ss += v * v; }
#pragma unroll
                for (int m = 1; m <= 8; m <<= 1) { s += __shfl_xor(s, m, 64); ss += __shfl_xor(ss, m, 64); }
                float mn = s * (1.f / 128.f);
                mo[r] = mn; io[r] = rsqrtf(ss * (1.f / 128.f) - mn * mn + 1e-6f);
            }
#pragma unroll
            for (int nt = 0; nt < 8; ++nt)
#pragma unroll
                for (int r = 0; r < 4; ++r)
                    arena[(4 * quad + r) * 136 + 16 * nt + cidx] =
                        f2bf((xacc[nt][r] - mo[r]) * io[r]);
        }
        __syncthreads();
        s8v a_hn[4];
#pragma unroll
        for (int kt = 0; kt < 4; ++kt)
            a_hn[kt] = *(const s8v*)(arena + cidx * 136 + kt * 32 + 8 * quad);

        // ---- ffn: 4 chunks of 128 cols; acts stage through slot1 only ----
        {
            f4v ga[8];
#pragma unroll
            for (int nt = 0; nt < 8; ++nt) {
                float bvv = f2b[ly * C_ + 16 * nt + cidx];
                f4v t = {bvv, bvv, bvv, bvv}; ga[nt] = t;
            }
#pragma unroll 1
            for (int c = 0; c < 4; ++c) {
                f4v fa[8];
#pragma unroll
                for (int nt = 0; nt < 8; ++nt) {
                    float bvv = f1b[ly * 512 + 128 * c + 16 * nt + cidx];
                    f4v t = {bvv, bvv, bvv, bvv}; fa[nt] = t;
                }
#pragma unroll
                for (int kt = 0; kt < 4; ++kt)
#pragma unroll
                    for (int nt = 0; nt < 8; ++nt) {
                        int ntg = 8 * c + nt;
                        s8v w = *(const s8v*)(W1 + ((size_t)((kt * 32 + ntg) * 64 + lane)) * 8);
                        fa[nt] = __builtin_amdgcn_mfma_f32_16x16x32_bf16(a_hn[kt], w, fa[nt], 0, 0, 0);
                    }
#pragma unroll
                for (int nt = 0; nt < 8; ++nt)
#pragma unroll
                    for (int r = 0; r < 4; ++r)
                        arena[SLOT + (4 * quad + r) * 136 + 16 * nt + cidx] =
                            f2bf(gelu_tanh(fa[nt][r]));
                __syncthreads();
#pragma unroll
                for (int ktl = 0; ktl < 4; ++ktl) {
                    s8v a = *(const s8v*)(arena + SLOT + cidx * 136 + ktl * 32 + 8 * quad);
#pragma unroll
                    for (int nt = 0; nt < 8; ++nt) {
                        s8v w = *(const s8v*)(W2 + ((size_t)(((4 * c + ktl) * 8 + nt) * 64 + lane)) * 8);
                        ga[nt] = __builtin_amdgcn_mfma_f32_16x16x32_bf16(a, w, ga[nt], 0, 0, 0);
                    }
                }
                __syncthreads();
            }
#pragma unroll
            for (int nt = 0; nt < 8; ++nt)
#pragma unroll
                for (int r = 0; r < 4; ++r) xacc[nt][r] += ga[nt][r];
        }
    } // layer loop

    // ================= head =================
    {
        float mo[4], io[4];
#pragma unroll
        for (int r = 0; r < 4; ++r) {
            float s = 0.f, ss = 0.f;
#pragma unroll
            for (int nt = 0; nt < 8; ++nt) { float v = xacc[nt][r]; s += v; ss += v * v; }
#pragma unroll
            for (int m = 1; m <= 8; m <<= 1) { s += __shfl_xor(s, m, 64); ss += __shfl_xor(ss, m, 64); }
            float mn = s * (1.f / 128.f);
            mo[r] = mn; io[r] = rsqrtf(ss * (1.f / 128.f) - mn * mn + 1e-6f);
        }
#pragma unroll
        for (int nt = 0; nt < 8; ++nt)
#pragma unroll
            for (int r = 0; r < 4; ++r)
                arena[(4 * quad + r) * 136 + 16 * nt + cidx] =
                    f2bf((xacc[nt][r] - mo[r]) * io[r]);
    }
    __syncthreads();
    s8v a_xf[4];
#pragma unroll
    for (int kt = 0; kt < 4; ++kt)
        a_xf[kt] = *(const s8v*)(arena + cidx * 136 + kt * 32 + 8 * quad);

    // cf A-fragments: raw nrmb, direct from global (held in regs, reused 8x)
    s8v acf[4][4];
#pragma unroll
    for (int kt = 0; kt < 4; ++kt)
#pragma unroll
        for (int mt = 0; mt < 4; ++mt)
            acf[kt][mt] = *(const s8v*)(nrmb + cbase[mt] + kt * 32 + 8 * quad);

    const u16* Wxc = wsb + OFF_XC;
    const u16* Wcc = wsb + OFF_CC;
    float part[4][4];
#pragma unroll
    for (int mt = 0; mt < 4; ++mt)
#pragma unroll
        for (int r = 0; r < 4; ++r) part[mt][r] = 0.f;

#pragma unroll 1
    for (int ntc = 0; ntc < 4; ++ntc) {
#pragma unroll 1
        for (int g = 0; g < 2; ++g) {
            const int nbase = 6 * ntc + 3 * g;   // global ntl base (0..21 step 3)
            {
                f4v hx[3];
#pragma unroll
                for (int ntl = 0; ntl < 3; ++ntl) {
                    float hb = o1b[16 * (nbase + ntl) + cidx];
                    f4v t = {hb, hb, hb, hb}; hx[ntl] = t;
                }
#pragma unroll
                for (int kt = 0; kt < 4; ++kt)
#pragma unroll
                    for (int ntl = 0; ntl < 3; ++ntl) {
                        s8v w = *(const s8v*)(Wxc + ((size_t)((kt * 24 + nbase + ntl) * 64 + lane)) * 8);
                        hx[ntl] = __builtin_amdgcn_mfma_f32_16x16x32_bf16(a_xf[kt], w, hx[ntl], 0, 0, 0);
                    }
#pragma unroll
                for (int ntl = 0; ntl < 3; ++ntl)
#pragma unroll
                    for (int r = 0; r < 4; ++r)
                        arena[SLOT + (4 * quad + r) * 56 + 16 * ntl + cidx] = f2bf(hx[ntl][r]);
            }
            __syncthreads();

            f4v hc[3][4];
#pragma unroll
            for (int ntl = 0; ntl < 3; ++ntl)
#pragma unroll
                for (int mt = 0; mt < 4; ++mt) { f4v t = {0.f, 0.f, 0.f, 0.f}; hc[ntl][mt] = t; }
#pragma unroll
            for (int kt = 0; kt < 4; ++kt)
#pragma unroll
                for (int ntl = 0; ntl < 3; ++ntl) {
                    s8v w = *(const s8v*)(Wcc + ((size_t)((kt * 24 + nbase + ntl) * 64 + lane)) * 8);
#pragma unroll
                    for (int mt = 0; mt < 4; ++mt)
                        hc[ntl][mt] = __builtin_amdgcn_mfma_f32_16x16x32_bf16(acf[kt][mt], w, hc[ntl][mt], 0, 0, 0);
                }

#pragma unroll
            for (int ntl = 0; ntl < 3; ++ntl) {
                float w2v = o2w[16 * (nbase + ntl) + cidx];
#pragma unroll
                for (int mt = 0; mt < 4; ++mt)
#pragma unroll
                    for (int r = 0; r < 4; ++r) {
                        float h1 = hc[ntl][mt][r] +
                                   bfu(arena[SLOT + (4 * mt + quad) * 56 + 16 * ntl + cidx]);
                        part[mt][r] = fmaf(gelu_erf(h1), w2v, part[mt][r]);
                    }
            }
            __syncthreads();
        }
    }

#pragma unroll
    for (int mt = 0; mt < 4; ++mt)
#pragma unroll
        for (int r = 0; r < 4; ++r) {
#pragma unroll
            for (int m = 1; m <= 8; m <<= 1) part[mt][r] += __shfl_xor(part[mt][r], m, 64);
            part[mt][r] += o2b[0];
        }
    if (cidx == 0) {
#pragma unroll
        for (int mt = 0; mt < 4; ++mt) {
            float4 t = {part[mt][0], part[mt][1], part[mt][2], part[mt][3]};
            *(float4*)&s_rs[(4 * mt + quad) * 4] = t;
        }
    }
    __syncthreads();

    if (lane < 16) {
        int p = lane;
        float4 vv = *(float4*)&s_rs[4 * p];
        float mx = fmaxf(fmaxf(vv.x, vv.y), fmaxf(vv.z, vv.w));
        float e0 = __expf(vv.x - mx), e1 = __expf(vv.y - mx);
        float e2 = __expf(vv.z - mx), e3 = __expf(vv.w - mx);
        float si = 1.f / (e0 + e1 + e2 + e3);
        size_t base = ((size_t)(b * 4) * HU_ + hu) * WU_ + wu0 + p;
        out[base]                          = e0 * si;
        out[base + (size_t)HU_ * WU_]      = e1 * si;
        out[base + (size_t)2 * HU_ * WU_]  = e2 * si;
        out[base + (size_t)3 * HU_ * WU_]  = e3 * si;
    }
}

extern "C" void kernel_launch(void* const* d_in, const int* in_sizes, int n_in,
                              void* d_out, int out_size, void* d_ws, size_t ws_size,
                              hipStream_t stream) {
    const float* feat_map    = (const float*)d_in[0];
    const float* feat_map_up = (const float*)d_in[1];
    const float* ctx_ln_b    = (const float*)d_in[2];
    const float* q_w  = (const float*)d_in[3];
    const float* q_b  = (const float*)d_in[4];
    const float* k_w  = (const float*)d_in[5];
    const float* v_w  = (const float*)d_in[7];
    const float* v_b  = (const float*)d_in[8];
    const float* o_w  = (const float*)d_in[9];
    const float* o_b  = (const float*)d_in[10];
    const float* fc1_w = (const float*)d_in[11];
    const float* fc1_b = (const float*)d_in[12];
    const float* fc2_w = (const float*)d_in[13];
    const float* fc2_b = (const float*)d_in[14];
    const float* out1_w = (const float*)d_in[15];
    const float* out1_b = (const float*)d_in[16];
    const float* out2_w = (const float*)d_in[17];
    const float* out2_b = (const float*)d_in[18];
    const float* ctx_ln_g = (const float*)d_in[19];
    float* out = (float*)d_out;
    u16* ws = (u16*)d_ws;

    swz_all<<<240, 256, 0, stream>>>(q_w, k_w, v_w, o_w, fc1_w, fc2_w, out1_w, ws);
    norm_kernel<<<128, 256, 0, stream>>>(feat_map, ws + OFF_NRM);

    fused_kernel<<<3072, 64, 0, stream>>>(
        ws + OFF_NRM, feat_map_up, ws, ctx_ln_g, ctx_ln_b,
        q_b, v_b, o_b, fc1_b, fc2_b,
        out1_b, out2_w, out2_b, out);
}

// Round 4
// 623.534 us; speedup vs baseline: 1.1781x; 1.1781x over previous
//
#include <hip/hip_runtime.h>
#include <math.h>

#define C_   128
#define HU_  128
#define WU_  192
#define HD_  64
#define WD_  96
#define HWD_ (HD_ * WD_)

typedef unsigned short u16;
typedef __attribute__((ext_vector_type(8))) short s8v;   // 8 bf16 = 4 VGPRs
typedef __attribute__((ext_vector_type(4))) float f4v;   // MFMA C/D

// ---- workspace layout (u16 units) ----
#define OFF_Q   0        // 2 layers x 16384
#define OFF_K   32768    // Wk' = diag(g)Wk (affine-folded)
#define OFF_V   65536    // Wv' = diag(g)Wv
#define OFF_O   98304
#define OFF_F1  131072   // 2 layers x 65536
#define OFF_F2  262144
#define OFF_XC  393216   // 49152 (out1 Wa+Wc, 128x384)
#define OFF_CC  442368   // 49152 (out1 Wb-Wc, 128x384)
#define OFF_NRM 491520   // normalized ctx bf16: (B,HD,WD,C) = 1572864 u16
#define OFF_VB  2064384  // folded v-bias: b@Wv + vb, 2x128 f32 = 512 u16

#define SLOT 2176        // u16 per LDS tile slot (16 rows x 136)

__device__ __forceinline__ u16 f2bf(float f) {
    unsigned u = __float_as_uint(f);
    unsigned r = (u + 0x7FFFu + ((u >> 16) & 1u)) >> 16;   // RNE
    return (u16)r;
}
__device__ __forceinline__ float bfu(u16 h) { return __uint_as_float(((unsigned)h) << 16); }

__device__ __forceinline__ float gelu_tanh(float x) {
    float u = 1.5957691216057308f * (x + 0.044715f * x * x * x);
    float e = __expf(u);
    float th = 1.0f - 2.0f / (1.0f + e);
    return 0.5f * x * (1.0f + th);
}
__device__ __forceinline__ float fast_erf(float x) {
    float z = fabsf(x);
    float t = 1.0f / (1.0f + 0.3275911f * z);
    float p = t * (0.254829592f + t * (-0.284496736f + t * (1.421413741f +
              t * (-1.453152027f + t * 1.061405429f))));
    float r = 1.0f - p * __expf(-z * z);
    return copysignf(r, x);
}
__device__ __forceinline__ float gelu_erf(float x) {
    return 0.5f * x * (1.0f + fast_erf(x * 0.7071067811865476f));
}

// ---------------- prologue 1: weight swizzles + affine folding ----------------
// ctx affine (g,b) folded into k/v paths:
//   k = (nrm*g+b)@Wk -> nrm@(diag(g)Wk)  [+ b@Wk: constant over softmax axis, cancels]
//   v = (nrm*g+b)@Wv -> nrm@(diag(g)Wv) + (b@Wv + vb)   [sum(attn)=1 passes bias through]
// frames 960..963 compute vb' = b@Wv + vb (f32, OFF_VB).
__global__ __launch_bounds__(256) void swz_all(
    const float* __restrict__ q_w, const float* __restrict__ k_w,
    const float* __restrict__ v_w, const float* __restrict__ o_w,
    const float* __restrict__ f1w, const float* __restrict__ f2w,
    const float* __restrict__ o1w,
    const float* __restrict__ ctx_g, const float* __restrict__ ctx_b,
    const float* __restrict__ vb_in, u16* __restrict__ ws)
{
    int tid = blockIdx.x * 256 + threadIdx.x;
    int f = tid >> 6, lane = tid & 63;
    if (f >= 964) return;
    if (f >= 960) {                 // folded v-bias
        int lf = f - 960;           // 0..3
        int ly = lf >> 1, col = (lf & 1) * 64 + lane;
        float s = vb_in[ly * 128 + col];
        const float* bp = ctx_b + ly * 128;
        const float* wp = v_w + (size_t)ly * 128 * 128 + col;
        for (int c = 0; c < 128; ++c) s += bp[c] * wp[(size_t)c * 128];
        ((float*)(ws + OFF_VB))[ly * 128 + col] = s;
        return;
    }
    int rq = 8 * (lane >> 4), cq = lane & 15;
    const float* src; const float* src2 = nullptr; float sgn = 1.f;
    int NT, N, dstoff, lf;
    bool scale_g = false;
    if (f < 64)       { src = q_w;  NT = 8;  N = 128; dstoff = OFF_Q;  lf = f; }
    else if (f < 128) { src = k_w;  NT = 8;  N = 128; dstoff = OFF_K;  lf = f - 64;  scale_g = true; }
    else if (f < 192) { src = v_w;  NT = 8;  N = 128; dstoff = OFF_V;  lf = f - 128; scale_g = true; }
    else if (f < 256) { src = o_w;  NT = 8;  N = 128; dstoff = OFF_O;  lf = f - 192; }
    else if (f < 512) { src = f1w;  NT = 32; N = 512; dstoff = OFF_F1; lf = f - 256; }
    else if (f < 768) { src = f2w;  NT = 8;  N = 128; dstoff = OFF_F2; lf = f - 512; }
    else if (f < 864) { src = o1w;             src2 = o1w + 256 * 384; sgn =  1.f;
                        NT = 24; N = 384; dstoff = OFF_XC; lf = f - 768; }
    else              { src = o1w + 128 * 384; src2 = o1w + 256 * 384; sgn = -1.f;
                        NT = 24; N = 384; dstoff = OFF_CC; lf = f - 864; }
    int kt = lf / NT, nt = lf - kt * NT;
    int row0 = kt * 32 + rq, col = nt * 16 + cq;
    s8v o;
#pragma unroll
    for (int j = 0; j < 8; ++j) {
        float v = src[(size_t)(row0 + j) * N + col];
        if (src2) v += sgn * src2[(size_t)(row0 + j) * N + col];
        if (scale_g) v *= ctx_g[row0 + j];   // global row = ly*128 + ch
        o[j] = (short)f2bf(v);
    }
    *(s8v*)(ws + dstoff + (size_t)lf * 512 + (size_t)lane * 8) = o;
}

// ---------------- prologue 2: per-down-pixel LN of feat_map (eps 1e-5) ----------------
__global__ __launch_bounds__(256) void norm_kernel(const float* __restrict__ fm,
                                                   u16* __restrict__ dst) {
    int row = blockIdx.x;          // b*HD + y
    int b = row >> 6, y = row & 63;
    __shared__ float tile[128 * 97];
    __shared__ float smean[96], srst[96];
    for (int idx = threadIdx.x; idx < 128 * 96; idx += 256) {
        int c = idx / 96, w = idx - c * 96;
        tile[c * 97 + w] = fm[(((size_t)b * 128 + c) * 64 + y) * 96 + w];
    }
    __syncthreads();
    if (threadIdx.x < 96) {
        int w = threadIdx.x;
        float s = 0.f, ss = 0.f;
        for (int c = 0; c < 128; ++c) { float v = tile[c * 97 + w]; s += v; ss += v * v; }
        float mn = s * (1.f / 128.f);
        smean[w] = mn;
        srst[w]  = rsqrtf(ss * (1.f / 128.f) - mn * mn + 1e-5f);
    }
    __syncthreads();
    for (int idx = threadIdx.x; idx < 96 * 16; idx += 256) {
        int w = idx >> 4, cg = idx & 15;
        float mn = smean[w], iv = srst[w];
        s8v o;
#pragma unroll
        for (int j = 0; j < 8; ++j)
            o[j] = (short)f2bf((tile[(8 * cg + j) * 97 + w] - mn) * iv);
        *(s8v*)(dst + ((size_t)row * 96 + w) * 128 + 8 * cg) = o;
    }
}

// ---------------- main fused kernel: 1 wave = 16 pixels ----------------
// R4: affine folded into Wk/Wv (prologue) -> a_cn[4][4] (64 arch regs +
// ~1280 VALU of fmaf/f2bf per wave) eliminated; k/v/head all consume RAW
// nrmb fragments. Fragments held only half-resident (2 of 4 mt tiles, 32
// regs) in k/v GEMMs; head reloads per-kt (L2-hot). Evidence (R2/R3):
// (64,N) caps ARCH vgprs at ~256/N with acc split; arch demand must be
// <~110 to avoid scratch. WRITE_SIZE 114MB @R3 was pure spill traffic.
__global__ __launch_bounds__(64, 2) void fused_kernel(
    const u16*  __restrict__ nrmb, const float* __restrict__ fmu,
    const u16*  __restrict__ wsb,
    const float* __restrict__ qb, const float* __restrict__ ob,
    const float* __restrict__ f1b, const float* __restrict__ f2b,
    const float* __restrict__ o1b, const float* __restrict__ o2w,
    const float* __restrict__ o2b,
    float* __restrict__ out)
{
    const int lane = threadIdx.x;
    const int cidx = lane & 15, quad = lane >> 4;
    const int n0 = blockIdx.x * 16;
    const int b  = n0 / (HU_ * WU_);
    const int rem = n0 - b * (HU_ * WU_);
    const int hu  = rem / WU_;
    const int wu0 = rem - hu * WU_;

    __shared__ u16 arena[2 * SLOT];     // slot0 xn/q/oT/hn, slot1 ffn acts / head hx
    __shared__ float s_at[272];
    float* s_rs = s_at;

    const float* vbp = (const float*)(wsb + OFF_VB);

    // residual x: row p = 4*quad+r, ch = 16*nt+cidx
    float xacc[8][4];
#pragma unroll
    for (int nt = 0; nt < 8; ++nt) {
        int ch = 16 * nt + cidx;
        float4 v = *(const float4*)(fmu + ((size_t)(b * C_ + ch) * HU_ + hu) * WU_ + wu0 + 4 * quad);
        xacc[nt][0] = v.x; xacc[nt][1] = v.y; xacc[nt][2] = v.z; xacc[nt][3] = v.w;
    }

    const float slopes[4] = {0.451801007f, 0.204124145f, 0.092223264f, 0.041666668f};
    const int ry0 = min(hu >> 1, HD_ - 1);
    const int ry1 = min((hu >> 1) + 1, HD_ - 1);
    const float dyv0 = -(float)abs(hu - 2 * ry0);
    const float dyv1 = -(float)abs(hu - 2 * ry1);

    const int k2l = cidx & 3;
    const int ryl = (k2l >> 1) ? ry1 : ry0;
    int cbase[4];
#pragma unroll
    for (int mt = 0; mt < 4; ++mt) {
        int p = 4 * mt + (cidx >> 2);
        int rxv = min(((wu0 + p) >> 1) + (k2l & 1), WD_ - 1);
        cbase[mt] = ((b * HD_ + ryl) * WD_ + rxv) * 128;
    }

#pragma unroll 1
    for (int ly = 0; ly < 2; ++ly) {
        const u16* Wq = wsb + OFF_Q  + ly * 16384;
        const u16* Wk = wsb + OFF_K  + ly * 16384;
        const u16* Wv = wsb + OFF_V  + ly * 16384;
        const u16* Wo = wsb + OFF_O  + ly * 16384;
        const u16* W1 = wsb + OFF_F1 + ly * 65536;
        const u16* W2 = wsb + OFF_F2 + ly * 65536;

        // ---- xn = LN(x,1e-6) -> slot0 ----
        {
            float mo[4], io[4];
#pragma unroll
            for (int r = 0; r < 4; ++r) {
                float s = 0.f, ss = 0.f;
#pragma unroll
                for (int nt = 0; nt < 8; ++nt) { float v = xacc[nt][r]; s += v; ss += v * v; }
#pragma unroll
                for (int m = 1; m <= 8; m <<= 1) { s += __shfl_xor(s, m, 64); ss += __shfl_xor(ss, m, 64); }
                float mn = s * (1.f / 128.f);
                mo[r] = mn; io[r] = rsqrtf(ss * (1.f / 128.f) - mn * mn + 1e-6f);
            }
#pragma unroll
            for (int nt = 0; nt < 8; ++nt)
#pragma unroll
                for (int r = 0; r < 4; ++r)
                    arena[(4 * quad + r) * 136 + 16 * nt + cidx] =
                        f2bf((xacc[nt][r] - mo[r]) * io[r]);
        }
        __syncthreads();
        s8v a_xn[4];
#pragma unroll
        for (int kt = 0; kt < 4; ++kt)
            a_xn[kt] = *(const s8v*)(arena + cidx * 136 + kt * 32 + 8 * quad);

        // ---- q = xn @ Wq + qb -> slot0 bf16 (overwrites xn) ----
        {
            f4v qa[8];
#pragma unroll
            for (int nt = 0; nt < 8; ++nt) {
                float bvv = qb[ly * C_ + 16 * nt + cidx];
                f4v t = {bvv, bvv, bvv, bvv}; qa[nt] = t;
            }
#pragma unroll
            for (int kt = 0; kt < 4; ++kt)
#pragma unroll
                for (int nt = 0; nt < 8; ++nt) {
                    s8v w = *(const s8v*)(Wq + ((size_t)((kt * 8 + nt) * 64 + lane)) * 8);
                    qa[nt] = __builtin_amdgcn_mfma_f32_16x16x32_bf16(a_xn[kt], w, qa[nt], 0, 0, 0);
                }
#pragma unroll
            for (int nt = 0; nt < 8; ++nt)
#pragma unroll
                for (int r = 0; r < 4; ++r)
                    arena[(4 * quad + r) * 136 + 16 * nt + cidx] = f2bf(qa[nt][r]);
        }
        __syncthreads();

        // ---- k GEMM (raw nrm @ Wk', no bias: b@Wk cancels in softmax) ----
        // mt tiles processed in 2 halves: 8 fragments = 32 arch regs resident.
#pragma unroll 1
        for (int mh = 0; mh < 2; ++mh) {
            s8v fr[4][2];
#pragma unroll
            for (int kt = 0; kt < 4; ++kt)
#pragma unroll
                for (int i = 0; i < 2; ++i)
                    fr[kt][i] = *(const s8v*)(nrmb + cbase[2 * mh + i] + kt * 32 + 8 * quad);
#pragma unroll 1
            for (int h = 0; h < 4; ++h) {
                float part[2][4];
#pragma unroll
                for (int i = 0; i < 2; ++i)
#pragma unroll
                    for (int r = 0; r < 4; ++r) part[i][r] = 0.f;
#pragma unroll
                for (int ntp = 0; ntp < 2; ++ntp) {
                    int nt = 2 * h + ntp;
                    f4v ka[2];
#pragma unroll
                    for (int i = 0; i < 2; ++i) { f4v t = {0.f, 0.f, 0.f, 0.f}; ka[i] = t; }
#pragma unroll
                    for (int kt = 0; kt < 4; ++kt) {
                        s8v w = *(const s8v*)(Wk + ((size_t)((kt * 8 + nt) * 64 + lane)) * 8);
#pragma unroll
                        for (int i = 0; i < 2; ++i)
                            ka[i] = __builtin_amdgcn_mfma_f32_16x16x32_bf16(fr[kt][i], w, ka[i], 0, 0, 0);
                    }
#pragma unroll
                    for (int i = 0; i < 2; ++i) {
                        float qv = bfu(arena[(4 * (2 * mh + i) + quad) * 136 + 16 * nt + cidx]);
#pragma unroll
                        for (int r = 0; r < 4; ++r) part[i][r] = fmaf(qv, ka[i][r], part[i][r]);
                    }
                }
#pragma unroll
                for (int i = 0; i < 2; ++i)
#pragma unroll
                    for (int r = 0; r < 4; ++r) {
#pragma unroll
                        for (int m = 1; m <= 8; m <<= 1) part[i][r] += __shfl_xor(part[i][r], m, 64);
                    }
                if (cidx == 0) {
#pragma unroll
                    for (int i = 0; i < 2; ++i) {
                        float4 t = {part[i][0], part[i][1], part[i][2], part[i][3]};
                        *(float4*)&s_at[(4 * (2 * mh + i) + quad) * 16 + 4 * h] = t;
                    }
                }
            }
        }
        __syncthreads();

        // ---- softmax in place ----
        {
            int p = lane >> 2, h = lane & 3;
            float4 sc = *(float4*)&s_at[p * 16 + 4 * h];
            int pw = wu0 + p;
            float sim[4] = {sc.x, sc.y, sc.z, sc.w};
#pragma unroll
            for (int r = 0; r < 4; ++r) {
                int rxv = min((pw >> 1) + (r & 1), WD_ - 1);
                float cd = ((r >> 1) ? dyv1 : dyv0) - (float)abs(pw - 2 * rxv);
                sim[r] = sim[r] * 0.17677669529663687f + slopes[h] * cd;
            }
            float mx = fmaxf(fmaxf(sim[0], sim[1]), fmaxf(sim[2], sim[3]));
            float e0 = __expf(sim[0] - mx), e1 = __expf(sim[1] - mx);
            float e2 = __expf(sim[2] - mx), e3 = __expf(sim[3] - mx);
            float si = 1.f / (e0 + e1 + e2 + e3);
            float4 at = {e0 * si, e1 * si, e2 * si, e3 * si};
            *(float4*)&s_at[p * 16 + 4 * h] = at;
        }
        __syncthreads();

        // ---- v GEMM (raw nrm @ Wv' + vb') + fused o = attn@v -> oT slot0 ----
#pragma unroll 1
        for (int mh = 0; mh < 2; ++mh) {
            s8v fr[4][2];
#pragma unroll
            for (int kt = 0; kt < 4; ++kt)
#pragma unroll
                for (int i = 0; i < 2; ++i)
                    fr[kt][i] = *(const s8v*)(nrmb + cbase[2 * mh + i] + kt * 32 + 8 * quad);
#pragma unroll 1
            for (int nt = 0; nt < 8; ++nt) {
                float vbb = vbp[ly * C_ + 16 * nt + cidx];
                f4v va[2];
#pragma unroll
                for (int i = 0; i < 2; ++i) { f4v t = {vbb, vbb, vbb, vbb}; va[i] = t; }
#pragma unroll
                for (int kt = 0; kt < 4; ++kt) {
                    s8v w = *(const s8v*)(Wv + ((size_t)((kt * 8 + nt) * 64 + lane)) * 8);
#pragma unroll
                    for (int i = 0; i < 2; ++i)
                        va[i] = __builtin_amdgcn_mfma_f32_16x16x32_bf16(fr[kt][i], w, va[i], 0, 0, 0);
                }
                int h = nt >> 1;
#pragma unroll
                for (int i = 0; i < 2; ++i) {
                    int mt = 2 * mh + i;
                    float4 at = *(float4*)&s_at[(4 * mt + quad) * 16 + 4 * h];
                    float ov = at.x * va[i][0] + at.y * va[i][1] + at.z * va[i][2] + at.w * va[i][3];
                    arena[(4 * mt + quad) * 136 + 16 * nt + cidx] = f2bf(ov);
                }
            }
        }
        __syncthreads();

        // ---- x += o @ Wo + ob ----
        {
            s8v a_o[4];
#pragma unroll
            for (int kt = 0; kt < 4; ++kt)
                a_o[kt] = *(const s8v*)(arena + cidx * 136 + kt * 32 + 8 * quad);
            f4v oa[8];
#pragma unroll
            for (int nt = 0; nt < 8; ++nt) {
                float bvv = ob[ly * C_ + 16 * nt + cidx];
                f4v t = {bvv, bvv, bvv, bvv}; oa[nt] = t;
            }
#pragma unroll
            for (int kt = 0; kt < 4; ++kt)
#pragma unroll
                for (int nt = 0; nt < 8; ++nt) {
                    s8v w = *(const s8v*)(Wo + ((size_t)((kt * 8 + nt) * 64 + lane)) * 8);
                    oa[nt] = __builtin_amdgcn_mfma_f32_16x16x32_bf16(a_o[kt], w, oa[nt], 0, 0, 0);
                }
#pragma unroll
            for (int nt = 0; nt < 8; ++nt)
#pragma unroll
                for (int r = 0; r < 4; ++r) xacc[nt][r] += oa[nt][r];
        }
        __syncthreads();

        // ---- hn = LN(x,1e-6) -> slot0 ----
        {
            float mo[4], io[4];
#pragma unroll
            for (int r = 0; r < 4; ++r) {
                float s = 0.f, ss = 0.f;
#pragma unroll
                for (int nt = 0; nt < 8; ++nt) { float v = xacc[nt][r]; s += v; ss += v * v; }
#pragma unroll
                for (int m = 1; m <= 8; m <<= 1) { s += __shfl_xor(s, m, 64); ss += __shfl_xor(ss, m, 64); }
                float mn = s * (1.f / 128.f);
                mo[r] = mn; io[r] = rsqrtf(ss * (1.f / 128.f) - mn * mn + 1e-6f);
            }
#pragma unroll
            for (int nt = 0; nt < 8; ++nt)
#pragma unroll
                for (int r = 0; r < 4; ++r)
                    arena[(4 * quad + r) * 136 + 16 * nt + cidx] =
                        f2bf((xacc[nt][r] - mo[r]) * io[r]);
        }
        __syncthreads();
        s8v a_hn[4];
#pragma unroll
        for (int kt = 0; kt < 4; ++kt)
            a_hn[kt] = *(const s8v*)(arena + cidx * 136 + kt * 32 + 8 * quad);

        // ---- ffn: 4 chunks of 128 cols; acts stage through slot1 only ----
        {
            f4v ga[8];
#pragma unroll
            for (int nt = 0; nt < 8; ++nt) {
                float bvv = f2b[ly * C_ + 16 * nt + cidx];
                f4v t = {bvv, bvv, bvv, bvv}; ga[nt] = t;
            }
#pragma unroll 1
            for (int c = 0; c < 4; ++c) {
                f4v fa[8];
#pragma unroll
                for (int nt = 0; nt < 8; ++nt) {
                    float bvv = f1b[ly * 512 + 128 * c + 16 * nt + cidx];
                    f4v t = {bvv, bvv, bvv, bvv}; fa[nt] = t;
                }
#pragma unroll
                for (int kt = 0; kt < 4; ++kt)
#pragma unroll
                    for (int nt = 0; nt < 8; ++nt) {
                        int ntg = 8 * c + nt;
                        s8v w = *(const s8v*)(W1 + ((size_t)((kt * 32 + ntg) * 64 + lane)) * 8);
                        fa[nt] = __builtin_amdgcn_mfma_f32_16x16x32_bf16(a_hn[kt], w, fa[nt], 0, 0, 0);
                    }
#pragma unroll
                for (int nt = 0; nt < 8; ++nt)
#pragma unroll
                    for (int r = 0; r < 4; ++r)
                        arena[SLOT + (4 * quad + r) * 136 + 16 * nt + cidx] =
                            f2bf(gelu_tanh(fa[nt][r]));
                __syncthreads();
#pragma unroll
                for (int ktl = 0; ktl < 4; ++ktl) {
                    s8v a = *(const s8v*)(arena + SLOT + cidx * 136 + ktl * 32 + 8 * quad);
#pragma unroll
                    for (int nt = 0; nt < 8; ++nt) {
                        s8v w = *(const s8v*)(W2 + ((size_t)(((4 * c + ktl) * 8 + nt) * 64 + lane)) * 8);
                        ga[nt] = __builtin_amdgcn_mfma_f32_16x16x32_bf16(a, w, ga[nt], 0, 0, 0);
                    }
                }
                __syncthreads();
            }
#pragma unroll
            for (int nt = 0; nt < 8; ++nt)
#pragma unroll
                for (int r = 0; r < 4; ++r) xacc[nt][r] += ga[nt][r];
        }
    } // layer loop

    // ================= head =================
    {
        float mo[4], io[4];
#pragma unroll
        for (int r = 0; r < 4; ++r) {
            float s = 0.f, ss = 0.f;
#pragma unroll
            for (int nt = 0; nt < 8; ++nt) { float v = xacc[nt][r]; s += v; ss += v * v; }
#pragma unroll
            for (int m = 1; m <= 8; m <<= 1) { s += __shfl_xor(s, m, 64); ss += __shfl_xor(ss, m, 64); }
            float mn = s * (1.f / 128.f);
            mo[r] = mn; io[r] = rsqrtf(ss * (1.f / 128.f) - mn * mn + 1e-6f);
        }
#pragma unroll
        for (int nt = 0; nt < 8; ++nt)
#pragma unroll
            for (int r = 0; r < 4; ++r)
                arena[(4 * quad + r) * 136 + 16 * nt + cidx] =
                    f2bf((xacc[nt][r] - mo[r]) * io[r]);
    }
    __syncthreads();
    s8v a_xf[4];
#pragma unroll
    for (int kt = 0; kt < 4; ++kt)
        a_xf[kt] = *(const s8v*)(arena + cidx * 136 + kt * 32 + 8 * quad);

    const u16* Wxc = wsb + OFF_XC;
    const u16* Wcc = wsb + OFF_CC;
    float part[4][4];
#pragma unroll
    for (int mt = 0; mt < 4; ++mt)
#pragma unroll
        for (int r = 0; r < 4; ++r) part[mt][r] = 0.f;

#pragma unroll 1
    for (int ntc = 0; ntc < 4; ++ntc) {
#pragma unroll 1
        for (int g = 0; g < 2; ++g) {
            const int nbase = 6 * ntc + 3 * g;   // global ntl base (0..21 step 3)
            {
                f4v hx[3];
#pragma unroll
                for (int ntl = 0; ntl < 3; ++ntl) {
                    float hb = o1b[16 * (nbase + ntl) + cidx];
                    f4v t = {hb, hb, hb, hb}; hx[ntl] = t;
                }
#pragma unroll
                for (int kt = 0; kt < 4; ++kt)
#pragma unroll
                    for (int ntl = 0; ntl < 3; ++ntl) {
                        s8v w = *(const s8v*)(Wxc + ((size_t)((kt * 24 + nbase + ntl) * 64 + lane)) * 8);
                        hx[ntl] = __builtin_amdgcn_mfma_f32_16x16x32_bf16(a_xf[kt], w, hx[ntl], 0, 0, 0);
                    }
#pragma unroll
                for (int ntl = 0; ntl < 3; ++ntl)
#pragma unroll
                    for (int r = 0; r < 4; ++r)
                        arena[SLOT + (4 * quad + r) * 56 + 16 * ntl + cidx] = f2bf(hx[ntl][r]);
            }
            __syncthreads();

            f4v hc[3][4];
#pragma unroll
            for (int ntl = 0; ntl < 3; ++ntl)
#pragma unroll
                for (int mt = 0; mt < 4; ++mt) { f4v t = {0.f, 0.f, 0.f, 0.f}; hc[ntl][mt] = t; }
#pragma unroll 1
            for (int kt = 0; kt < 4; ++kt) {
                s8v fr[4];
#pragma unroll
                for (int mt = 0; mt < 4; ++mt)
                    fr[mt] = *(const s8v*)(nrmb + cbase[mt] + kt * 32 + 8 * quad);
#pragma unroll
                for (int ntl = 0; ntl < 3; ++ntl) {
                    s8v w = *(const s8v*)(Wcc + ((size_t)((kt * 24 + nbase + ntl) * 64 + lane)) * 8);
#pragma unroll
                    for (int mt = 0; mt < 4; ++mt)
                        hc[ntl][mt] = __builtin_amdgcn_mfma_f32_16x16x32_bf16(fr[mt], w, hc[ntl][mt], 0, 0, 0);
                }
            }

#pragma unroll
            for (int ntl = 0; ntl < 3; ++ntl) {
                float w2v = o2w[16 * (nbase + ntl) + cidx];
#pragma unroll
                for (int mt = 0; mt < 4; ++mt)
#pragma unroll
                    for (int r = 0; r < 4; ++r) {
                        float h1 = hc[ntl][mt][r] +
                                   bfu(arena[SLOT + (4 * mt + quad) * 56 + 16 * ntl + cidx]);
                        part[mt][r] = fmaf(gelu_erf(h1), w2v, part[mt][r]);
                    }
            }
            __syncthreads();
        }
    }

#pragma unroll
    for (int mt = 0; mt < 4; ++mt)
#pragma unroll
        for (int r = 0; r < 4; ++r) {
#pragma unroll
            for (int m = 1; m <= 8; m <<= 1) part[mt][r] += __shfl_xor(part[mt][r], m, 64);
            part[mt][r] += o2b[0];
        }
    if (cidx == 0) {
#pragma unroll
        for (int mt = 0; mt < 4; ++mt) {
            float4 t = {part[mt][0], part[mt][1], part[mt][2], part[mt][3]};
            *(float4*)&s_rs[(4 * mt + quad) * 4] = t;
        }
    }
    __syncthreads();

    if (lane < 16) {
        int p = lane;
        float4 vv = *(float4*)&s_rs[4 * p];
        float mx = fmaxf(fmaxf(vv.x, vv.y), fmaxf(vv.z, vv.w));
        float e0 = __expf(vv.x - mx), e1 = __expf(vv.y - mx);
        float e2 = __expf(vv.z - mx), e3 = __expf(vv.w - mx);
        float si = 1.f / (e0 + e1 + e2 + e3);
        size_t base = ((size_t)(b * 4) * HU_ + hu) * WU_ + wu0 + p;
        out[base]                          = e0 * si;
        out[base + (size_t)HU_ * WU_]      = e1 * si;
        out[base + (size_t)2 * HU_ * WU_]  = e2 * si;
        out[base + (size_t)3 * HU_ * WU_]  = e3 * si;
    }
}

extern "C" void kernel_launch(void* const* d_in, const int* in_sizes, int n_in,
                              void* d_out, int out_size, void* d_ws, size_t ws_size,
                              hipStream_t stream) {
    const float* feat_map    = (const float*)d_in[0];
    const float* feat_map_up = (const float*)d_in[1];
    const float* ctx_ln_b    = (const float*)d_in[2];
    const float* q_w  = (const float*)d_in[3];
    const float* q_b  = (const float*)d_in[4];
    const float* k_w  = (const float*)d_in[5];
    const float* v_w  = (const float*)d_in[7];
    const float* v_b  = (const float*)d_in[8];
    const float* o_w  = (const float*)d_in[9];
    const float* o_b  = (const float*)d_in[10];
    const float* fc1_w = (const float*)d_in[11];
    const float* fc1_b = (const float*)d_in[12];
    const float* fc2_w = (const float*)d_in[13];
    const float* fc2_b = (const float*)d_in[14];
    const float* out1_w = (const float*)d_in[15];
    const float* out1_b = (const float*)d_in[16];
    const float* out2_w = (const float*)d_in[17];
    const float* out2_b = (const float*)d_in[18];
    const float* ctx_ln_g = (const float*)d_in[19];
    float* out = (float*)d_out;
    u16* ws = (u16*)d_ws;

    swz_all<<<242, 256, 0, stream>>>(q_w, k_w, v_w, o_w, fc1_w, fc2_w, out1_w,
                                     ctx_ln_g, ctx_ln_b, v_b, ws);
    norm_kernel<<<128, 256, 0, stream>>>(feat_map, ws + OFF_NRM);

    fused_kernel<<<3072, 64, 0, stream>>>(
        ws + OFF_NRM, feat_map_up, ws,
        q_b, o_b, fc1_b, fc2_b,
        out1_b, out2_w, out2_b, out);
}

// Round 5
// 414.431 us; speedup vs baseline: 1.7725x; 1.5046x over previous
//
#include <hip/hip_runtime.h>
#include <math.h>

#define C_   128
#define HU_  128
#define WU_  192
#define HD_  64
#define WD_  96
#define HWD_ (HD_ * WD_)

typedef unsigned short u16;
typedef __attribute__((ext_vector_type(8))) short s8v;   // 8 bf16 = 4 VGPRs
typedef __attribute__((ext_vector_type(4))) float f4v;   // MFMA C/D

// ---- workspace layout (u16 units) ----
#define OFF_Q   0        // 2 layers x 16384
#define OFF_K   32768    // Wk' = diag(g)Wk (affine-folded)
#define OFF_V   65536    // Wv' = diag(g)Wv
#define OFF_O   98304
#define OFF_F1  131072   // 2 layers x 65536
#define OFF_F2  262144
#define OFF_XC  393216   // 49152 (out1 Wa+Wc, 128x384)
#define OFF_CC  442368   // 49152 (out1 Wb-Wc, 128x384)
#define OFF_NRM 491520   // normalized ctx bf16: (B,HD,WD,C) = 1572864 u16
#define OFF_VB  2064384  // folded v-bias: b@Wv + vb, 2x128 f32 = 512 u16

#define SLOT 2176        // u16 per LDS tile slot (16 rows x 136)

__device__ __forceinline__ u16 f2bf(float f) {
    unsigned u = __float_as_uint(f);
    unsigned r = (u + 0x7FFFu + ((u >> 16) & 1u)) >> 16;   // RNE
    return (u16)r;
}
__device__ __forceinline__ float bfu(u16 h) { return __uint_as_float(((unsigned)h) << 16); }

__device__ __forceinline__ float gelu_tanh(float x) {
    float u = 1.5957691216057308f * (x + 0.044715f * x * x * x);
    float e = __expf(u);
    float th = 1.0f - 2.0f / (1.0f + e);
    return 0.5f * x * (1.0f + th);
}
__device__ __forceinline__ float fast_erf(float x) {
    float z = fabsf(x);
    float t = 1.0f / (1.0f + 0.3275911f * z);
    float p = t * (0.254829592f + t * (-0.284496736f + t * (1.421413741f +
              t * (-1.453152027f + t * 1.061405429f))));
    float r = 1.0f - p * __expf(-z * z);
    return copysignf(r, x);
}
__device__ __forceinline__ float gelu_erf(float x) {
    return 0.5f * x * (1.0f + fast_erf(x * 0.7071067811865476f));
}

// async global->LDS: each lane stages 16B; LDS dest = base + lane*16 (HW rule)
__device__ __forceinline__ void glds1(const u16* src, u16* dst, int lane) {
    __builtin_amdgcn_global_load_lds(
        (const __attribute__((address_space(1))) void*)(src + (size_t)lane * 8),
        (__attribute__((address_space(3))) void*)dst, 16, 0, 0);
}
#define WAITVM8() asm volatile("s_waitcnt vmcnt(8)" ::: "memory")
#define WAITVM6() asm volatile("s_waitcnt vmcnt(6)" ::: "memory")
#define WAITVM0() asm volatile("s_waitcnt vmcnt(0)" ::: "memory")

// ---------------- prologue 1: weight swizzles + affine folding ----------------
__global__ __launch_bounds__(256) void swz_all(
    const float* __restrict__ q_w, const float* __restrict__ k_w,
    const float* __restrict__ v_w, const float* __restrict__ o_w,
    const float* __restrict__ f1w, const float* __restrict__ f2w,
    const float* __restrict__ o1w,
    const float* __restrict__ ctx_g, const float* __restrict__ ctx_b,
    const float* __restrict__ vb_in, u16* __restrict__ ws)
{
    int tid = blockIdx.x * 256 + threadIdx.x;
    int f = tid >> 6, lane = tid & 63;
    if (f >= 964) return;
    if (f >= 960) {                 // folded v-bias
        int lf = f - 960;           // 0..3
        int ly = lf >> 1, col = (lf & 1) * 64 + lane;
        float s = vb_in[ly * 128 + col];
        const float* bp = ctx_b + ly * 128;
        const float* wp = v_w + (size_t)ly * 128 * 128 + col;
        for (int c = 0; c < 128; ++c) s += bp[c] * wp[(size_t)c * 128];
        ((float*)(ws + OFF_VB))[ly * 128 + col] = s;
        return;
    }
    int rq = 8 * (lane >> 4), cq = lane & 15;
    const float* src; const float* src2 = nullptr; float sgn = 1.f;
    int NT, N, dstoff, lf;
    bool scale_g = false;
    if (f < 64)       { src = q_w;  NT = 8;  N = 128; dstoff = OFF_Q;  lf = f; }
    else if (f < 128) { src = k_w;  NT = 8;  N = 128; dstoff = OFF_K;  lf = f - 64;  scale_g = true; }
    else if (f < 192) { src = v_w;  NT = 8;  N = 128; dstoff = OFF_V;  lf = f - 128; scale_g = true; }
    else if (f < 256) { src = o_w;  NT = 8;  N = 128; dstoff = OFF_O;  lf = f - 192; }
    else if (f < 512) { src = f1w;  NT = 32; N = 512; dstoff = OFF_F1; lf = f - 256; }
    else if (f < 768) { src = f2w;  NT = 8;  N = 128; dstoff = OFF_F2; lf = f - 512; }
    else if (f < 864) { src = o1w;             src2 = o1w + 256 * 384; sgn =  1.f;
                        NT = 24; N = 384; dstoff = OFF_XC; lf = f - 768; }
    else              { src = o1w + 128 * 384; src2 = o1w + 256 * 384; sgn = -1.f;
                        NT = 24; N = 384; dstoff = OFF_CC; lf = f - 864; }
    int kt = lf / NT, nt = lf - kt * NT;
    int row0 = kt * 32 + rq, col = nt * 16 + cq;
    s8v o;
#pragma unroll
    for (int j = 0; j < 8; ++j) {
        float v = src[(size_t)(row0 + j) * N + col];
        if (src2) v += sgn * src2[(size_t)(row0 + j) * N + col];
        if (scale_g) v *= ctx_g[row0 + j];
        o[j] = (short)f2bf(v);
    }
    *(s8v*)(ws + dstoff + (size_t)lf * 512 + (size_t)lane * 8) = o;
}

// ---------------- prologue 2: per-down-pixel LN of feat_map (eps 1e-5) ----------------
__global__ __launch_bounds__(256) void norm_kernel(const float* __restrict__ fm,
                                                   u16* __restrict__ dst) {
    int row = blockIdx.x;          // b*HD + y
    int b = row >> 6, y = row & 63;
    __shared__ float tile[128 * 97];
    __shared__ float smean[96], srst[96];
    for (int idx = threadIdx.x; idx < 128 * 96; idx += 256) {
        int c = idx / 96, w = idx - c * 96;
        tile[c * 97 + w] = fm[(((size_t)b * 128 + c) * 64 + y) * 96 + w];
    }
    __syncthreads();
    if (threadIdx.x < 96) {
        int w = threadIdx.x;
        float s = 0.f, ss = 0.f;
        for (int c = 0; c < 128; ++c) { float v = tile[c * 97 + w]; s += v; ss += v * v; }
        float mn = s * (1.f / 128.f);
        smean[w] = mn;
        srst[w]  = rsqrtf(ss * (1.f / 128.f) - mn * mn + 1e-5f);
    }
    __syncthreads();
    for (int idx = threadIdx.x; idx < 96 * 16; idx += 256) {
        int w = idx >> 4, cg = idx & 15;
        float mn = smean[w], iv = srst[w];
        s8v o;
#pragma unroll
        for (int j = 0; j < 8; ++j)
            o[j] = (short)f2bf((tile[(8 * cg + j) * 97 + w] - mn) * iv);
        *(s8v*)(dst + ((size_t)row * 96 + w) * 128 + 8 * cg) = o;
    }
}

// ---------------- main fused kernel: 1 wave = 16 pixels ----------------
// R5: weight streams (q/k/v/o/fc1/fc2/head-XC) staged via async
// global_load_lds, double-buffered 8KB groups, counted vmcnt(8/0) waits.
// R4 evidence: ~570K stall cycles/block from weight loads at overlap
// depth ~2 (88 VGPRs). Async staging = 16KB in flight, zero VGPR cost.
__global__ __launch_bounds__(64, 2) void fused_kernel(
    const u16*  __restrict__ nrmb, const float* __restrict__ fmu,
    const u16*  __restrict__ wsb,
    const float* __restrict__ qb, const float* __restrict__ ob,
    const float* __restrict__ f1b, const float* __restrict__ f2b,
    const float* __restrict__ o1b, const float* __restrict__ o2w,
    const float* __restrict__ o2b,
    float* __restrict__ out)
{
    const int lane = threadIdx.x;
    const int cidx = lane & 15, quad = lane >> 4;
    const int n0 = blockIdx.x * 16;
    const int b  = n0 / (HU_ * WU_);
    const int rem = n0 - b * (HU_ * WU_);
    const int hu  = rem / WU_;
    const int wu0 = rem - hu * WU_;

    __shared__ __align__(16) u16 wlds[2][4096];   // 16KB weight stream dbuf
    __shared__ u16 arena[2 * SLOT];
    __shared__ float s_at[272];
    float* s_rs = s_at;

    const float* vbp = (const float*)(wsb + OFF_VB);

    float xacc[8][4];
#pragma unroll
    for (int nt = 0; nt < 8; ++nt) {
        int ch = 16 * nt + cidx;
        float4 v = *(const float4*)(fmu + ((size_t)(b * C_ + ch) * HU_ + hu) * WU_ + wu0 + 4 * quad);
        xacc[nt][0] = v.x; xacc[nt][1] = v.y; xacc[nt][2] = v.z; xacc[nt][3] = v.w;
    }

    const float slopes[4] = {0.451801007f, 0.204124145f, 0.092223264f, 0.041666668f};
    const int ry0 = min(hu >> 1, HD_ - 1);
    const int ry1 = min((hu >> 1) + 1, HD_ - 1);
    const float dyv0 = -(float)abs(hu - 2 * ry0);
    const float dyv1 = -(float)abs(hu - 2 * ry1);

    const int k2l = cidx & 3;
    const int ryl = (k2l >> 1) ? ry1 : ry0;
    int cbase[4];
#pragma unroll
    for (int mt = 0; mt < 4; ++mt) {
        int p = 4 * mt + (cidx >> 2);
        int rxv = min(((wu0 + p) >> 1) + (k2l & 1), WD_ - 1);
        cbase[mt] = ((b * HD_ + ryl) * WD_ + rxv) * 128;
    }

#pragma unroll 1
    for (int ly = 0; ly < 2; ++ly) {
        const u16* Wq = wsb + OFF_Q  + ly * 16384;
        const u16* Wk = wsb + OFF_K  + ly * 16384;
        const u16* Wv = wsb + OFF_V  + ly * 16384;
        const u16* Wo = wsb + OFF_O  + ly * 16384;
        const u16* W1 = wsb + OFF_F1 + ly * 65536;
        const u16* W2 = wsb + OFF_F2 + ly * 65536;

        s8v fr[4][2];

        // early-issue q groups 0,1 (cover: LN)
#pragma unroll
        for (int jj = 0; jj < 8; ++jj) glds1(Wq + (size_t)jj * 512, &wlds[0][jj * 512], lane);
#pragma unroll
        for (int jj = 0; jj < 8; ++jj) glds1(Wq + (size_t)(8 + jj) * 512, &wlds[1][jj * 512], lane);

        // ---- xn = LN(x,1e-6) -> slot0 ----
        {
            float mo[4], io[4];
#pragma unroll
            for (int r = 0; r < 4; ++r) {
                float s = 0.f, ss = 0.f;
#pragma unroll
                for (int nt = 0; nt < 8; ++nt) { float v = xacc[nt][r]; s += v; ss += v * v; }
#pragma unroll
                for (int m = 1; m <= 8; m <<= 1) { s += __shfl_xor(s, m, 64); ss += __shfl_xor(ss, m, 64); }
                float mn = s * (1.f / 128.f);
                mo[r] = mn; io[r] = rsqrtf(ss * (1.f / 128.f) - mn * mn + 1e-6f);
            }
#pragma unroll
            for (int nt = 0; nt < 8; ++nt)
#pragma unroll
                for (int r = 0; r < 4; ++r)
                    arena[(4 * quad + r) * 136 + 16 * nt + cidx] =
                        f2bf((xacc[nt][r] - mo[r]) * io[r]);
        }
        __syncthreads();
        s8v a_xn[4];
#pragma unroll
        for (int kt = 0; kt < 4; ++kt)
            a_xn[kt] = *(const s8v*)(arena + cidx * 136 + kt * 32 + 8 * quad);

        // ---- q GEMM (streamed; group g = kt) ----
        {
            f4v qa[8];
#pragma unroll
            for (int nt = 0; nt < 8; ++nt) {
                float bvv = qb[ly * C_ + 16 * nt + cidx];
                f4v t = {bvv, bvv, bvv, bvv}; qa[nt] = t;
            }
#pragma unroll
            for (int g = 0; g < 4; ++g) {
                if (g < 3) { WAITVM8(); } else { WAITVM0(); }
#pragma unroll
                for (int nt = 0; nt < 8; ++nt) {
                    s8v w = *(const s8v*)&wlds[g & 1][nt * 512 + lane * 8];
                    qa[nt] = __builtin_amdgcn_mfma_f32_16x16x32_bf16(a_xn[g], w, qa[nt], 0, 0, 0);
                }
                if (g < 2) {
#pragma unroll
                    for (int jj = 0; jj < 8; ++jj)
                        glds1(Wq + (size_t)((g + 2) * 8 + jj) * 512, &wlds[g & 1][jj * 512], lane);
                }
            }
#pragma unroll
            for (int kt = 0; kt < 4; ++kt)
#pragma unroll
                for (int i = 0; i < 2; ++i)
                    fr[kt][i] = *(const s8v*)(nrmb + cbase[i] + kt * 32 + 8 * quad);
#pragma unroll
            for (int jj = 0; jj < 8; ++jj)
                glds1(Wk + (size_t)(((jj & 3) * 8) + (jj >> 2)) * 512, &wlds[0][jj * 512], lane);
#pragma unroll
            for (int jj = 0; jj < 8; ++jj) {
                const int j = 8 + jj;
                glds1(Wk + (size_t)(((j & 3) * 8) + (j >> 2)) * 512, &wlds[1][jj * 512], lane);
            }
#pragma unroll
            for (int nt = 0; nt < 8; ++nt)
#pragma unroll
                for (int r = 0; r < 4; ++r)
                    arena[(4 * quad + r) * 136 + 16 * nt + cidx] = f2bf(qa[nt][r]);
        }
        __syncthreads();

        // ---- k GEMM + fused raw scores (streamed; mh=g>>2, h=g&3) ----
#pragma unroll
        for (int g = 0; g < 8; ++g) {
            if (g < 7) { WAITVM8(); } else { WAITVM0(); }
            if (g == 4) {
#pragma unroll
                for (int kt = 0; kt < 4; ++kt)
#pragma unroll
                    for (int i = 0; i < 2; ++i)
                        fr[kt][i] = *(const s8v*)(nrmb + cbase[2 + i] + kt * 32 + 8 * quad);
            }
            const int mh = g >> 2, h = g & 3;
            float part[2][4];
#pragma unroll
            for (int i = 0; i < 2; ++i)
#pragma unroll
                for (int r = 0; r < 4; ++r) part[i][r] = 0.f;
#pragma unroll
            for (int ntp = 0; ntp < 2; ++ntp) {
                const int nt = 2 * h + ntp;
                f4v ka[2];
#pragma unroll
                for (int i = 0; i < 2; ++i) { f4v t = {0.f, 0.f, 0.f, 0.f}; ka[i] = t; }
#pragma unroll
                for (int kt = 0; kt < 4; ++kt) {
                    s8v w = *(const s8v*)&wlds[g & 1][(ntp * 4 + kt) * 512 + lane * 8];
                    ka[0] = __builtin_amdgcn_mfma_f32_16x16x32_bf16(fr[kt][0], w, ka[0], 0, 0, 0);
                    ka[1] = __builtin_amdgcn_mfma_f32_16x16x32_bf16(fr[kt][1], w, ka[1], 0, 0, 0);
                }
#pragma unroll
                for (int i = 0; i < 2; ++i) {
                    float qv = bfu(arena[(4 * (2 * mh + i) + quad) * 136 + 16 * nt + cidx]);
#pragma unroll
                    for (int r = 0; r < 4; ++r) part[i][r] = fmaf(qv, ka[i][r], part[i][r]);
                }
            }
#pragma unroll
            for (int i = 0; i < 2; ++i)
#pragma unroll
                for (int r = 0; r < 4; ++r) {
#pragma unroll
                    for (int m = 1; m <= 8; m <<= 1) part[i][r] += __shfl_xor(part[i][r], m, 64);
                }
            if (cidx == 0) {
#pragma unroll
                for (int i = 0; i < 2; ++i) {
                    float4 t = {part[i][0], part[i][1], part[i][2], part[i][3]};
                    *(float4*)&s_at[(4 * (2 * mh + i) + quad) * 16 + 4 * h] = t;
                }
            }
            if (g < 6) {
                const int gn = g + 2;
#pragma unroll
                for (int jj = 0; jj < 8; ++jj) {
                    const int j = 8 * (gn & 3) + jj;
                    glds1(Wk + (size_t)(((j & 3) * 8) + (j >> 2)) * 512, &wlds[g & 1][jj * 512], lane);
                }
            }
        }
#pragma unroll
        for (int kt = 0; kt < 4; ++kt)
#pragma unroll
            for (int i = 0; i < 2; ++i)
                fr[kt][i] = *(const s8v*)(nrmb + cbase[i] + kt * 32 + 8 * quad);
#pragma unroll
        for (int jj = 0; jj < 8; ++jj)
            glds1(Wv + (size_t)(((jj & 3) * 8) + (jj >> 2)) * 512, &wlds[0][jj * 512], lane);
#pragma unroll
        for (int jj = 0; jj < 8; ++jj)
            glds1(Wv + (size_t)(((jj & 3) * 8) + 2 + (jj >> 2)) * 512, &wlds[1][jj * 512], lane);
        __syncthreads();

        // ---- softmax in place ----
        {
            int p = lane >> 2, h = lane & 3;
            float4 sc = *(float4*)&s_at[p * 16 + 4 * h];
            int pw = wu0 + p;
            float sim[4] = {sc.x, sc.y, sc.z, sc.w};
#pragma unroll
            for (int r = 0; r < 4; ++r) {
                int rxv = min((pw >> 1) + (r & 1), WD_ - 1);
                float cd = ((r >> 1) ? dyv1 : dyv0) - (float)abs(pw - 2 * rxv);
                sim[r] = sim[r] * 0.17677669529663687f + slopes[h] * cd;
            }
            float mx = fmaxf(fmaxf(sim[0], sim[1]), fmaxf(sim[2], sim[3]));
            float e0 = __expf(sim[0] - mx), e1 = __expf(sim[1] - mx);
            float e2 = __expf(sim[2] - mx), e3 = __expf(sim[3] - mx);
            float si = 1.f / (e0 + e1 + e2 + e3);
            float4 at = {e0 * si, e1 * si, e2 * si, e3 * si};
            *(float4*)&s_at[p * 16 + 4 * h] = at;
        }
        __syncthreads();

        // ---- v GEMM + fused o = attn@v -> oT slot0 (streamed) ----
#pragma unroll
        for (int g = 0; g < 8; ++g) {
            if (g < 7) { WAITVM8(); } else { WAITVM0(); }
            if (g == 4) {
#pragma unroll
                for (int kt = 0; kt < 4; ++kt)
#pragma unroll
                    for (int i = 0; i < 2; ++i)
                        fr[kt][i] = *(const s8v*)(nrmb + cbase[2 + i] + kt * 32 + 8 * quad);
            }
            const int mh = g >> 2, gp = g & 3;
#pragma unroll
            for (int ntp = 0; ntp < 2; ++ntp) {
                const int nt = 2 * gp + ntp;
                float vbb = vbp[ly * C_ + 16 * nt + cidx];
                f4v va[2];
#pragma unroll
                for (int i = 0; i < 2; ++i) { f4v t = {vbb, vbb, vbb, vbb}; va[i] = t; }
#pragma unroll
                for (int kt = 0; kt < 4; ++kt) {
                    s8v w = *(const s8v*)&wlds[g & 1][(ntp * 4 + kt) * 512 + lane * 8];
                    va[0] = __builtin_amdgcn_mfma_f32_16x16x32_bf16(fr[kt][0], w, va[0], 0, 0, 0);
                    va[1] = __builtin_amdgcn_mfma_f32_16x16x32_bf16(fr[kt][1], w, va[1], 0, 0, 0);
                }
                const int h = nt >> 1;
#pragma unroll
                for (int i = 0; i < 2; ++i) {
                    const int mt = 2 * mh + i;
                    float4 at = *(float4*)&s_at[(4 * mt + quad) * 16 + 4 * h];
                    float ov = at.x * va[i][0] + at.y * va[i][1] + at.z * va[i][2] + at.w * va[i][3];
                    arena[(4 * mt + quad) * 136 + 16 * nt + cidx] = f2bf(ov);
                }
            }
            if (g < 6) {
                const int gq = (g + 2) & 3;
#pragma unroll
                for (int jj = 0; jj < 8; ++jj)
                    glds1(Wv + (size_t)(((jj & 3) * 8) + 2 * gq + (jj >> 2)) * 512, &wlds[g & 1][jj * 512], lane);
            }
        }
#pragma unroll
        for (int jj = 0; jj < 8; ++jj) glds1(Wo + (size_t)jj * 512, &wlds[0][jj * 512], lane);
#pragma unroll
        for (int jj = 0; jj < 8; ++jj) glds1(Wo + (size_t)(8 + jj) * 512, &wlds[1][jj * 512], lane);
        __syncthreads();

        // ---- x += o @ Wo + ob (streamed) ----
        {
            s8v a_o[4];
#pragma unroll
            for (int kt = 0; kt < 4; ++kt)
                a_o[kt] = *(const s8v*)(arena + cidx * 136 + kt * 32 + 8 * quad);
            f4v oa[8];
#pragma unroll
            for (int nt = 0; nt < 8; ++nt) {
                float bvv = ob[ly * C_ + 16 * nt + cidx];
                f4v t = {bvv, bvv, bvv, bvv}; oa[nt] = t;
            }
#pragma unroll
            for (int g = 0; g < 4; ++g) {
                if (g < 3) { WAITVM8(); } else { WAITVM0(); }
#pragma unroll
                for (int nt = 0; nt < 8; ++nt) {
                    s8v w = *(const s8v*)&wlds[g & 1][nt * 512 + lane * 8];
                    oa[nt] = __builtin_amdgcn_mfma_f32_16x16x32_bf16(a_o[g], w, oa[nt], 0, 0, 0);
                }
                if (g < 2) {
#pragma unroll
                    for (int jj = 0; jj < 8; ++jj)
                        glds1(Wo + (size_t)((g + 2) * 8 + jj) * 512, &wlds[g & 1][jj * 512], lane);
                }
            }
#pragma unroll
            for (int jj = 0; jj < 8; ++jj) glds1(W1 + (size_t)jj * 512, &wlds[0][jj * 512], lane);
#pragma unroll
            for (int jj = 0; jj < 8; ++jj) glds1(W1 + (size_t)(32 + jj) * 512, &wlds[1][jj * 512], lane);
#pragma unroll
            for (int nt = 0; nt < 8; ++nt)
#pragma unroll
                for (int r = 0; r < 4; ++r) xacc[nt][r] += oa[nt][r];
        }
        __syncthreads();

        // ---- hn = LN(x,1e-6) -> slot0 ----
        {
            float mo[4], io[4];
#pragma unroll
            for (int r = 0; r < 4; ++r) {
                float s = 0.f, ss = 0.f;
#pragma unroll
                for (int nt = 0; nt < 8; ++nt) { float v = xacc[nt][r]; s += v; ss += v * v; }
#pragma unroll
                for (int m = 1; m <= 8; m <<= 1) { s += __shfl_xor(s, m, 64); ss += __shfl_xor(ss, m, 64); }
                float mn = s * (1.f / 128.f);
                mo[r] = mn; io[r] = rsqrtf(ss * (1.f / 128.f) - mn * mn + 1e-6f);
            }
#pragma unroll
            for (int nt = 0; nt < 8; ++nt)
#pragma unroll
                for (int r = 0; r < 4; ++r)
                    arena[(4 * quad + r) * 136 + 16 * nt + cidx] =
                        f2bf((xacc[nt][r] - mo[r]) * io[r]);
        }
        __syncthreads();
        s8v a_hn[4];
#pragma unroll
        for (int kt = 0; kt < 4; ++kt)
            a_hn[kt] = *(const s8v*)(arena + cidx * 136 + kt * 32 + 8 * quad);

        // ---- ffn: 4 chunks of 128 cols, both GEMMs streamed ----
        {
            f4v ga[8];
#pragma unroll
            for (int nt = 0; nt < 8; ++nt) {
                float bvv = f2b[ly * C_ + 16 * nt + cidx];
                f4v t = {bvv, bvv, bvv, bvv}; ga[nt] = t;
            }
#pragma unroll 1
            for (int c = 0; c < 4; ++c) {
                f4v fa[8];
#pragma unroll
                for (int nt = 0; nt < 8; ++nt) {
                    float bvv = f1b[ly * 512 + 128 * c + 16 * nt + cidx];
                    f4v t = {bvv, bvv, bvv, bvv}; fa[nt] = t;
                }
#pragma unroll
                for (int g = 0; g < 4; ++g) {
                    if (g < 3) { WAITVM8(); } else { WAITVM0(); }
#pragma unroll
                    for (int nt = 0; nt < 8; ++nt) {
                        s8v w = *(const s8v*)&wlds[g & 1][nt * 512 + lane * 8];
                        fa[nt] = __builtin_amdgcn_mfma_f32_16x16x32_bf16(a_hn[g], w, fa[nt], 0, 0, 0);
                    }
                    if (g < 2) {
#pragma unroll
                        for (int jj = 0; jj < 8; ++jj)
                            glds1(W1 + (size_t)((g + 2) * 32 + 8 * c + jj) * 512, &wlds[g & 1][jj * 512], lane);
                    }
                }
#pragma unroll
                for (int jj = 0; jj < 8; ++jj)
                    glds1(W2 + (size_t)(32 * c + jj) * 512, &wlds[0][jj * 512], lane);
#pragma unroll
                for (int jj = 0; jj < 8; ++jj)
                    glds1(W2 + (size_t)(32 * c + 8 + jj) * 512, &wlds[1][jj * 512], lane);
#pragma unroll
                for (int nt = 0; nt < 8; ++nt)
#pragma unroll
                    for (int r = 0; r < 4; ++r)
                        arena[SLOT + (4 * quad + r) * 136 + 16 * nt + cidx] =
                            f2bf(gelu_tanh(fa[nt][r]));
                __syncthreads();
#pragma unroll
                for (int g = 0; g < 4; ++g) {
                    if (g < 3) { WAITVM8(); } else { WAITVM0(); }
                    s8v a = *(const s8v*)(arena + SLOT + cidx * 136 + g * 32 + 8 * quad);
#pragma unroll
                    for (int nt = 0; nt < 8; ++nt) {
                        s8v w = *(const s8v*)&wlds[g & 1][nt * 512 + lane * 8];
                        ga[nt] = __builtin_amdgcn_mfma_f32_16x16x32_bf16(a, w, ga[nt], 0, 0, 0);
                    }
                    if (g < 2) {
#pragma unroll
                        for (int jj = 0; jj < 8; ++jj)
                            glds1(W2 + (size_t)(32 * c + (g + 2) * 8 + jj) * 512, &wlds[g & 1][jj * 512], lane);
                    }
                }
                if (c < 3) {
#pragma unroll
                    for (int jj = 0; jj < 8; ++jj)
                        glds1(W1 + (size_t)(8 * (c + 1) + jj) * 512, &wlds[0][jj * 512], lane);
#pragma unroll
                    for (int jj = 0; jj < 8; ++jj)
                        glds1(W1 + (size_t)(32 + 8 * (c + 1) + jj) * 512, &wlds[1][jj * 512], lane);
                }
                __syncthreads();
            }
#pragma unroll
            for (int nt = 0; nt < 8; ++nt)
#pragma unroll
                for (int r = 0; r < 4; ++r) xacc[nt][r] += ga[nt][r];
        }
    } // layer loop

    // ================= head =================
    const u16* Wxc = wsb + OFF_XC;
    const u16* Wcc = wsb + OFF_CC;
#pragma unroll
    for (int jj = 0; jj < 6; ++jj)
        glds1(Wxc + (size_t)((jj / 3) * 24 + (jj % 3)) * 512, &wlds[0][jj * 512], lane);
#pragma unroll
    for (int jj = 0; jj < 6; ++jj)
        glds1(Wxc + (size_t)((2 + jj / 3) * 24 + (jj % 3)) * 512, &wlds[1][jj * 512], lane);
    {
        float mo[4], io[4];
#pragma unroll
        for (int r = 0; r < 4; ++r) {
            float s = 0.f, ss = 0.f;
#pragma unroll
            for (int nt = 0; nt < 8; ++nt) { float v = xacc[nt][r]; s += v; ss += v * v; }
#pragma unroll
            for (int m = 1; m <= 8; m <<= 1) { s += __shfl_xor(s, m, 64); ss += __shfl_xor(ss, m, 64); }
            float mn = s * (1.f / 128.f);
            mo[r] = mn; io[r] = rsqrtf(ss * (1.f / 128.f) - mn * mn + 1e-6f);
        }
#pragma unroll
        for (int nt = 0; nt < 8; ++nt)
#pragma unroll
            for (int r = 0; r < 4; ++r)
                arena[(4 * quad + r) * 136 + 16 * nt + cidx] =
                    f2bf((xacc[nt][r] - mo[r]) * io[r]);
    }
    __syncthreads();
    s8v a_xf[4];
#pragma unroll
    for (int kt = 0; kt < 4; ++kt)
        a_xf[kt] = *(const s8v*)(arena + cidx * 136 + kt * 32 + 8 * quad);

    float part[4][4];
#pragma unroll
    for (int mt = 0; mt < 4; ++mt)
#pragma unroll
        for (int r = 0; r < 4; ++r) part[mt][r] = 0.f;

#pragma unroll 1
    for (int it = 0; it < 8; ++it) {
        const int nbase = 6 * (it >> 1) + 3 * (it & 1);
        {
            f4v hx[3];
#pragma unroll
            for (int ntl = 0; ntl < 3; ++ntl) {
                float hb = o1b[16 * (nbase + ntl) + cidx];
                f4v t = {hb, hb, hb, hb}; hx[ntl] = t;
            }
            WAITVM6();
#pragma unroll
            for (int kt = 0; kt < 2; ++kt)
#pragma unroll
                for (int ntl = 0; ntl < 3; ++ntl) {
                    s8v w = *(const s8v*)&wlds[0][(kt * 3 + ntl) * 512 + lane * 8];
                    hx[ntl] = __builtin_amdgcn_mfma_f32_16x16x32_bf16(a_xf[kt], w, hx[ntl], 0, 0, 0);
                }
            WAITVM0();
#pragma unroll
            for (int kt = 2; kt < 4; ++kt)
#pragma unroll
                for (int ntl = 0; ntl < 3; ++ntl) {
                    s8v w = *(const s8v*)&wlds[1][((kt - 2) * 3 + ntl) * 512 + lane * 8];
                    hx[ntl] = __builtin_amdgcn_mfma_f32_16x16x32_bf16(a_xf[kt], w, hx[ntl], 0, 0, 0);
                }
            if (it < 7) {
                const int nb2 = 6 * ((it + 1) >> 1) + 3 * ((it + 1) & 1);
#pragma unroll
                for (int jj = 0; jj < 6; ++jj)
                    glds1(Wxc + (size_t)((jj / 3) * 24 + nb2 + (jj % 3)) * 512, &wlds[0][jj * 512], lane);
#pragma unroll
                for (int jj = 0; jj < 6; ++jj)
                    glds1(Wxc + (size_t)((2 + jj / 3) * 24 + nb2 + (jj % 3)) * 512, &wlds[1][jj * 512], lane);
            }
#pragma unroll
            for (int ntl = 0; ntl < 3; ++ntl)
#pragma unroll
                for (int r = 0; r < 4; ++r)
                    arena[SLOT + (4 * quad + r) * 56 + 16 * ntl + cidx] = f2bf(hx[ntl][r]);
        }
        __syncthreads();

        f4v hc[3][4];
#pragma unroll
        for (int ntl = 0; ntl < 3; ++ntl)
#pragma unroll
            for (int mt = 0; mt < 4; ++mt) { f4v t = {0.f, 0.f, 0.f, 0.f}; hc[ntl][mt] = t; }
#pragma unroll 1
        for (int kt = 0; kt < 4; ++kt) {
            s8v frh[4];
#pragma unroll
            for (int mt = 0; mt < 4; ++mt)
                frh[mt] = *(const s8v*)(nrmb + cbase[mt] + kt * 32 + 8 * quad);
#pragma unroll
            for (int ntl = 0; ntl < 3; ++ntl) {
                s8v w = *(const s8v*)(Wcc + ((size_t)((kt * 24 + nbase + ntl) * 64 + lane)) * 8);
#pragma unroll
                for (int mt = 0; mt < 4; ++mt)
                    hc[ntl][mt] = __builtin_amdgcn_mfma_f32_16x16x32_bf16(frh[mt], w, hc[ntl][mt], 0, 0, 0);
            }
        }

#pragma unroll
        for (int ntl = 0; ntl < 3; ++ntl) {
            float w2v = o2w[16 * (nbase + ntl) + cidx];
#pragma unroll
            for (int mt = 0; mt < 4; ++mt)
#pragma unroll
                for (int r = 0; r < 4; ++r) {
                    float h1 = hc[ntl][mt][r] +
                               bfu(arena[SLOT + (4 * mt + quad) * 56 + 16 * ntl + cidx]);
                    part[mt][r] = fmaf(gelu_erf(h1), w2v, part[mt][r]);
                }
        }
        __syncthreads();
    }

#pragma unroll
    for (int mt = 0; mt < 4; ++mt)
#pragma unroll
        for (int r = 0; r < 4; ++r) {
#pragma unroll
            for (int m = 1; m <= 8; m <<= 1) part[mt][r] += __shfl_xor(part[mt][r], m, 64);
            part[mt][r] += o2b[0];
        }
    if (cidx == 0) {
#pragma unroll
        for (int mt = 0; mt < 4; ++mt) {
            float4 t = {part[mt][0], part[mt][1], part[mt][2], part[mt][3]};
            *(float4*)&s_rs[(4 * mt + quad) * 4] = t;
        }
    }
    __syncthreads();

    if (lane < 16) {
        int p = lane;
        float4 vv = *(float4*)&s_rs[4 * p];
        float mx = fmaxf(fmaxf(vv.x, vv.y), fmaxf(vv.z, vv.w));
        float e0 = __expf(vv.x - mx), e1 = __expf(vv.y - mx);
        float e2 = __expf(vv.z - mx), e3 = __expf(vv.w - mx);
        float si = 1.f / (e0 + e1 + e2 + e3);
        size_t base = ((size_t)(b * 4) * HU_ + hu) * WU_ + wu0 + p;
        out[base]                          = e0 * si;
        out[base + (size_t)HU_ * WU_]      = e1 * si;
        out[base + (size_t)2 * HU_ * WU_]  = e2 * si;
        out[base + (size_t)3 * HU_ * WU_]  = e3 * si;
    }
}

extern "C" void kernel_launch(void* const* d_in, const int* in_sizes, int n_in,
                              void* d_out, int out_size, void* d_ws, size_t ws_size,
                              hipStream_t stream) {
    const float* feat_map    = (const float*)d_in[0];
    const float* feat_map_up = (const float*)d_in[1];
    const float* ctx_ln_b    = (const float*)d_in[2];
    const float* q_w  = (const float*)d_in[3];
    const float* q_b  = (const float*)d_in[4];
    const float* k_w  = (const float*)d_in[5];
    const float* v_w  = (const float*)d_in[7];
    const float* v_b  = (const float*)d_in[8];
    const float* o_w  = (const float*)d_in[9];
    const float* o_b  = (const float*)d_in[10];
    const float* fc1_w = (const float*)d_in[11];
    const float* fc1_b = (const float*)d_in[12];
    const float* fc2_w = (const float*)d_in[13];
    const float* fc2_b = (const float*)d_in[14];
    const float* out1_w = (const float*)d_in[15];
    const float* out1_b = (const float*)d_in[16];
    const float* out2_w = (const float*)d_in[17];
    const float* out2_b = (const float*)d_in[18];
    const float* ctx_ln_g = (const float*)d_in[19];
    float* out = (float*)d_out;
    u16* ws = (u16*)d_ws;

    swz_all<<<242, 256, 0, stream>>>(q_w, k_w, v_w, o_w, fc1_w, fc2_w, out1_w,
                                     ctx_ln_g, ctx_ln_b, v_b, ws);
    norm_kernel<<<128, 256, 0, stream>>>(feat_map, ws + OFF_NRM);

    fused_kernel<<<3072, 64, 0, stream>>>(
        ws + OFF_NRM, feat_map_up, ws,
        q_b, o_b, fc1_b, fc2_b,
        out1_b, out2_w, out2_b, out);
}

// Round 6
// 412.614 us; speedup vs baseline: 1.7803x; 1.0044x over previous
//
#include <hip/hip_runtime.h>
#include <math.h>

#define C_   128
#define HU_  128
#define WU_  192
#define HD_  64
#define WD_  96
#define HWD_ (HD_ * WD_)

typedef unsigned short u16;
typedef __attribute__((ext_vector_type(8))) short s8v;   // 8 bf16 = 4 VGPRs
typedef __attribute__((ext_vector_type(4))) float f4v;   // MFMA C/D

// ---- workspace layout (u16 units) ----
#define OFF_Q   0        // 2 layers x 16384
#define OFF_K   32768    // Wk' = diag(g)Wk (affine-folded)
#define OFF_V   65536    // Wv' = diag(g)Wv
#define OFF_O   98304
#define OFF_F1  131072   // 2 layers x 65536
#define OFF_F2  262144
#define OFF_XC  393216   // 49152 (out1 Wa+Wc, 128x384)
#define OFF_CC  442368   // 49152 (out1 Wb-Wc, 128x384)
#define OFF_NRM 491520   // normalized ctx bf16: (B,HD,WD,C) = 1572864 u16
#define OFF_VB  2064384  // folded v-bias: b@Wv + vb, 2x128 f32 = 512 u16

#define SLOT 2176        // u16 per LDS tile slot (16 rows x 136)

__device__ __forceinline__ u16 f2bf(float f) {
    unsigned u = __float_as_uint(f);
    unsigned r = (u + 0x7FFFu + ((u >> 16) & 1u)) >> 16;   // RNE
    return (u16)r;
}
__device__ __forceinline__ float bfu(u16 h) { return __uint_as_float(((unsigned)h) << 16); }

__device__ __forceinline__ float gelu_tanh(float x) {
    float u = 1.5957691216057308f * (x + 0.044715f * x * x * x);
    float e = __expf(u);
    float th = 1.0f - 2.0f / (1.0f + e);
    return 0.5f * x * (1.0f + th);
}
__device__ __forceinline__ float fast_erf(float x) {
    float z = fabsf(x);
    float t = 1.0f / (1.0f + 0.3275911f * z);
    float p = t * (0.254829592f + t * (-0.284496736f + t * (1.421413741f +
              t * (-1.453152027f + t * 1.061405429f))));
    float r = 1.0f - p * __expf(-z * z);
    return copysignf(r, x);
}
__device__ __forceinline__ float gelu_erf(float x) {
    return 0.5f * x * (1.0f + fast_erf(x * 0.7071067811865476f));
}

// async global->LDS: each lane stages 16B; LDS dest = base + lane*16 (HW rule)
__device__ __forceinline__ void glds1(const u16* src, u16* dst, int lane) {
    __builtin_amdgcn_global_load_lds(
        (const __attribute__((address_space(1))) void*)(src + (size_t)lane * 8),
        (__attribute__((address_space(3))) void*)dst, 16, 0, 0);
}
// group protocol (2 waves share wlds; each wave stages its own half):
//  GW*: wait OWN staged chunks of the group, then rendezvous -> all halves in.
//  BAR: post-consume rendezvous -> nobody still reads buffer we re-stage.
#define GW4() do { asm volatile("s_waitcnt vmcnt(4)" ::: "memory"); __builtin_amdgcn_s_barrier(); } while (0)
#define GW3() do { asm volatile("s_waitcnt vmcnt(3)" ::: "memory"); __builtin_amdgcn_s_barrier(); } while (0)
#define GW0() do { asm volatile("s_waitcnt vmcnt(0)" ::: "memory"); __builtin_amdgcn_s_barrier(); } while (0)
#define BAR() __builtin_amdgcn_s_barrier()
// wave-local LDS fence (arena/s_at are wave-private; no cross-wave barrier,
// and crucially NO vmcnt drain -> cross-phase prefetch stays in flight)
#define WFENCE() asm volatile("s_waitcnt lgkmcnt(0)" ::: "memory")

// ---------------- prologue 1: weight swizzles + affine folding ----------------
__global__ __launch_bounds__(256) void swz_all(
    const float* __restrict__ q_w, const float* __restrict__ k_w,
    const float* __restrict__ v_w, const float* __restrict__ o_w,
    const float* __restrict__ f1w, const float* __restrict__ f2w,
    const float* __restrict__ o1w,
    const float* __restrict__ ctx_g, const float* __restrict__ ctx_b,
    const float* __restrict__ vb_in, u16* __restrict__ ws)
{
    int tid = blockIdx.x * 256 + threadIdx.x;
    int f = tid >> 6, lane = tid & 63;
    if (f >= 964) return;
    if (f >= 960) {                 // folded v-bias
        int lf = f - 960;           // 0..3
        int ly = lf >> 1, col = (lf & 1) * 64 + lane;
        float s = vb_in[ly * 128 + col];
        const float* bp = ctx_b + ly * 128;
        const float* wp = v_w + (size_t)ly * 128 * 128 + col;
        for (int c = 0; c < 128; ++c) s += bp[c] * wp[(size_t)c * 128];
        ((float*)(ws + OFF_VB))[ly * 128 + col] = s;
        return;
    }
    int rq = 8 * (lane >> 4), cq = lane & 15;
    const float* src; const float* src2 = nullptr; float sgn = 1.f;
    int NT, N, dstoff, lf;
    bool scale_g = false;
    if (f < 64)       { src = q_w;  NT = 8;  N = 128; dstoff = OFF_Q;  lf = f; }
    else if (f < 128) { src = k_w;  NT = 8;  N = 128; dstoff = OFF_K;  lf = f - 64;  scale_g = true; }
    else if (f < 192) { src = v_w;  NT = 8;  N = 128; dstoff = OFF_V;  lf = f - 128; scale_g = true; }
    else if (f < 256) { src = o_w;  NT = 8;  N = 128; dstoff = OFF_O;  lf = f - 192; }
    else if (f < 512) { src = f1w;  NT = 32; N = 512; dstoff = OFF_F1; lf = f - 256; }
    else if (f < 768) { src = f2w;  NT = 8;  N = 128; dstoff = OFF_F2; lf = f - 512; }
    else if (f < 864) { src = o1w;             src2 = o1w + 256 * 384; sgn =  1.f;
                        NT = 24; N = 384; dstoff = OFF_XC; lf = f - 768; }
    else              { src = o1w + 128 * 384; src2 = o1w + 256 * 384; sgn = -1.f;
                        NT = 24; N = 384; dstoff = OFF_CC; lf = f - 864; }
    int kt = lf / NT, nt = lf - kt * NT;
    int row0 = kt * 32 + rq, col = nt * 16 + cq;
    s8v o;
#pragma unroll
    for (int j = 0; j < 8; ++j) {
        float v = src[(size_t)(row0 + j) * N + col];
        if (src2) v += sgn * src2[(size_t)(row0 + j) * N + col];
        if (scale_g) v *= ctx_g[row0 + j];
        o[j] = (short)f2bf(v);
    }
    *(s8v*)(ws + dstoff + (size_t)lf * 512 + (size_t)lane * 8) = o;
}

// ---------------- prologue 2: per-down-pixel LN of feat_map (eps 1e-5) ----------------
__global__ __launch_bounds__(256) void norm_kernel(const float* __restrict__ fm,
                                                   u16* __restrict__ dst) {
    int row = blockIdx.x;          // b*HD + y
    int b = row >> 6, y = row & 63;
    __shared__ float tile[128 * 97];
    __shared__ float smean[96], srst[96];
    for (int idx = threadIdx.x; idx < 128 * 96; idx += 256) {
        int c = idx / 96, w = idx - c * 96;
        tile[c * 97 + w] = fm[(((size_t)b * 128 + c) * 64 + y) * 96 + w];
    }
    __syncthreads();
    if (threadIdx.x < 96) {
        int w = threadIdx.x;
        float s = 0.f, ss = 0.f;
        for (int c = 0; c < 128; ++c) { float v = tile[c * 97 + w]; s += v; ss += v * v; }
        float mn = s * (1.f / 128.f);
        smean[w] = mn;
        srst[w]  = rsqrtf(ss * (1.f / 128.f) - mn * mn + 1e-5f);
    }
    __syncthreads();
    for (int idx = threadIdx.x; idx < 96 * 16; idx += 256) {
        int w = idx >> 4, cg = idx & 15;
        float mn = smean[w], iv = srst[w];
        s8v o;
#pragma unroll
        for (int j = 0; j < 8; ++j)
            o[j] = (short)f2bf((tile[(8 * cg + j) * 97 + w] - mn) * iv);
        *(s8v*)(dst + ((size_t)row * 96 + w) * 128 + 8 * cg) = o;
    }
}

// ---------------- main fused kernel: 2 waves x 16 pixels, shared weight stream ----------------
// R6: 128-thread blocks; waves share the async-staged weight dbuf (each wave
// stages half of every 8KB group), private arena/s_at per wave. R5 evidence:
// 52% idle at 5.2 waves/CU with every wave redundantly staging. Now 4 blocks
// x 2 waves = 8 waves/CU, halved L2 weight traffic + issue slots, and phase
// fences are wave-local lgkmcnt (no vmcnt drain -> cross-phase prefetch lives).
__global__ __launch_bounds__(128, 2) void fused_kernel(
    const u16*  __restrict__ nrmb, const float* __restrict__ fmu,
    const u16*  __restrict__ wsb,
    const float* __restrict__ qb, const float* __restrict__ ob,
    const float* __restrict__ f1b, const float* __restrict__ f2b,
    const float* __restrict__ o1b, const float* __restrict__ o2w,
    const float* __restrict__ o2b,
    float* __restrict__ out)
{
    const int tid  = threadIdx.x;
    const int wid  = tid >> 6;
    const int lane = tid & 63;
    const int cidx = lane & 15, quad = lane >> 4;
    const int n0 = blockIdx.x * 32 + wid * 16;
    const int b  = n0 / (HU_ * WU_);
    const int rem = n0 - b * (HU_ * WU_);
    const int hu  = rem / WU_;
    const int wu0 = rem - hu * WU_;

    __shared__ __align__(16) u16 wlds[2][4096];     // 16KB shared weight dbuf
    __shared__ __align__(16) u16 arena2[2][2 * SLOT]; // per-wave slots
    __shared__ float s_at2[2][272];
    u16*   const arena = arena2[wid];
    float* const s_at  = s_at2[wid];
    float* const s_rs  = s_at;

    const float* vbp = (const float*)(wsb + OFF_VB);

    float xacc[8][4];
#pragma unroll
    for (int nt = 0; nt < 8; ++nt) {
        int ch = 16 * nt + cidx;
        float4 v = *(const float4*)(fmu + ((size_t)(b * C_ + ch) * HU_ + hu) * WU_ + wu0 + 4 * quad);
        xacc[nt][0] = v.x; xacc[nt][1] = v.y; xacc[nt][2] = v.z; xacc[nt][3] = v.w;
    }

    const float slopes[4] = {0.451801007f, 0.204124145f, 0.092223264f, 0.041666668f};
    const int ry0 = min(hu >> 1, HD_ - 1);
    const int ry1 = min((hu >> 1) + 1, HD_ - 1);
    const float dyv0 = -(float)abs(hu - 2 * ry0);
    const float dyv1 = -(float)abs(hu - 2 * ry1);

    const int k2l = cidx & 3;
    const int ryl = (k2l >> 1) ? ry1 : ry0;
    int cbase[4];
#pragma unroll
    for (int mt = 0; mt < 4; ++mt) {
        int p = 4 * mt + (cidx >> 2);
        int rxv = min(((wu0 + p) >> 1) + (k2l & 1), WD_ - 1);
        cbase[mt] = ((b * HD_ + ryl) * WD_ + rxv) * 128;
    }

#pragma unroll 1
    for (int ly = 0; ly < 2; ++ly) {
        const u16* Wq = wsb + OFF_Q  + ly * 16384;
        const u16* Wk = wsb + OFF_K  + ly * 16384;
        const u16* Wv = wsb + OFF_V  + ly * 16384;
        const u16* Wo = wsb + OFF_O  + ly * 16384;
        const u16* W1 = wsb + OFF_F1 + ly * 65536;
        const u16* W2 = wsb + OFF_F2 + ly * 65536;

        s8v fr[4][2];

        // early-issue q groups 0,1 (own half; cover: LN)
#pragma unroll
        for (int jl = 0; jl < 4; ++jl) {
            int j = 4 * wid + jl;
            glds1(Wq + (size_t)j * 512, &wlds[0][j * 512], lane);
        }
#pragma unroll
        for (int jl = 0; jl < 4; ++jl) {
            int j = 4 * wid + jl;
            glds1(Wq + (size_t)(8 + j) * 512, &wlds[1][j * 512], lane);
        }

        // ---- xn = LN(x,1e-6) -> slot0 ----
        {
            float mo[4], io[4];
#pragma unroll
            for (int r = 0; r < 4; ++r) {
                float s = 0.f, ss = 0.f;
#pragma unroll
                for (int nt = 0; nt < 8; ++nt) { float v = xacc[nt][r]; s += v; ss += v * v; }
#pragma unroll
                for (int m = 1; m <= 8; m <<= 1) { s += __shfl_xor(s, m, 64); ss += __shfl_xor(ss, m, 64); }
                float mn = s * (1.f / 128.f);
                mo[r] = mn; io[r] = rsqrtf(ss * (1.f / 128.f) - mn * mn + 1e-6f);
            }
#pragma unroll
            for (int nt = 0; nt < 8; ++nt)
#pragma unroll
                for (int r = 0; r < 4; ++r)
                    arena[(4 * quad + r) * 136 + 16 * nt + cidx] =
                        f2bf((xacc[nt][r] - mo[r]) * io[r]);
        }
        WFENCE();
        s8v a_xn[4];
#pragma unroll
        for (int kt = 0; kt < 4; ++kt)
            a_xn[kt] = *(const s8v*)(arena + cidx * 136 + kt * 32 + 8 * quad);

        // ---- q GEMM (streamed; group g = kt) ----
        {
            f4v qa[8];
#pragma unroll
            for (int nt = 0; nt < 8; ++nt) {
                float bvv = qb[ly * C_ + 16 * nt + cidx];
                f4v t = {bvv, bvv, bvv, bvv}; qa[nt] = t;
            }
#pragma unroll
            for (int g = 0; g < 4; ++g) {
                if (g < 3) { GW4(); } else { GW0(); }
#pragma unroll
                for (int nt = 0; nt < 8; ++nt) {
                    s8v w = *(const s8v*)&wlds[g & 1][nt * 512 + lane * 8];
                    qa[nt] = __builtin_amdgcn_mfma_f32_16x16x32_bf16(a_xn[g], w, qa[nt], 0, 0, 0);
                }
                BAR();
                if (g < 2) {
#pragma unroll
                    for (int jl = 0; jl < 4; ++jl) {
                        int j = 4 * wid + jl;
                        glds1(Wq + (size_t)((g + 2) * 8 + j) * 512, &wlds[g & 1][j * 512], lane);
                    }
                }
            }
#pragma unroll
            for (int kt = 0; kt < 4; ++kt)
#pragma unroll
                for (int i = 0; i < 2; ++i)
                    fr[kt][i] = *(const s8v*)(nrmb + cbase[i] + kt * 32 + 8 * quad);
#pragma unroll
            for (int jl = 0; jl < 4; ++jl) {
                int j = 4 * wid + jl;
                glds1(Wk + (size_t)(((j & 3) * 8) + (j >> 2)) * 512, &wlds[0][j * 512], lane);
            }
#pragma unroll
            for (int jl = 0; jl < 4; ++jl) {
                int j = 4 * wid + jl;
                int jc = 8 + j;
                glds1(Wk + (size_t)(((jc & 3) * 8) + (jc >> 2)) * 512, &wlds[1][j * 512], lane);
            }
#pragma unroll
            for (int nt = 0; nt < 8; ++nt)
#pragma unroll
                for (int r = 0; r < 4; ++r)
                    arena[(4 * quad + r) * 136 + 16 * nt + cidx] = f2bf(qa[nt][r]);
        }
        WFENCE();

        // ---- k GEMM + fused raw scores (streamed; mh=g>>2, h=g&3) ----
#pragma unroll
        for (int g = 0; g < 8; ++g) {
            if (g < 7) { GW4(); } else { GW0(); }
            if (g == 4) {
#pragma unroll
                for (int kt = 0; kt < 4; ++kt)
#pragma unroll
                    for (int i = 0; i < 2; ++i)
                        fr[kt][i] = *(const s8v*)(nrmb + cbase[2 + i] + kt * 32 + 8 * quad);
            }
            const int mh = g >> 2, h = g & 3;
            float part[2][4];
#pragma unroll
            for (int i = 0; i < 2; ++i)
#pragma unroll
                for (int r = 0; r < 4; ++r) part[i][r] = 0.f;
#pragma unroll
            for (int ntp = 0; ntp < 2; ++ntp) {
                const int nt = 2 * h + ntp;
                f4v ka[2];
#pragma unroll
                for (int i = 0; i < 2; ++i) { f4v t = {0.f, 0.f, 0.f, 0.f}; ka[i] = t; }
#pragma unroll
                for (int kt = 0; kt < 4; ++kt) {
                    s8v w = *(const s8v*)&wlds[g & 1][(ntp * 4 + kt) * 512 + lane * 8];
                    ka[0] = __builtin_amdgcn_mfma_f32_16x16x32_bf16(fr[kt][0], w, ka[0], 0, 0, 0);
                    ka[1] = __builtin_amdgcn_mfma_f32_16x16x32_bf16(fr[kt][1], w, ka[1], 0, 0, 0);
                }
#pragma unroll
                for (int i = 0; i < 2; ++i) {
                    float qv = bfu(arena[(4 * (2 * mh + i) + quad) * 136 + 16 * nt + cidx]);
#pragma unroll
                    for (int r = 0; r < 4; ++r) part[i][r] = fmaf(qv, ka[i][r], part[i][r]);
                }
            }
#pragma unroll
            for (int i = 0; i < 2; ++i)
#pragma unroll
                for (int r = 0; r < 4; ++r) {
#pragma unroll
                    for (int m = 1; m <= 8; m <<= 1) part[i][r] += __shfl_xor(part[i][r], m, 64);
                }
            if (cidx == 0) {
#pragma unroll
                for (int i = 0; i < 2; ++i) {
                    float4 t = {part[i][0], part[i][1], part[i][2], part[i][3]};
                    *(float4*)&s_at[(4 * (2 * mh + i) + quad) * 16 + 4 * h] = t;
                }
            }
            BAR();
            if (g < 6) {
                const int gn = g + 2;
#pragma unroll
                for (int jl = 0; jl < 4; ++jl) {
                    int j = 4 * wid + jl;
                    int jc = 8 * (gn & 3) + j;
                    glds1(Wk + (size_t)(((jc & 3) * 8) + (jc >> 2)) * 512, &wlds[g & 1][j * 512], lane);
                }
            }
        }
#pragma unroll
        for (int kt = 0; kt < 4; ++kt)
#pragma unroll
            for (int i = 0; i < 2; ++i)
                fr[kt][i] = *(const s8v*)(nrmb + cbase[i] + kt * 32 + 8 * quad);
#pragma unroll
        for (int jl = 0; jl < 4; ++jl) {
            int j = 4 * wid + jl;
            glds1(Wv + (size_t)(((j & 3) * 8) + (j >> 2)) * 512, &wlds[0][j * 512], lane);
        }
#pragma unroll
        for (int jl = 0; jl < 4; ++jl) {
            int j = 4 * wid + jl;
            glds1(Wv + (size_t)(((j & 3) * 8) + 2 + (j >> 2)) * 512, &wlds[1][j * 512], lane);
        }
        WFENCE();

        // ---- softmax in place (wave-private s_at) ----
        {
            int p = lane >> 2, h = lane & 3;
            float4 sc = *(float4*)&s_at[p * 16 + 4 * h];
            int pw = wu0 + p;
            float sim[4] = {sc.x, sc.y, sc.z, sc.w};
#pragma unroll
            for (int r = 0; r < 4; ++r) {
                int rxv = min((pw >> 1) + (r & 1), WD_ - 1);
                float cd = ((r >> 1) ? dyv1 : dyv0) - (float)abs(pw - 2 * rxv);
                sim[r] = sim[r] * 0.17677669529663687f + slopes[h] * cd;
            }
            float mx = fmaxf(fmaxf(sim[0], sim[1]), fmaxf(sim[2], sim[3]));
            float e0 = __expf(sim[0] - mx), e1 = __expf(sim[1] - mx);
            float e2 = __expf(sim[2] - mx), e3 = __expf(sim[3] - mx);
            float si = 1.f / (e0 + e1 + e2 + e3);
            float4 at = {e0 * si, e1 * si, e2 * si, e3 * si};
            *(float4*)&s_at[p * 16 + 4 * h] = at;
        }
        WFENCE();

        // ---- v GEMM + fused o = attn@v -> oT slot0 (streamed) ----
#pragma unroll
        for (int g = 0; g < 8; ++g) {
            if (g < 7) { GW4(); } else { GW0(); }
            if (g == 4) {
#pragma unroll
                for (int kt = 0; kt < 4; ++kt)
#pragma unroll
                    for (int i = 0; i < 2; ++i)
                        fr[kt][i] = *(const s8v*)(nrmb + cbase[2 + i] + kt * 32 + 8 * quad);
            }
            const int mh = g >> 2, gp = g & 3;
#pragma unroll
            for (int ntp = 0; ntp < 2; ++ntp) {
                const int nt = 2 * gp + ntp;
                float vbb = vbp[ly * C_ + 16 * nt + cidx];
                f4v va[2];
#pragma unroll
                for (int i = 0; i < 2; ++i) { f4v t = {vbb, vbb, vbb, vbb}; va[i] = t; }
#pragma unroll
                for (int kt = 0; kt < 4; ++kt) {
                    s8v w = *(const s8v*)&wlds[g & 1][(ntp * 4 + kt) * 512 + lane * 8];
                    va[0] = __builtin_amdgcn_mfma_f32_16x16x32_bf16(fr[kt][0], w, va[0], 0, 0, 0);
                    va[1] = __builtin_amdgcn_mfma_f32_16x16x32_bf16(fr[kt][1], w, va[1], 0, 0, 0);
                }
                const int h = nt >> 1;
#pragma unroll
                for (int i = 0; i < 2; ++i) {
                    const int mt = 2 * mh + i;
                    float4 at = *(float4*)&s_at[(4 * mt + quad) * 16 + 4 * h];
                    float ov = at.x * va[i][0] + at.y * va[i][1] + at.z * va[i][2] + at.w * va[i][3];
                    arena[(4 * mt + quad) * 136 + 16 * nt + cidx] = f2bf(ov);
                }
            }
            BAR();
            if (g < 6) {
                const int gq = (g + 2) & 3;
#pragma unroll
                for (int jl = 0; jl < 4; ++jl) {
                    int j = 4 * wid + jl;
                    glds1(Wv + (size_t)(((j & 3) * 8) + 2 * gq + (j >> 2)) * 512, &wlds[g & 1][j * 512], lane);
                }
            }
        }
#pragma unroll
        for (int jl = 0; jl < 4; ++jl) {
            int j = 4 * wid + jl;
            glds1(Wo + (size_t)j * 512, &wlds[0][j * 512], lane);
        }
#pragma unroll
        for (int jl = 0; jl < 4; ++jl) {
            int j = 4 * wid + jl;
            glds1(Wo + (size_t)(8 + j) * 512, &wlds[1][j * 512], lane);
        }
        WFENCE();

        // ---- x += o @ Wo + ob (streamed) ----
        {
            s8v a_o[4];
#pragma unroll
            for (int kt = 0; kt < 4; ++kt)
                a_o[kt] = *(const s8v*)(arena + cidx * 136 + kt * 32 + 8 * quad);
            f4v oa[8];
#pragma unroll
            for (int nt = 0; nt < 8; ++nt) {
                float bvv = ob[ly * C_ + 16 * nt + cidx];
                f4v t = {bvv, bvv, bvv, bvv}; oa[nt] = t;
            }
#pragma unroll
            for (int g = 0; g < 4; ++g) {
                if (g < 3) { GW4(); } else { GW0(); }
#pragma unroll
                for (int nt = 0; nt < 8; ++nt) {
                    s8v w = *(const s8v*)&wlds[g & 1][nt * 512 + lane * 8];
                    oa[nt] = __builtin_amdgcn_mfma_f32_16x16x32_bf16(a_o[g], w, oa[nt], 0, 0, 0);
                }
                BAR();
                if (g < 2) {
#pragma unroll
                    for (int jl = 0; jl < 4; ++jl) {
                        int j = 4 * wid + jl;
                        glds1(Wo + (size_t)((g + 2) * 8 + j) * 512, &wlds[g & 1][j * 512], lane);
                    }
                }
            }
#pragma unroll
            for (int jl = 0; jl < 4; ++jl) {
                int j = 4 * wid + jl;
                glds1(W1 + (size_t)j * 512, &wlds[0][j * 512], lane);
            }
#pragma unroll
            for (int jl = 0; jl < 4; ++jl) {
                int j = 4 * wid + jl;
                glds1(W1 + (size_t)(32 + j) * 512, &wlds[1][j * 512], lane);
            }
#pragma unroll
            for (int nt = 0; nt < 8; ++nt)
#pragma unroll
                for (int r = 0; r < 4; ++r) xacc[nt][r] += oa[nt][r];
        }

        // ---- hn = LN(x,1e-6) -> slot0 ----
        {
            float mo[4], io[4];
#pragma unroll
            for (int r = 0; r < 4; ++r) {
                float s = 0.f, ss = 0.f;
#pragma unroll
                for (int nt = 0; nt < 8; ++nt) { float v = xacc[nt][r]; s += v; ss += v * v; }
#pragma unroll
                for (int m = 1; m <= 8; m <<= 1) { s += __shfl_xor(s, m, 64); ss += __shfl_xor(ss, m, 64); }
                float mn = s * (1.f / 128.f);
                mo[r] = mn; io[r] = rsqrtf(ss * (1.f / 128.f) - mn * mn + 1e-6f);
            }
#pragma unroll
            for (int nt = 0; nt < 8; ++nt)
#pragma unroll
                for (int r = 0; r < 4; ++r)
                    arena[(4 * quad + r) * 136 + 16 * nt + cidx] =
                        f2bf((xacc[nt][r] - mo[r]) * io[r]);
        }
        WFENCE();
        s8v a_hn[4];
#pragma unroll
        for (int kt = 0; kt < 4; ++kt)
            a_hn[kt] = *(const s8v*)(arena + cidx * 136 + kt * 32 + 8 * quad);

        // ---- ffn: 4 chunks of 128 cols, both GEMMs streamed ----
        {
            f4v ga[8];
#pragma unroll
            for (int nt = 0; nt < 8; ++nt) {
                float bvv = f2b[ly * C_ + 16 * nt + cidx];
                f4v t = {bvv, bvv, bvv, bvv}; ga[nt] = t;
            }
#pragma unroll 1
            for (int c = 0; c < 4; ++c) {
                f4v fa[8];
#pragma unroll
                for (int nt = 0; nt < 8; ++nt) {
                    float bvv = f1b[ly * 512 + 128 * c + 16 * nt + cidx];
                    f4v t = {bvv, bvv, bvv, bvv}; fa[nt] = t;
                }
#pragma unroll
                for (int g = 0; g < 4; ++g) {
                    if (g < 3) { GW4(); } else { GW0(); }
#pragma unroll
                    for (int nt = 0; nt < 8; ++nt) {
                        s8v w = *(const s8v*)&wlds[g & 1][nt * 512 + lane * 8];
                        fa[nt] = __builtin_amdgcn_mfma_f32_16x16x32_bf16(a_hn[g], w, fa[nt], 0, 0, 0);
                    }
                    BAR();
                    if (g < 2) {
#pragma unroll
                        for (int jl = 0; jl < 4; ++jl) {
                            int j = 4 * wid + jl;
                            glds1(W1 + (size_t)((g + 2) * 32 + 8 * c + j) * 512, &wlds[g & 1][j * 512], lane);
                        }
                    }
                }
#pragma unroll
                for (int jl = 0; jl < 4; ++jl) {
                    int j = 4 * wid + jl;
                    glds1(W2 + (size_t)(32 * c + j) * 512, &wlds[0][j * 512], lane);
                }
#pragma unroll
                for (int jl = 0; jl < 4; ++jl) {
                    int j = 4 * wid + jl;
                    glds1(W2 + (size_t)(32 * c + 8 + j) * 512, &wlds[1][j * 512], lane);
                }
#pragma unroll
                for (int nt = 0; nt < 8; ++nt)
#pragma unroll
                    for (int r = 0; r < 4; ++r)
                        arena[SLOT + (4 * quad + r) * 136 + 16 * nt + cidx] =
                            f2bf(gelu_tanh(fa[nt][r]));
                WFENCE();
#pragma unroll
                for (int g = 0; g < 4; ++g) {
                    if (g < 3) { GW4(); } else { GW0(); }
                    s8v a = *(const s8v*)(arena + SLOT + cidx * 136 + g * 32 + 8 * quad);
#pragma unroll
                    for (int nt = 0; nt < 8; ++nt) {
                        s8v w = *(const s8v*)&wlds[g & 1][nt * 512 + lane * 8];
                        ga[nt] = __builtin_amdgcn_mfma_f32_16x16x32_bf16(a, w, ga[nt], 0, 0, 0);
                    }
                    BAR();
                    if (g < 2) {
#pragma unroll
                        for (int jl = 0; jl < 4; ++jl) {
                            int j = 4 * wid + jl;
                            glds1(W2 + (size_t)(32 * c + (g + 2) * 8 + j) * 512, &wlds[g & 1][j * 512], lane);
                        }
                    }
                }
                if (c < 3) {
#pragma unroll
                    for (int jl = 0; jl < 4; ++jl) {
                        int j = 4 * wid + jl;
                        glds1(W1 + (size_t)(8 * (c + 1) + j) * 512, &wlds[0][j * 512], lane);
                    }
#pragma unroll
                    for (int jl = 0; jl < 4; ++jl) {
                        int j = 4 * wid + jl;
                        glds1(W1 + (size_t)(32 + 8 * (c + 1) + j) * 512, &wlds[1][j * 512], lane);
                    }
                }
            }
#pragma unroll
            for (int nt = 0; nt < 8; ++nt)
#pragma unroll
                for (int r = 0; r < 4; ++r) xacc[nt][r] += ga[nt][r];
        }
    } // layer loop

    // ================= head =================
    const u16* Wxc = wsb + OFF_XC;
    const u16* Wcc = wsb + OFF_CC;
#pragma unroll
    for (int jl = 0; jl < 3; ++jl) {
        int j = 3 * wid + jl;
        glds1(Wxc + (size_t)((j / 3) * 24 + (j % 3)) * 512, &wlds[0][j * 512], lane);
    }
#pragma unroll
    for (int jl = 0; jl < 3; ++jl) {
        int j = 3 * wid + jl;
        glds1(Wxc + (size_t)((2 + j / 3) * 24 + (j % 3)) * 512, &wlds[1][j * 512], lane);
    }
    {
        float mo[4], io[4];
#pragma unroll
        for (int r = 0; r < 4; ++r) {
            float s = 0.f, ss = 0.f;
#pragma unroll
            for (int nt = 0; nt < 8; ++nt) { float v = xacc[nt][r]; s += v; ss += v * v; }
#pragma unroll
            for (int m = 1; m <= 8; m <<= 1) { s += __shfl_xor(s, m, 64); ss += __shfl_xor(ss, m, 64); }
            float mn = s * (1.f / 128.f);
            mo[r] = mn; io[r] = rsqrtf(ss * (1.f / 128.f) - mn * mn + 1e-6f);
        }
#pragma unroll
        for (int nt = 0; nt < 8; ++nt)
#pragma unroll
            for (int r = 0; r < 4; ++r)
                arena[(4 * quad + r) * 136 + 16 * nt + cidx] =
                    f2bf((xacc[nt][r] - mo[r]) * io[r]);
    }
    WFENCE();
    s8v a_xf[4];
#pragma unroll
    for (int kt = 0; kt < 4; ++kt)
        a_xf[kt] = *(const s8v*)(arena + cidx * 136 + kt * 32 + 8 * quad);

    float part[4][4];
#pragma unroll
    for (int mt = 0; mt < 4; ++mt)
#pragma unroll
        for (int r = 0; r < 4; ++r) part[mt][r] = 0.f;

#pragma unroll 1
    for (int it = 0; it < 8; ++it) {
        const int nbase = 6 * (it >> 1) + 3 * (it & 1);
        {
            f4v hx[3];
#pragma unroll
            for (int ntl = 0; ntl < 3; ++ntl) {
                float hb = o1b[16 * (nbase + ntl) + cidx];
                f4v t = {hb, hb, hb, hb}; hx[ntl] = t;
            }
            GW3();
#pragma unroll
            for (int kt = 0; kt < 2; ++kt)
#pragma unroll
                for (int ntl = 0; ntl < 3; ++ntl) {
                    s8v w = *(const s8v*)&wlds[0][(kt * 3 + ntl) * 512 + lane * 8];
                    hx[ntl] = __builtin_amdgcn_mfma_f32_16x16x32_bf16(a_xf[kt], w, hx[ntl], 0, 0, 0);
                }
            GW0();
#pragma unroll
            for (int kt = 2; kt < 4; ++kt)
#pragma unroll
                for (int ntl = 0; ntl < 3; ++ntl) {
                    s8v w = *(const s8v*)&wlds[1][((kt - 2) * 3 + ntl) * 512 + lane * 8];
                    hx[ntl] = __builtin_amdgcn_mfma_f32_16x16x32_bf16(a_xf[kt], w, hx[ntl], 0, 0, 0);
                }
            BAR();
            if (it < 7) {
                const int nb2 = 6 * ((it + 1) >> 1) + 3 * ((it + 1) & 1);
#pragma unroll
                for (int jl = 0; jl < 3; ++jl) {
                    int j = 3 * wid + jl;
                    glds1(Wxc + (size_t)((j / 3) * 24 + nb2 + (j % 3)) * 512, &wlds[0][j * 512], lane);
                }
#pragma unroll
                for (int jl = 0; jl < 3; ++jl) {
                    int j = 3 * wid + jl;
                    glds1(Wxc + (size_t)((2 + j / 3) * 24 + nb2 + (j % 3)) * 512, &wlds[1][j * 512], lane);
                }
            }
#pragma unroll
            for (int ntl = 0; ntl < 3; ++ntl)
#pragma unroll
                for (int r = 0; r < 4; ++r)
                    arena[SLOT + (4 * quad + r) * 56 + 16 * ntl + cidx] = f2bf(hx[ntl][r]);
        }
        WFENCE();

        f4v hc[3][4];
#pragma unroll
        for (int ntl = 0; ntl < 3; ++ntl)
#pragma unroll
            for (int mt = 0; mt < 4; ++mt) { f4v t = {0.f, 0.f, 0.f, 0.f}; hc[ntl][mt] = t; }
#pragma unroll 1
        for (int kt = 0; kt < 4; ++kt) {
            s8v frh[4];
#pragma unroll
            for (int mt = 0; mt < 4; ++mt)
                frh[mt] = *(const s8v*)(nrmb + cbase[mt] + kt * 32 + 8 * quad);
#pragma unroll
            for (int ntl = 0; ntl < 3; ++ntl) {
                s8v w = *(const s8v*)(Wcc + ((size_t)((kt * 24 + nbase + ntl) * 64 + lane)) * 8);
#pragma unroll
                for (int mt = 0; mt < 4; ++mt)
                    hc[ntl][mt] = __builtin_amdgcn_mfma_f32_16x16x32_bf16(frh[mt], w, hc[ntl][mt], 0, 0, 0);
            }
        }

#pragma unroll
        for (int ntl = 0; ntl < 3; ++ntl) {
            float w2v = o2w[16 * (nbase + ntl) + cidx];
#pragma unroll
            for (int mt = 0; mt < 4; ++mt)
#pragma unroll
                for (int r = 0; r < 4; ++r) {
                    float h1 = hc[ntl][mt][r] +
                               bfu(arena[SLOT + (4 * mt + quad) * 56 + 16 * ntl + cidx]);
                    part[mt][r] = fmaf(gelu_erf(h1), w2v, part[mt][r]);
                }
        }
        WFENCE();
    }

#pragma unroll
    for (int mt = 0; mt < 4; ++mt)
#pragma unroll
        for (int r = 0; r < 4; ++r) {
#pragma unroll
            for (int m = 1; m <= 8; m <<= 1) part[mt][r] += __shfl_xor(part[mt][r], m, 64);
            part[mt][r] += o2b[0];
        }
    if (cidx == 0) {
#pragma unroll
        for (int mt = 0; mt < 4; ++mt) {
            float4 t = {part[mt][0], part[mt][1], part[mt][2], part[mt][3]};
            *(float4*)&s_rs[(4 * mt + quad) * 4] = t;
        }
    }
    WFENCE();

    if (lane < 16) {
        int p = lane;
        float4 vv = *(float4*)&s_rs[4 * p];
        float mx = fmaxf(fmaxf(vv.x, vv.y), fmaxf(vv.z, vv.w));
        float e0 = __expf(vv.x - mx), e1 = __expf(vv.y - mx);
        float e2 = __expf(vv.z - mx), e3 = __expf(vv.w - mx);
        float si = 1.f / (e0 + e1 + e2 + e3);
        size_t base = ((size_t)(b * 4) * HU_ + hu) * WU_ + wu0 + p;
        out[base]                          = e0 * si;
        out[base + (size_t)HU_ * WU_]      = e1 * si;
        out[base + (size_t)2 * HU_ * WU_]  = e2 * si;
        out[base + (size_t)3 * HU_ * WU_]  = e3 * si;
    }
}

extern "C" void kernel_launch(void* const* d_in, const int* in_sizes, int n_in,
                              void* d_out, int out_size, void* d_ws, size_t ws_size,
                              hipStream_t stream) {
    const float* feat_map    = (const float*)d_in[0];
    const float* feat_map_up = (const float*)d_in[1];
    const float* ctx_ln_b    = (const float*)d_in[2];
    const float* q_w  = (const float*)d_in[3];
    const float* q_b  = (const float*)d_in[4];
    const float* k_w  = (const float*)d_in[5];
    const float* v_w  = (const float*)d_in[7];
    const float* v_b  = (const float*)d_in[8];
    const float* o_w  = (const float*)d_in[9];
    const float* o_b  = (const float*)d_in[10];
    const float* fc1_w = (const float*)d_in[11];
    const float* fc1_b = (const float*)d_in[12];
    const float* fc2_w = (const float*)d_in[13];
    const float* fc2_b = (const float*)d_in[14];
    const float* out1_w = (const float*)d_in[15];
    const float* out1_b = (const float*)d_in[16];
    const float* out2_w = (const float*)d_in[17];
    const float* out2_b = (const float*)d_in[18];
    const float* ctx_ln_g = (const float*)d_in[19];
    float* out = (float*)d_out;
    u16* ws = (u16*)d_ws;

    swz_all<<<242, 256, 0, stream>>>(q_w, k_w, v_w, o_w, fc1_w, fc2_w, out1_w,
                                     ctx_ln_g, ctx_ln_b, v_b, ws);
    norm_kernel<<<128, 256, 0, stream>>>(feat_map, ws + OFF_NRM);

    fused_kernel<<<1536, 128, 0, stream>>>(
        ws + OFF_NRM, feat_map_up, ws,
        q_b, o_b, fc1_b, fc2_b,
        out1_b, out2_w, out2_b, out);
}

// Round 7
// 407.469 us; speedup vs baseline: 1.8028x; 1.0126x over previous
//
#include <hip/hip_runtime.h>
#include <math.h>

#define C_   128
#define HU_  128
#define WU_  192
#define HD_  64
#define WD_  96
#define HWD_ (HD_ * WD_)

typedef unsigned short u16;
typedef __attribute__((ext_vector_type(8))) short s8v;   // 8 bf16 = 4 VGPRs
typedef __attribute__((ext_vector_type(4))) float f4v;   // MFMA C/D

// ---- workspace layout (u16 units) ----
#define OFF_Q   0        // 2 layers x 16384
#define OFF_K   32768    // Wk' = diag(g)Wk (affine-folded)
#define OFF_V   65536    // Wv' = diag(g)Wv
#define OFF_O   98304
#define OFF_F1  131072   // 2 layers x 65536
#define OFF_F2  262144
#define OFF_XC  393216   // 49152 (out1 Wa+Wc, 128x384)
#define OFF_CC  442368   // 49152 (out1 Wb-Wc, 128x384)
#define OFF_NRM 491520   // normalized ctx bf16: (B,HD,WD,C) = 1572864 u16
#define OFF_VB  2064384  // folded v-bias: b@Wv + vb, 2x128 f32 = 512 u16

#define SLOT 2176        // u16 per LDS tile slot (16 rows x 136)

__device__ __forceinline__ u16 f2bf(float f) {
    unsigned u = __float_as_uint(f);
    unsigned r = (u + 0x7FFFu + ((u >> 16) & 1u)) >> 16;   // RNE
    return (u16)r;
}
__device__ __forceinline__ float bfu(u16 h) { return __uint_as_float(((unsigned)h) << 16); }

__device__ __forceinline__ float gelu_tanh(float x) {
    float u = 1.5957691216057308f * (x + 0.044715f * x * x * x);
    float e = __expf(u);
    float th = 1.0f - 2.0f / (1.0f + e);
    return 0.5f * x * (1.0f + th);
}
__device__ __forceinline__ float fast_erf(float x) {
    float z = fabsf(x);
    float t = 1.0f / (1.0f + 0.3275911f * z);
    float p = t * (0.254829592f + t * (-0.284496736f + t * (1.421413741f +
              t * (-1.453152027f + t * 1.061405429f))));
    float r = 1.0f - p * __expf(-z * z);
    return copysignf(r, x);
}
__device__ __forceinline__ float gelu_erf(float x) {
    return 0.5f * x * (1.0f + fast_erf(x * 0.7071067811865476f));
}

// async global->LDS: each lane stages 16B; LDS dest = base + lane*16 (HW rule)
__device__ __forceinline__ void glds1(const u16* src, u16* dst, int lane) {
    __builtin_amdgcn_global_load_lds(
        (const __attribute__((address_space(1))) void*)(src + (size_t)lane * 8),
        (__attribute__((address_space(3))) void*)dst, 16, 0, 0);
}
// group protocol (4 waves share wlds; each wave stages 2 of a group's 8 chunks):
//  GW*: wait OWN staged chunks, then rendezvous -> all 8 chunks in LDS.
//  BAR: post-consume rendezvous -> nobody still reads buffer being re-staged.
#define GW2() do { asm volatile("s_waitcnt vmcnt(2)" ::: "memory"); __builtin_amdgcn_s_barrier(); } while (0)
#define GW0() do { asm volatile("s_waitcnt vmcnt(0)" ::: "memory"); __builtin_amdgcn_s_barrier(); } while (0)
#define BAR() __builtin_amdgcn_s_barrier()
// wave-local LDS fence (arena is wave-private; no cross-wave barrier, and no
// vmcnt drain -> cross-phase prefetch stays in flight)
#define WFENCE() asm volatile("s_waitcnt lgkmcnt(0)" ::: "memory")

// ---------------- prologue 1: weight swizzles + affine folding ----------------
__global__ __launch_bounds__(256) void swz_all(
    const float* __restrict__ q_w, const float* __restrict__ k_w,
    const float* __restrict__ v_w, const float* __restrict__ o_w,
    const float* __restrict__ f1w, const float* __restrict__ f2w,
    const float* __restrict__ o1w,
    const float* __restrict__ ctx_g, const float* __restrict__ ctx_b,
    const float* __restrict__ vb_in, u16* __restrict__ ws)
{
    int tid = blockIdx.x * 256 + threadIdx.x;
    int f = tid >> 6, lane = tid & 63;
    if (f >= 964) return;
    if (f >= 960) {                 // folded v-bias
        int lf = f - 960;           // 0..3
        int ly = lf >> 1, col = (lf & 1) * 64 + lane;
        float s = vb_in[ly * 128 + col];
        const float* bp = ctx_b + ly * 128;
        const float* wp = v_w + (size_t)ly * 128 * 128 + col;
        for (int c = 0; c < 128; ++c) s += bp[c] * wp[(size_t)c * 128];
        ((float*)(ws + OFF_VB))[ly * 128 + col] = s;
        return;
    }
    int rq = 8 * (lane >> 4), cq = lane & 15;
    const float* src; const float* src2 = nullptr; float sgn = 1.f;
    int NT, N, dstoff, lf;
    bool scale_g = false;
    if (f < 64)       { src = q_w;  NT = 8;  N = 128; dstoff = OFF_Q;  lf = f; }
    else if (f < 128) { src = k_w;  NT = 8;  N = 128; dstoff = OFF_K;  lf = f - 64;  scale_g = true; }
    else if (f < 192) { src = v_w;  NT = 8;  N = 128; dstoff = OFF_V;  lf = f - 128; scale_g = true; }
    else if (f < 256) { src = o_w;  NT = 8;  N = 128; dstoff = OFF_O;  lf = f - 192; }
    else if (f < 512) { src = f1w;  NT = 32; N = 512; dstoff = OFF_F1; lf = f - 256; }
    else if (f < 768) { src = f2w;  NT = 8;  N = 128; dstoff = OFF_F2; lf = f - 512; }
    else if (f < 864) { src = o1w;             src2 = o1w + 256 * 384; sgn =  1.f;
                        NT = 24; N = 384; dstoff = OFF_XC; lf = f - 768; }
    else              { src = o1w + 128 * 384; src2 = o1w + 256 * 384; sgn = -1.f;
                        NT = 24; N = 384; dstoff = OFF_CC; lf = f - 864; }
    int kt = lf / NT, nt = lf - kt * NT;
    int row0 = kt * 32 + rq, col = nt * 16 + cq;
    s8v o;
#pragma unroll
    for (int j = 0; j < 8; ++j) {
        float v = src[(size_t)(row0 + j) * N + col];
        if (src2) v += sgn * src2[(size_t)(row0 + j) * N + col];
        if (scale_g) v *= ctx_g[row0 + j];
        o[j] = (short)f2bf(v);
    }
    *(s8v*)(ws + dstoff + (size_t)lf * 512 + (size_t)lane * 8) = o;
}

// ---------------- prologue 2: per-down-pixel LN of feat_map (eps 1e-5) ----------------
__global__ __launch_bounds__(256) void norm_kernel(const float* __restrict__ fm,
                                                   u16* __restrict__ dst) {
    int row = blockIdx.x;          // b*HD + y
    int b = row >> 6, y = row & 63;
    __shared__ float tile[128 * 97];
    __shared__ float smean[96], srst[96];
    for (int idx = threadIdx.x; idx < 128 * 96; idx += 256) {
        int c = idx / 96, w = idx - c * 96;
        tile[c * 97 + w] = fm[(((size_t)b * 128 + c) * 64 + y) * 96 + w];
    }
    __syncthreads();
    if (threadIdx.x < 96) {
        int w = threadIdx.x;
        float s = 0.f, ss = 0.f;
        for (int c = 0; c < 128; ++c) { float v = tile[c * 97 + w]; s += v; ss += v * v; }
        float mn = s * (1.f / 128.f);
        smean[w] = mn;
        srst[w]  = rsqrtf(ss * (1.f / 128.f) - mn * mn + 1e-5f);
    }
    __syncthreads();
    for (int idx = threadIdx.x; idx < 96 * 16; idx += 256) {
        int w = idx >> 4, cg = idx & 15;
        float mn = smean[w], iv = srst[w];
        s8v o;
#pragma unroll
        for (int j = 0; j < 8; ++j)
            o[j] = (short)f2bf((tile[(8 * cg + j) * 97 + w] - mn) * iv);
        *(s8v*)(dst + ((size_t)row * 96 + w) * 128 + 8 * cg) = o;
    }
}

// ---------------- main fused kernel: 4 waves x 16 pixels, shared weight stream ----------------
// R7: 256-thread blocks, 4 waves share the staged weight dbuf (2 chunks/wave
// per 8KB group, vmcnt(2) waits). s_at folded into arena slot1 @+1024 ->
// block LDS 51200B -> EXACTLY 3 blocks/CU, grid 768 = EXACTLY 3/CU resident:
// zero dispatch tail (R6's 4+2 batching wasted ~17%), 12 waves/CU sustained,
// 3 waves/SIMD from 3 independent blocks. Weight L2 traffic/wave halved again.
// fr[mh=1] reload moved g==4 -> g==2 (avoids compiler-forced vmcnt(0) drain).
__global__ __launch_bounds__(256, 2) void fused_kernel(
    const u16*  __restrict__ nrmb, const float* __restrict__ fmu,
    const u16*  __restrict__ wsb,
    const float* __restrict__ qb, const float* __restrict__ ob,
    const float* __restrict__ f1b, const float* __restrict__ f2b,
    const float* __restrict__ o1b, const float* __restrict__ o2w,
    const float* __restrict__ o2b,
    float* __restrict__ out)
{
    const int tid  = threadIdx.x;
    const int wid  = tid >> 6;
    const int lane = tid & 63;
    const int cidx = lane & 15, quad = lane >> 4;
    const int n0 = blockIdx.x * 64 + wid * 16;
    const int b  = n0 / (HU_ * WU_);
    const int rem = n0 - b * (HU_ * WU_);
    const int hu  = rem / WU_;
    const int wu0 = rem - hu * WU_;

    __shared__ __align__(16) u16 wlds[2][4096];       // 16KB shared weight dbuf
    __shared__ __align__(16) u16 arena2[4][2 * SLOT]; // per-wave slots (8704B each)
    u16*   const arena = arena2[wid];
    // s_at aliases slot1 @ +1024 u16: head hx staging ends at +887; FFN acts
    // and s_at are never simultaneously live.
    float* const s_at  = (float*)(arena + SLOT + 1024);
    float* const s_rs  = s_at;

    const float* vbp = (const float*)(wsb + OFF_VB);

    float xacc[8][4];
#pragma unroll
    for (int nt = 0; nt < 8; ++nt) {
        int ch = 16 * nt + cidx;
        float4 v = *(const float4*)(fmu + ((size_t)(b * C_ + ch) * HU_ + hu) * WU_ + wu0 + 4 * quad);
        xacc[nt][0] = v.x; xacc[nt][1] = v.y; xacc[nt][2] = v.z; xacc[nt][3] = v.w;
    }

    const float slopes[4] = {0.451801007f, 0.204124145f, 0.092223264f, 0.041666668f};
    const int ry0 = min(hu >> 1, HD_ - 1);
    const int ry1 = min((hu >> 1) + 1, HD_ - 1);
    const float dyv0 = -(float)abs(hu - 2 * ry0);
    const float dyv1 = -(float)abs(hu - 2 * ry1);

    const int k2l = cidx & 3;
    const int ryl = (k2l >> 1) ? ry1 : ry0;
    int cbase[4];
#pragma unroll
    for (int mt = 0; mt < 4; ++mt) {
        int p = 4 * mt + (cidx >> 2);
        int rxv = min(((wu0 + p) >> 1) + (k2l & 1), WD_ - 1);
        cbase[mt] = ((b * HD_ + ryl) * WD_ + rxv) * 128;
    }

#pragma unroll 1
    for (int ly = 0; ly < 2; ++ly) {
        const u16* Wq = wsb + OFF_Q  + ly * 16384;
        const u16* Wk = wsb + OFF_K  + ly * 16384;
        const u16* Wv = wsb + OFF_V  + ly * 16384;
        const u16* Wo = wsb + OFF_O  + ly * 16384;
        const u16* W1 = wsb + OFF_F1 + ly * 65536;
        const u16* W2 = wsb + OFF_F2 + ly * 65536;

        s8v fr[4][2];

        // early-issue q groups 0,1 (own 2 chunks each; cover: LN)
#pragma unroll
        for (int jl = 0; jl < 2; ++jl) {
            int j = 2 * wid + jl;
            glds1(Wq + (size_t)j * 512, &wlds[0][j * 512], lane);
        }
#pragma unroll
        for (int jl = 0; jl < 2; ++jl) {
            int j = 2 * wid + jl;
            glds1(Wq + (size_t)(8 + j) * 512, &wlds[1][j * 512], lane);
        }

        // ---- xn = LN(x,1e-6) -> slot0 ----
        {
            float mo[4], io[4];
#pragma unroll
            for (int r = 0; r < 4; ++r) {
                float s = 0.f, ss = 0.f;
#pragma unroll
                for (int nt = 0; nt < 8; ++nt) { float v = xacc[nt][r]; s += v; ss += v * v; }
#pragma unroll
                for (int m = 1; m <= 8; m <<= 1) { s += __shfl_xor(s, m, 64); ss += __shfl_xor(ss, m, 64); }
                float mn = s * (1.f / 128.f);
                mo[r] = mn; io[r] = rsqrtf(ss * (1.f / 128.f) - mn * mn + 1e-6f);
            }
#pragma unroll
            for (int nt = 0; nt < 8; ++nt)
#pragma unroll
                for (int r = 0; r < 4; ++r)
                    arena[(4 * quad + r) * 136 + 16 * nt + cidx] =
                        f2bf((xacc[nt][r] - mo[r]) * io[r]);
        }
        WFENCE();
        s8v a_xn[4];
#pragma unroll
        for (int kt = 0; kt < 4; ++kt)
            a_xn[kt] = *(const s8v*)(arena + cidx * 136 + kt * 32 + 8 * quad);

        // ---- q GEMM (streamed; group g = kt) ----
        {
            f4v qa[8];
#pragma unroll
            for (int nt = 0; nt < 8; ++nt) {
                float bvv = qb[ly * C_ + 16 * nt + cidx];
                f4v t = {bvv, bvv, bvv, bvv}; qa[nt] = t;
            }
#pragma unroll
            for (int g = 0; g < 4; ++g) {
                if (g < 3) { GW2(); } else { GW0(); }
#pragma unroll
                for (int nt = 0; nt < 8; ++nt) {
                    s8v w = *(const s8v*)&wlds[g & 1][nt * 512 + lane * 8];
                    qa[nt] = __builtin_amdgcn_mfma_f32_16x16x32_bf16(a_xn[g], w, qa[nt], 0, 0, 0);
                }
                BAR();
                if (g < 2) {
#pragma unroll
                    for (int jl = 0; jl < 2; ++jl) {
                        int j = 2 * wid + jl;
                        glds1(Wq + (size_t)((g + 2) * 8 + j) * 512, &wlds[g & 1][j * 512], lane);
                    }
                }
            }
#pragma unroll
            for (int kt = 0; kt < 4; ++kt)
#pragma unroll
                for (int i = 0; i < 2; ++i)
                    fr[kt][i] = *(const s8v*)(nrmb + cbase[i] + kt * 32 + 8 * quad);
#pragma unroll
            for (int jl = 0; jl < 2; ++jl) {
                int j = 2 * wid + jl;
                glds1(Wk + (size_t)(((j & 3) * 8) + (j >> 2)) * 512, &wlds[0][j * 512], lane);
            }
#pragma unroll
            for (int jl = 0; jl < 2; ++jl) {
                int j = 2 * wid + jl;
                int jc = 8 + j;
                glds1(Wk + (size_t)(((jc & 3) * 8) + (jc >> 2)) * 512, &wlds[1][j * 512], lane);
            }
#pragma unroll
            for (int nt = 0; nt < 8; ++nt)
#pragma unroll
                for (int r = 0; r < 4; ++r)
                    arena[(4 * quad + r) * 136 + 16 * nt + cidx] = f2bf(qa[nt][r]);
        }
        WFENCE();

        // ---- k GEMM + fused raw scores (streamed; mh=g>>2, h=g&3) ----
#pragma unroll
        for (int g = 0; g < 8; ++g) {
            if (g < 7) { GW2(); } else { GW0(); }
            const int mh = g >> 2, h = g & 3;
            float part[2][4];
#pragma unroll
            for (int i = 0; i < 2; ++i)
#pragma unroll
                for (int r = 0; r < 4; ++r) part[i][r] = 0.f;
#pragma unroll
            for (int ntp = 0; ntp < 2; ++ntp) {
                const int nt = 2 * h + ntp;
                f4v ka[2];
#pragma unroll
                for (int i = 0; i < 2; ++i) { f4v t = {0.f, 0.f, 0.f, 0.f}; ka[i] = t; }
#pragma unroll
                for (int kt = 0; kt < 4; ++kt) {
                    s8v w = *(const s8v*)&wlds[g & 1][(ntp * 4 + kt) * 512 + lane * 8];
                    ka[0] = __builtin_amdgcn_mfma_f32_16x16x32_bf16(fr[kt][0], w, ka[0], 0, 0, 0);
                    ka[1] = __builtin_amdgcn_mfma_f32_16x16x32_bf16(fr[kt][1], w, ka[1], 0, 0, 0);
                }
#pragma unroll
                for (int i = 0; i < 2; ++i) {
                    float qv = bfu(arena[(4 * (2 * mh + i) + quad) * 136 + 16 * nt + cidx]);
#pragma unroll
                    for (int r = 0; r < 4; ++r) part[i][r] = fmaf(qv, ka[i][r], part[i][r]);
                }
            }
#pragma unroll
            for (int i = 0; i < 2; ++i)
#pragma unroll
                for (int r = 0; r < 4; ++r) {
#pragma unroll
                    for (int m = 1; m <= 8; m <<= 1) part[i][r] += __shfl_xor(part[i][r], m, 64);
                }
            if (cidx == 0) {
#pragma unroll
                for (int i = 0; i < 2; ++i) {
                    float4 t = {part[i][0], part[i][1], part[i][2], part[i][3]};
                    *(float4*)&s_at[(4 * (2 * mh + i) + quad) * 16 + 4 * h] = t;
                }
            }
            BAR();
            if (g == 2) {   // mh=1 fragments: issued early so g==3's vmcnt(2) drains them
#pragma unroll
                for (int kt = 0; kt < 4; ++kt)
#pragma unroll
                    for (int i = 0; i < 2; ++i)
                        fr[kt][i] = *(const s8v*)(nrmb + cbase[2 + i] + kt * 32 + 8 * quad);
            }
            if (g < 6) {
                const int gn = g + 2;
#pragma unroll
                for (int jl = 0; jl < 2; ++jl) {
                    int j = 2 * wid + jl;
                    int jc = 8 * (gn & 3) + j;
                    glds1(Wk + (size_t)(((jc & 3) * 8) + (jc >> 2)) * 512, &wlds[g & 1][j * 512], lane);
                }
            }
        }
#pragma unroll
        for (int kt = 0; kt < 4; ++kt)
#pragma unroll
            for (int i = 0; i < 2; ++i)
                fr[kt][i] = *(const s8v*)(nrmb + cbase[i] + kt * 32 + 8 * quad);
#pragma unroll
        for (int jl = 0; jl < 2; ++jl) {
            int j = 2 * wid + jl;
            glds1(Wv + (size_t)(((j & 3) * 8) + (j >> 2)) * 512, &wlds[0][j * 512], lane);
        }
#pragma unroll
        for (int jl = 0; jl < 2; ++jl) {
            int j = 2 * wid + jl;
            glds1(Wv + (size_t)(((j & 3) * 8) + 2 + (j >> 2)) * 512, &wlds[1][j * 512], lane);
        }
        WFENCE();

        // ---- softmax in place (wave-private s_at) ----
        {
            int p = lane >> 2, h = lane & 3;
            float4 sc = *(float4*)&s_at[p * 16 + 4 * h];
            int pw = wu0 + p;
            float sim[4] = {sc.x, sc.y, sc.z, sc.w};
#pragma unroll
            for (int r = 0; r < 4; ++r) {
                int rxv = min((pw >> 1) + (r & 1), WD_ - 1);
                float cd = ((r >> 1) ? dyv1 : dyv0) - (float)abs(pw - 2 * rxv);
                sim[r] = sim[r] * 0.17677669529663687f + slopes[h] * cd;
            }
            float mx = fmaxf(fmaxf(sim[0], sim[1]), fmaxf(sim[2], sim[3]));
            float e0 = __expf(sim[0] - mx), e1 = __expf(sim[1] - mx);
            float e2 = __expf(sim[2] - mx), e3 = __expf(sim[3] - mx);
            float si = 1.f / (e0 + e1 + e2 + e3);
            float4 at = {e0 * si, e1 * si, e2 * si, e3 * si};
            *(float4*)&s_at[p * 16 + 4 * h] = at;
        }
        WFENCE();

        // ---- v GEMM + fused o = attn@v -> oT slot0 (streamed) ----
#pragma unroll
        for (int g = 0; g < 8; ++g) {
            if (g < 7) { GW2(); } else { GW0(); }
            const int mh = g >> 2, gp = g & 3;
#pragma unroll
            for (int ntp = 0; ntp < 2; ++ntp) {
                const int nt = 2 * gp + ntp;
                float vbb = vbp[ly * C_ + 16 * nt + cidx];
                f4v va[2];
#pragma unroll
                for (int i = 0; i < 2; ++i) { f4v t = {vbb, vbb, vbb, vbb}; va[i] = t; }
#pragma unroll
                for (int kt = 0; kt < 4; ++kt) {
                    s8v w = *(const s8v*)&wlds[g & 1][(ntp * 4 + kt) * 512 + lane * 8];
                    va[0] = __builtin_amdgcn_mfma_f32_16x16x32_bf16(fr[kt][0], w, va[0], 0, 0, 0);
                    va[1] = __builtin_amdgcn_mfma_f32_16x16x32_bf16(fr[kt][1], w, va[1], 0, 0, 0);
                }
                const int h = nt >> 1;
#pragma unroll
                for (int i = 0; i < 2; ++i) {
                    const int mt = 2 * mh + i;
                    float4 at = *(float4*)&s_at[(4 * mt + quad) * 16 + 4 * h];
                    float ov = at.x * va[i][0] + at.y * va[i][1] + at.z * va[i][2] + at.w * va[i][3];
                    arena[(4 * mt + quad) * 136 + 16 * nt + cidx] = f2bf(ov);
                }
            }
            BAR();
            if (g == 2) {   // mh=1 fragments, early
#pragma unroll
                for (int kt = 0; kt < 4; ++kt)
#pragma unroll
                    for (int i = 0; i < 2; ++i)
                        fr[kt][i] = *(const s8v*)(nrmb + cbase[2 + i] + kt * 32 + 8 * quad);
            }
            if (g < 6) {
                const int gq = (g + 2) & 3;
#pragma unroll
                for (int jl = 0; jl < 2; ++jl) {
                    int j = 2 * wid + jl;
                    glds1(Wv + (size_t)(((j & 3) * 8) + 2 * gq + (j >> 2)) * 512, &wlds[g & 1][j * 512], lane);
                }
            }
        }
#pragma unroll
        for (int jl = 0; jl < 2; ++jl) {
            int j = 2 * wid + jl;
            glds1(Wo + (size_t)j * 512, &wlds[0][j * 512], lane);
        }
#pragma unroll
        for (int jl = 0; jl < 2; ++jl) {
            int j = 2 * wid + jl;
            glds1(Wo + (size_t)(8 + j) * 512, &wlds[1][j * 512], lane);
        }
        WFENCE();

        // ---- x += o @ Wo + ob (streamed) ----
        {
            s8v a_o[4];
#pragma unroll
            for (int kt = 0; kt < 4; ++kt)
                a_o[kt] = *(const s8v*)(arena + cidx * 136 + kt * 32 + 8 * quad);
            f4v oa[8];
#pragma unroll
            for (int nt = 0; nt < 8; ++nt) {
                float bvv = ob[ly * C_ + 16 * nt + cidx];
                f4v t = {bvv, bvv, bvv, bvv}; oa[nt] = t;
            }
#pragma unroll
            for (int g = 0; g < 4; ++g) {
                if (g < 3) { GW2(); } else { GW0(); }
#pragma unroll
                for (int nt = 0; nt < 8; ++nt) {
                    s8v w = *(const s8v*)&wlds[g & 1][nt * 512 + lane * 8];
                    oa[nt] = __builtin_amdgcn_mfma_f32_16x16x32_bf16(a_o[g], w, oa[nt], 0, 0, 0);
                }
                BAR();
                if (g < 2) {
#pragma unroll
                    for (int jl = 0; jl < 2; ++jl) {
                        int j = 2 * wid + jl;
                        glds1(Wo + (size_t)((g + 2) * 8 + j) * 512, &wlds[g & 1][j * 512], lane);
                    }
                }
            }
#pragma unroll
            for (int jl = 0; jl < 2; ++jl) {
                int j = 2 * wid + jl;
                glds1(W1 + (size_t)j * 512, &wlds[0][j * 512], lane);
            }
#pragma unroll
            for (int jl = 0; jl < 2; ++jl) {
                int j = 2 * wid + jl;
                glds1(W1 + (size_t)(32 + j) * 512, &wlds[1][j * 512], lane);
            }
#pragma unroll
            for (int nt = 0; nt < 8; ++nt)
#pragma unroll
                for (int r = 0; r < 4; ++r) xacc[nt][r] += oa[nt][r];
        }

        // ---- hn = LN(x,1e-6) -> slot0 ----
        {
            float mo[4], io[4];
#pragma unroll
            for (int r = 0; r < 4; ++r) {
                float s = 0.f, ss = 0.f;
#pragma unroll
                for (int nt = 0; nt < 8; ++nt) { float v = xacc[nt][r]; s += v; ss += v * v; }
#pragma unroll
                for (int m = 1; m <= 8; m <<= 1) { s += __shfl_xor(s, m, 64); ss += __shfl_xor(ss, m, 64); }
                float mn = s * (1.f / 128.f);
                mo[r] = mn; io[r] = rsqrtf(ss * (1.f / 128.f) - mn * mn + 1e-6f);
            }
#pragma unroll
            for (int nt = 0; nt < 8; ++nt)
#pragma unroll
                for (int r = 0; r < 4; ++r)
                    arena[(4 * quad + r) * 136 + 16 * nt + cidx] =
                        f2bf((xacc[nt][r] - mo[r]) * io[r]);
        }
        WFENCE();
        s8v a_hn[4];
#pragma unroll
        for (int kt = 0; kt < 4; ++kt)
            a_hn[kt] = *(const s8v*)(arena + cidx * 136 + kt * 32 + 8 * quad);

        // ---- ffn: 4 chunks of 128 cols, both GEMMs streamed ----
        {
            f4v ga[8];
#pragma unroll
            for (int nt = 0; nt < 8; ++nt) {
                float bvv = f2b[ly * C_ + 16 * nt + cidx];
                f4v t = {bvv, bvv, bvv, bvv}; ga[nt] = t;
            }
#pragma unroll 1
            for (int c = 0; c < 4; ++c) {
                f4v fa[8];
#pragma unroll
                for (int nt = 0; nt < 8; ++nt) {
                    float bvv = f1b[ly * 512 + 128 * c + 16 * nt + cidx];
                    f4v t = {bvv, bvv, bvv, bvv}; fa[nt] = t;
                }
#pragma unroll
                for (int g = 0; g < 4; ++g) {
                    if (g < 3) { GW2(); } else { GW0(); }
#pragma unroll
                    for (int nt = 0; nt < 8; ++nt) {
                        s8v w = *(const s8v*)&wlds[g & 1][nt * 512 + lane * 8];
                        fa[nt] = __builtin_amdgcn_mfma_f32_16x16x32_bf16(a_hn[g], w, fa[nt], 0, 0, 0);
                    }
                    BAR();
                    if (g < 2) {
#pragma unroll
                        for (int jl = 0; jl < 2; ++jl) {
                            int j = 2 * wid + jl;
                            glds1(W1 + (size_t)((g + 2) * 32 + 8 * c + j) * 512, &wlds[g & 1][j * 512], lane);
                        }
                    }
                }
#pragma unroll
                for (int jl = 0; jl < 2; ++jl) {
                    int j = 2 * wid + jl;
                    glds1(W2 + (size_t)(32 * c + j) * 512, &wlds[0][j * 512], lane);
                }
#pragma unroll
                for (int jl = 0; jl < 2; ++jl) {
                    int j = 2 * wid + jl;
                    glds1(W2 + (size_t)(32 * c + 8 + j) * 512, &wlds[1][j * 512], lane);
                }
#pragma unroll
                for (int nt = 0; nt < 8; ++nt)
#pragma unroll
                    for (int r = 0; r < 4; ++r)
                        arena[SLOT + (4 * quad + r) * 136 + 16 * nt + cidx] =
                            f2bf(gelu_tanh(fa[nt][r]));
                WFENCE();
#pragma unroll
                for (int g = 0; g < 4; ++g) {
                    if (g < 3) { GW2(); } else { GW0(); }
                    s8v a = *(const s8v*)(arena + SLOT + cidx * 136 + g * 32 + 8 * quad);
#pragma unroll
                    for (int nt = 0; nt < 8; ++nt) {
                        s8v w = *(const s8v*)&wlds[g & 1][nt * 512 + lane * 8];
                        ga[nt] = __builtin_amdgcn_mfma_f32_16x16x32_bf16(a, w, ga[nt], 0, 0, 0);
                    }
                    BAR();
                    if (g < 2) {
#pragma unroll
                        for (int jl = 0; jl < 2; ++jl) {
                            int j = 2 * wid + jl;
                            glds1(W2 + (size_t)(32 * c + (g + 2) * 8 + j) * 512, &wlds[g & 1][j * 512], lane);
                        }
                    }
                }
                if (c < 3) {
#pragma unroll
                    for (int jl = 0; jl < 2; ++jl) {
                        int j = 2 * wid + jl;
                        glds1(W1 + (size_t)(8 * (c + 1) + j) * 512, &wlds[0][j * 512], lane);
                    }
#pragma unroll
                    for (int jl = 0; jl < 2; ++jl) {
                        int j = 2 * wid + jl;
                        glds1(W1 + (size_t)(32 + 8 * (c + 1) + j) * 512, &wlds[1][j * 512], lane);
                    }
                }
            }
#pragma unroll
            for (int nt = 0; nt < 8; ++nt)
#pragma unroll
                for (int r = 0; r < 4; ++r) xacc[nt][r] += ga[nt][r];
        }
    } // layer loop

    // ================= head =================
    // XC staging: wave w owns 3 chunks (j = 3w..3w+2); waves 0,1 -> buf0
    // (kt 0,1), waves 2,3 -> buf1 (kt 2,3). Divergent-but-wave-uniform waits.
    const u16* Wxc = wsb + OFF_XC;
    const u16* Wcc = wsb + OFF_CC;
#pragma unroll
    for (int jl = 0; jl < 3; ++jl) {
        int j = 3 * wid + jl;
        glds1(Wxc + (size_t)((j / 3) * 24 + (j % 3)) * 512, &wlds[j / 6][(j % 6) * 512], lane);
    }
    {
        float mo[4], io[4];
#pragma unroll
        for (int r = 0; r < 4; ++r) {
            float s = 0.f, ss = 0.f;
#pragma unroll
            for (int nt = 0; nt < 8; ++nt) { float v = xacc[nt][r]; s += v; ss += v * v; }
#pragma unroll
            for (int m = 1; m <= 8; m <<= 1) { s += __shfl_xor(s, m, 64); ss += __shfl_xor(ss, m, 64); }
            float mn = s * (1.f / 128.f);
            mo[r] = mn; io[r] = rsqrtf(ss * (1.f / 128.f) - mn * mn + 1e-6f);
        }
#pragma unroll
        for (int nt = 0; nt < 8; ++nt)
#pragma unroll
            for (int r = 0; r < 4; ++r)
                arena[(4 * quad + r) * 136 + 16 * nt + cidx] =
                    f2bf((xacc[nt][r] - mo[r]) * io[r]);
    }
    WFENCE();
    s8v a_xf[4];
#pragma unroll
    for (int kt = 0; kt < 4; ++kt)
        a_xf[kt] = *(const s8v*)(arena + cidx * 136 + kt * 32 + 8 * quad);

    float part[4][4];
#pragma unroll
    for (int mt = 0; mt < 4; ++mt)
#pragma unroll
        for (int r = 0; r < 4; ++r) part[mt][r] = 0.f;

#pragma unroll 1
    for (int it = 0; it < 8; ++it) {
        const int nbase = 6 * (it >> 1) + 3 * (it & 1);
        {
            f4v hx[3];
#pragma unroll
            for (int ntl = 0; ntl < 3; ++ntl) {
                float hb = o1b[16 * (nbase + ntl) + cidx];
                f4v t = {hb, hb, hb, hb}; hx[ntl] = t;
            }
            // half0 (buf0, kt 0-1): owners are waves 0,1
            if (wid < 2) { asm volatile("s_waitcnt vmcnt(0)" ::: "memory"); }
            BAR();
#pragma unroll
            for (int kt = 0; kt < 2; ++kt)
#pragma unroll
                for (int ntl = 0; ntl < 3; ++ntl) {
                    s8v w = *(const s8v*)&wlds[0][(kt * 3 + ntl) * 512 + lane * 8];
                    hx[ntl] = __builtin_amdgcn_mfma_f32_16x16x32_bf16(a_xf[kt], w, hx[ntl], 0, 0, 0);
                }
            // half1 (buf1, kt 2-3): owners are waves 2,3
            if (wid >= 2) { asm volatile("s_waitcnt vmcnt(0)" ::: "memory"); }
            BAR();
#pragma unroll
            for (int kt = 2; kt < 4; ++kt)
#pragma unroll
                for (int ntl = 0; ntl < 3; ++ntl) {
                    s8v w = *(const s8v*)&wlds[1][((kt - 2) * 3 + ntl) * 512 + lane * 8];
                    hx[ntl] = __builtin_amdgcn_mfma_f32_16x16x32_bf16(a_xf[kt], w, hx[ntl], 0, 0, 0);
                }
            BAR();
            if (it < 7) {
                const int nb2 = 6 * ((it + 1) >> 1) + 3 * ((it + 1) & 1);
#pragma unroll
                for (int jl = 0; jl < 3; ++jl) {
                    int j = 3 * wid + jl;
                    glds1(Wxc + (size_t)((j / 3) * 24 + nb2 + (j % 3)) * 512, &wlds[j / 6][(j % 6) * 512], lane);
                }
            }
#pragma unroll
            for (int ntl = 0; ntl < 3; ++ntl)
#pragma unroll
                for (int r = 0; r < 4; ++r)
                    arena[SLOT + (4 * quad + r) * 56 + 16 * ntl + cidx] = f2bf(hx[ntl][r]);
        }
        WFENCE();

        f4v hc[3][4];
#pragma unroll
        for (int ntl = 0; ntl < 3; ++ntl)
#pragma unroll
            for (int mt = 0; mt < 4; ++mt) { f4v t = {0.f, 0.f, 0.f, 0.f}; hc[ntl][mt] = t; }
#pragma unroll 1
        for (int kt = 0; kt < 4; ++kt) {
            s8v frh[4];
#pragma unroll
            for (int mt = 0; mt < 4; ++mt)
                frh[mt] = *(const s8v*)(nrmb + cbase[mt] + kt * 32 + 8 * quad);
#pragma unroll
            for (int ntl = 0; ntl < 3; ++ntl) {
                s8v w = *(const s8v*)(Wcc + ((size_t)((kt * 24 + nbase + ntl) * 64 + lane)) * 8);
#pragma unroll
                for (int mt = 0; mt < 4; ++mt)
                    hc[ntl][mt] = __builtin_amdgcn_mfma_f32_16x16x32_bf16(frh[mt], w, hc[ntl][mt], 0, 0, 0);
            }
        }

#pragma unroll
        for (int ntl = 0; ntl < 3; ++ntl) {
            float w2v = o2w[16 * (nbase + ntl) + cidx];
#pragma unroll
            for (int mt = 0; mt < 4; ++mt)
#pragma unroll
                for (int r = 0; r < 4; ++r) {
                    float h1 = hc[ntl][mt][r] +
                               bfu(arena[SLOT + (4 * mt + quad) * 56 + 16 * ntl + cidx]);
                    part[mt][r] = fmaf(gelu_erf(h1), w2v, part[mt][r]);
                }
        }
        WFENCE();
    }

#pragma unroll
    for (int mt = 0; mt < 4; ++mt)
#pragma unroll
        for (int r = 0; r < 4; ++r) {
#pragma unroll
            for (int m = 1; m <= 8; m <<= 1) part[mt][r] += __shfl_xor(part[mt][r], m, 64);
            part[mt][r] += o2b[0];
        }
    if (cidx == 0) {
#pragma unroll
        for (int mt = 0; mt < 4; ++mt) {
            float4 t = {part[mt][0], part[mt][1], part[mt][2], part[mt][3]};
            *(float4*)&s_rs[(4 * mt + quad) * 4] = t;
        }
    }
    WFENCE();

    if (lane < 16) {
        int p = lane;
        float4 vv = *(float4*)&s_rs[4 * p];
        float mx = fmaxf(fmaxf(vv.x, vv.y), fmaxf(vv.z, vv.w));
        float e0 = __expf(vv.x - mx), e1 = __expf(vv.y - mx);
        float e2 = __expf(vv.z - mx), e3 = __expf(vv.w - mx);
        float si = 1.f / (e0 + e1 + e2 + e3);
        size_t base = ((size_t)(b * 4) * HU_ + hu) * WU_ + wu0 + p;
        out[base]                          = e0 * si;
        out[base + (size_t)HU_ * WU_]      = e1 * si;
        out[base + (size_t)2 * HU_ * WU_]  = e2 * si;
        out[base + (size_t)3 * HU_ * WU_]  = e3 * si;
    }
}

extern "C" void kernel_launch(void* const* d_in, const int* in_sizes, int n_in,
                              void* d_out, int out_size, void* d_ws, size_t ws_size,
                              hipStream_t stream) {
    const float* feat_map    = (const float*)d_in[0];
    const float* feat_map_up = (const float*)d_in[1];
    const float* ctx_ln_b    = (const float*)d_in[2];
    const float* q_w  = (const float*)d_in[3];
    const float* q_b  = (const float*)d_in[4];
    const float* k_w  = (const float*)d_in[5];
    const float* v_w  = (const float*)d_in[7];
    const float* v_b  = (const float*)d_in[8];
    const float* o_w  = (const float*)d_in[9];
    const float* o_b  = (const float*)d_in[10];
    const float* fc1_w = (const float*)d_in[11];
    const float* fc1_b = (const float*)d_in[12];
    const float* fc2_w = (const float*)d_in[13];
    const float* fc2_b = (const float*)d_in[14];
    const float* out1_w = (const float*)d_in[15];
    const float* out1_b = (const float*)d_in[16];
    const float* out2_w = (const float*)d_in[17];
    const float* out2_b = (const float*)d_in[18];
    const float* ctx_ln_g = (const float*)d_in[19];
    float* out = (float*)d_out;
    u16* ws = (u16*)d_ws;

    swz_all<<<242, 256, 0, stream>>>(q_w, k_w, v_w, o_w, fc1_w, fc2_w, out1_w,
                                     ctx_ln_g, ctx_ln_b, v_b, ws);
    norm_kernel<<<128, 256, 0, stream>>>(feat_map, ws + OFF_NRM);

    fused_kernel<<<768, 256, 0, stream>>>(
        ws + OFF_NRM, feat_map_up, ws,
        q_b, o_b, fc1_b, fc2_b,
        out1_b, out2_w, out2_b, out);
}

// Round 8
// 390.121 us; speedup vs baseline: 1.8830x; 1.0445x over previous
//
#include <hip/hip_runtime.h>
#include <math.h>

#define C_   128
#define HU_  128
#define WU_  192
#define HD_  64
#define WD_  96
#define HWD_ (HD_ * WD_)

typedef unsigned short u16;
typedef __attribute__((ext_vector_type(8))) short s8v;   // 8 bf16 = 4 VGPRs
typedef __attribute__((ext_vector_type(4))) float f4v;   // MFMA C/D

// ---- workspace layout (u16 units) ----
#define OFF_Q   0        // 2 layers x 16384
#define OFF_K   32768    // Wk' = diag(g)Wk (affine-folded)
#define OFF_V   65536    // Wv' = diag(g)Wv
#define OFF_O   98304
#define OFF_F1  131072   // 2 layers x 65536
#define OFF_F2  262144
#define OFF_XC  393216   // 49152 (out1 Wa+Wc, 128x384)
#define OFF_CC  442368   // 49152 (out1 Wb-Wc, 128x384)
#define OFF_NRM 491520   // normalized ctx bf16: (B,HD,WD,C) = 1572864 u16
#define OFF_VB  2064384  // folded v-bias: b@Wv + vb, 2x128 f32 = 512 u16

#define SLOT 2176        // u16 per LDS tile slot (16 rows x 136)

__device__ __forceinline__ u16 f2bf(float f) {
    unsigned u = __float_as_uint(f);
    unsigned r = (u + 0x7FFFu + ((u >> 16) & 1u)) >> 16;   // RNE
    return (u16)r;
}
__device__ __forceinline__ float bfu(u16 h) { return __uint_as_float(((unsigned)h) << 16); }

// paired f32->bf16 via HW packed convert (RNE, bit-identical to f2bf for
// normal values). 1 VALU + 1 shift per pair vs 8 VALU for 2x manual f2bf.
__device__ __forceinline__ void st2bf(u16* p0, u16* p1, float a, float b) {
    unsigned r;
    asm("v_cvt_pk_bf16_f32 %0, %1, %2" : "=v"(r) : "v"(a), "v"(b));
    *p0 = (u16)r;
    *p1 = (u16)(r >> 16);
}

__device__ __forceinline__ float gelu_tanh(float x) {
    float u = 1.5957691216057308f * (x + 0.044715f * x * x * x);
    float e = __expf(u);
    float th = 1.0f - 2.0f / (1.0f + e);
    return 0.5f * x * (1.0f + th);
}
__device__ __forceinline__ float fast_erf(float x) {
    float z = fabsf(x);
    float t = 1.0f / (1.0f + 0.3275911f * z);
    float p = t * (0.254829592f + t * (-0.284496736f + t * (1.421413741f +
              t * (-1.453152027f + t * 1.061405429f))));
    float r = 1.0f - p * __expf(-z * z);
    return copysignf(r, x);
}
__device__ __forceinline__ float gelu_erf(float x) {
    return 0.5f * x * (1.0f + fast_erf(x * 0.7071067811865476f));
}

// async global->LDS: each lane stages 16B; LDS dest = base + lane*16 (HW rule)
__device__ __forceinline__ void glds1(const u16* src, u16* dst, int lane) {
    __builtin_amdgcn_global_load_lds(
        (const __attribute__((address_space(1))) void*)(src + (size_t)lane * 8),
        (__attribute__((address_space(3))) void*)dst, 16, 0, 0);
}
// group protocol (4 waves share wlds; each wave stages 2 of a group's 8 chunks):
//  GW*: wait OWN staged chunks, then rendezvous -> all 8 chunks in LDS.
//  BAR: post-consume rendezvous -> nobody still reads buffer being re-staged.
#define GW2() do { asm volatile("s_waitcnt vmcnt(2)" ::: "memory"); __builtin_amdgcn_s_barrier(); } while (0)
#define GW0() do { asm volatile("s_waitcnt vmcnt(0)" ::: "memory"); __builtin_amdgcn_s_barrier(); } while (0)
#define BAR() __builtin_amdgcn_s_barrier()
// wave-local LDS fence (arena is wave-private; no cross-wave barrier, and no
// vmcnt drain -> cross-phase prefetch stays in flight)
#define WFENCE() asm volatile("s_waitcnt lgkmcnt(0)" ::: "memory")

// ---------------- merged prologue: weight swizzles + affine fold + ctx LN ----------------
// blocks 0..241: weight swizzle frames (4 frames x 64 lanes per block);
// blocks 242..369: per-down-pixel LN of feat_map (eps 1e-5).
// Merging saves one launch and runs the two halves concurrently.
__global__ __launch_bounds__(256) void prologue_all(
    const float* __restrict__ q_w, const float* __restrict__ k_w,
    const float* __restrict__ v_w, const float* __restrict__ o_w,
    const float* __restrict__ f1w, const float* __restrict__ f2w,
    const float* __restrict__ o1w,
    const float* __restrict__ ctx_g, const float* __restrict__ ctx_b,
    const float* __restrict__ vb_in, const float* __restrict__ fm,
    u16* __restrict__ ws)
{
    if (blockIdx.x >= 242) {
        // ---- ctx LN path ----
        int row = blockIdx.x - 242;    // b*HD + y
        int b = row >> 6, y = row & 63;
        __shared__ float tile[128 * 97];
        __shared__ float smean[96], srst[96];
        u16* dst = ws + OFF_NRM;
        for (int idx = threadIdx.x; idx < 128 * 96; idx += 256) {
            int c = idx / 96, w = idx - c * 96;
            tile[c * 97 + w] = fm[(((size_t)b * 128 + c) * 64 + y) * 96 + w];
        }
        __syncthreads();
        if (threadIdx.x < 96) {
            int w = threadIdx.x;
            float s = 0.f, ss = 0.f;
            for (int c = 0; c < 128; ++c) { float v = tile[c * 97 + w]; s += v; ss += v * v; }
            float mn = s * (1.f / 128.f);
            smean[w] = mn;
            srst[w]  = rsqrtf(ss * (1.f / 128.f) - mn * mn + 1e-5f);
        }
        __syncthreads();
        for (int idx = threadIdx.x; idx < 96 * 16; idx += 256) {
            int w = idx >> 4, cg = idx & 15;
            float mn = smean[w], iv = srst[w];
            s8v o;
#pragma unroll
            for (int j = 0; j < 8; ++j)
                o[j] = (short)f2bf((tile[(8 * cg + j) * 97 + w] - mn) * iv);
            *(s8v*)(dst + ((size_t)row * 96 + w) * 128 + 8 * cg) = o;
        }
        return;
    }

    // ---- weight swizzle path ----
    int tid = blockIdx.x * 256 + threadIdx.x;
    int f = tid >> 6, lane = tid & 63;
    if (f >= 964) return;
    if (f >= 960) {                 // folded v-bias: vb' = b@Wv + vb
        int lf = f - 960;           // 0..3
        int ly = lf >> 1, col = (lf & 1) * 64 + lane;
        float s = vb_in[ly * 128 + col];
        const float* bp = ctx_b + ly * 128;
        const float* wp = v_w + (size_t)ly * 128 * 128 + col;
#pragma unroll 8
        for (int c = 0; c < 128; ++c) s += bp[c] * wp[(size_t)c * 128];
        ((float*)(ws + OFF_VB))[ly * 128 + col] = s;
        return;
    }
    int rq = 8 * (lane >> 4), cq = lane & 15;
    const float* src; const float* src2 = nullptr; float sgn = 1.f;
    int NT, N, dstoff, lf;
    bool scale_g = false;
    if (f < 64)       { src = q_w;  NT = 8;  N = 128; dstoff = OFF_Q;  lf = f; }
    else if (f < 128) { src = k_w;  NT = 8;  N = 128; dstoff = OFF_K;  lf = f - 64;  scale_g = true; }
    else if (f < 192) { src = v_w;  NT = 8;  N = 128; dstoff = OFF_V;  lf = f - 128; scale_g = true; }
    else if (f < 256) { src = o_w;  NT = 8;  N = 128; dstoff = OFF_O;  lf = f - 192; }
    else if (f < 512) { src = f1w;  NT = 32; N = 512; dstoff = OFF_F1; lf = f - 256; }
    else if (f < 768) { src = f2w;  NT = 8;  N = 128; dstoff = OFF_F2; lf = f - 512; }
    else if (f < 864) { src = o1w;             src2 = o1w + 256 * 384; sgn =  1.f;
                        NT = 24; N = 384; dstoff = OFF_XC; lf = f - 768; }
    else              { src = o1w + 128 * 384; src2 = o1w + 256 * 384; sgn = -1.f;
                        NT = 24; N = 384; dstoff = OFF_CC; lf = f - 864; }
    int kt = lf / NT, nt = lf - kt * NT;
    int row0 = kt * 32 + rq, col = nt * 16 + cq;
    s8v o;
#pragma unroll
    for (int j = 0; j < 8; ++j) {
        float v = src[(size_t)(row0 + j) * N + col];
        if (src2) v += sgn * src2[(size_t)(row0 + j) * N + col];
        if (scale_g) v *= ctx_g[row0 + j];
        o[j] = (short)f2bf(v);
    }
    *(s8v*)(ws + dstoff + (size_t)lf * 512 + (size_t)lane * 8) = o;
}

// ---------------- main fused kernel: 4 waves x 16 pixels, shared weight stream ----------------
// R8 (on R7 structure — topology unchanged; R5/R6/R7 all ~49% issue at
// 334/341/314us proved TLP/barrier count are NOT the limiter; the per-wave
// instruction stream is): (1) all paired bf16 arena writes use
// v_cvt_pk_bf16_f32 (1 op/2 values vs 4 ops/value manual RNE, bit-identical);
// (2) head CC kt-loop unroll 2 -> frh loads of kt+1 overlap kt's MFMAs;
// (3) prologues merged into one kernel.
__global__ __launch_bounds__(256, 2) void fused_kernel(
    const u16*  __restrict__ nrmb, const float* __restrict__ fmu,
    const u16*  __restrict__ wsb,
    const float* __restrict__ qb, const float* __restrict__ ob,
    const float* __restrict__ f1b, const float* __restrict__ f2b,
    const float* __restrict__ o1b, const float* __restrict__ o2w,
    const float* __restrict__ o2b,
    float* __restrict__ out)
{
    const int tid  = threadIdx.x;
    const int wid  = tid >> 6;
    const int lane = tid & 63;
    const int cidx = lane & 15, quad = lane >> 4;
    const int n0 = blockIdx.x * 64 + wid * 16;
    const int b  = n0 / (HU_ * WU_);
    const int rem = n0 - b * (HU_ * WU_);
    const int hu  = rem / WU_;
    const int wu0 = rem - hu * WU_;

    __shared__ __align__(16) u16 wlds[2][4096];       // 16KB shared weight dbuf
    __shared__ __align__(16) u16 arena2[4][2 * SLOT]; // per-wave slots (8704B each)
    u16*   const arena = arena2[wid];
    // s_at aliases slot1 @ +1024 u16: head hx staging ends at +887; FFN acts
    // and s_at are never simultaneously live.
    float* const s_at  = (float*)(arena + SLOT + 1024);
    float* const s_rs  = s_at;

    const float* vbp = (const float*)(wsb + OFF_VB);

    float xacc[8][4];
#pragma unroll
    for (int nt = 0; nt < 8; ++nt) {
        int ch = 16 * nt + cidx;
        float4 v = *(const float4*)(fmu + ((size_t)(b * C_ + ch) * HU_ + hu) * WU_ + wu0 + 4 * quad);
        xacc[nt][0] = v.x; xacc[nt][1] = v.y; xacc[nt][2] = v.z; xacc[nt][3] = v.w;
    }

    const float slopes[4] = {0.451801007f, 0.204124145f, 0.092223264f, 0.041666668f};
    const int ry0 = min(hu >> 1, HD_ - 1);
    const int ry1 = min((hu >> 1) + 1, HD_ - 1);
    const float dyv0 = -(float)abs(hu - 2 * ry0);
    const float dyv1 = -(float)abs(hu - 2 * ry1);

    const int k2l = cidx & 3;
    const int ryl = (k2l >> 1) ? ry1 : ry0;
    int cbase[4];
#pragma unroll
    for (int mt = 0; mt < 4; ++mt) {
        int p = 4 * mt + (cidx >> 2);
        int rxv = min(((wu0 + p) >> 1) + (k2l & 1), WD_ - 1);
        cbase[mt] = ((b * HD_ + ryl) * WD_ + rxv) * 128;
    }

#pragma unroll 1
    for (int ly = 0; ly < 2; ++ly) {
        const u16* Wq = wsb + OFF_Q  + ly * 16384;
        const u16* Wk = wsb + OFF_K  + ly * 16384;
        const u16* Wv = wsb + OFF_V  + ly * 16384;
        const u16* Wo = wsb + OFF_O  + ly * 16384;
        const u16* W1 = wsb + OFF_F1 + ly * 65536;
        const u16* W2 = wsb + OFF_F2 + ly * 65536;

        s8v fr[4][2];

        // early-issue q groups 0,1 (own 2 chunks each; cover: LN)
#pragma unroll
        for (int jl = 0; jl < 2; ++jl) {
            int j = 2 * wid + jl;
            glds1(Wq + (size_t)j * 512, &wlds[0][j * 512], lane);
        }
#pragma unroll
        for (int jl = 0; jl < 2; ++jl) {
            int j = 2 * wid + jl;
            glds1(Wq + (size_t)(8 + j) * 512, &wlds[1][j * 512], lane);
        }

        // ---- xn = LN(x,1e-6) -> slot0 ----
        {
            float mo[4], io[4];
#pragma unroll
            for (int r = 0; r < 4; ++r) {
                float s = 0.f, ss = 0.f;
#pragma unroll
                for (int nt = 0; nt < 8; ++nt) { float v = xacc[nt][r]; s += v; ss += v * v; }
#pragma unroll
                for (int m = 1; m <= 8; m <<= 1) { s += __shfl_xor(s, m, 64); ss += __shfl_xor(ss, m, 64); }
                float mn = s * (1.f / 128.f);
                mo[r] = mn; io[r] = rsqrtf(ss * (1.f / 128.f) - mn * mn + 1e-6f);
            }
#pragma unroll
            for (int nt = 0; nt < 8; ++nt)
#pragma unroll
                for (int r = 0; r < 4; r += 2)
                    st2bf(arena + (4 * quad + r) * 136 + 16 * nt + cidx,
                          arena + (4 * quad + r + 1) * 136 + 16 * nt + cidx,
                          (xacc[nt][r] - mo[r]) * io[r],
                          (xacc[nt][r + 1] - mo[r + 1]) * io[r + 1]);
        }
        WFENCE();
        s8v a_xn[4];
#pragma unroll
        for (int kt = 0; kt < 4; ++kt)
            a_xn[kt] = *(const s8v*)(arena + cidx * 136 + kt * 32 + 8 * quad);

        // ---- q GEMM (streamed; group g = kt) ----
        {
            f4v qa[8];
#pragma unroll
            for (int nt = 0; nt < 8; ++nt) {
                float bvv = qb[ly * C_ + 16 * nt + cidx];
                f4v t = {bvv, bvv, bvv, bvv}; qa[nt] = t;
            }
#pragma unroll
            for (int g = 0; g < 4; ++g) {
                if (g < 3) { GW2(); } else { GW0(); }
#pragma unroll
                for (int nt = 0; nt < 8; ++nt) {
                    s8v w = *(const s8v*)&wlds[g & 1][nt * 512 + lane * 8];
                    qa[nt] = __builtin_amdgcn_mfma_f32_16x16x32_bf16(a_xn[g], w, qa[nt], 0, 0, 0);
                }
                BAR();
                if (g < 2) {
#pragma unroll
                    for (int jl = 0; jl < 2; ++jl) {
                        int j = 2 * wid + jl;
                        glds1(Wq + (size_t)((g + 2) * 8 + j) * 512, &wlds[g & 1][j * 512], lane);
                    }
                }
            }
#pragma unroll
            for (int kt = 0; kt < 4; ++kt)
#pragma unroll
                for (int i = 0; i < 2; ++i)
                    fr[kt][i] = *(const s8v*)(nrmb + cbase[i] + kt * 32 + 8 * quad);
#pragma unroll
            for (int jl = 0; jl < 2; ++jl) {
                int j = 2 * wid + jl;
                glds1(Wk + (size_t)(((j & 3) * 8) + (j >> 2)) * 512, &wlds[0][j * 512], lane);
            }
#pragma unroll
            for (int jl = 0; jl < 2; ++jl) {
                int j = 2 * wid + jl;
                int jc = 8 + j;
                glds1(Wk + (size_t)(((jc & 3) * 8) + (jc >> 2)) * 512, &wlds[1][j * 512], lane);
            }
#pragma unroll
            for (int nt = 0; nt < 8; ++nt)
#pragma unroll
                for (int r = 0; r < 4; r += 2)
                    st2bf(arena + (4 * quad + r) * 136 + 16 * nt + cidx,
                          arena + (4 * quad + r + 1) * 136 + 16 * nt + cidx,
                          qa[nt][r], qa[nt][r + 1]);
        }
        WFENCE();

        // ---- k GEMM + fused raw scores (streamed; mh=g>>2, h=g&3) ----
#pragma unroll
        for (int g = 0; g < 8; ++g) {
            if (g < 7) { GW2(); } else { GW0(); }
            const int mh = g >> 2, h = g & 3;
            float part[2][4];
#pragma unroll
            for (int i = 0; i < 2; ++i)
#pragma unroll
                for (int r = 0; r < 4; ++r) part[i][r] = 0.f;
#pragma unroll
            for (int ntp = 0; ntp < 2; ++ntp) {
                const int nt = 2 * h + ntp;
                f4v ka[2];
#pragma unroll
                for (int i = 0; i < 2; ++i) { f4v t = {0.f, 0.f, 0.f, 0.f}; ka[i] = t; }
#pragma unroll
                for (int kt = 0; kt < 4; ++kt) {
                    s8v w = *(const s8v*)&wlds[g & 1][(ntp * 4 + kt) * 512 + lane * 8];
                    ka[0] = __builtin_amdgcn_mfma_f32_16x16x32_bf16(fr[kt][0], w, ka[0], 0, 0, 0);
                    ka[1] = __builtin_amdgcn_mfma_f32_16x16x32_bf16(fr[kt][1], w, ka[1], 0, 0, 0);
                }
#pragma unroll
                for (int i = 0; i < 2; ++i) {
                    float qv = bfu(arena[(4 * (2 * mh + i) + quad) * 136 + 16 * nt + cidx]);
#pragma unroll
                    for (int r = 0; r < 4; ++r) part[i][r] = fmaf(qv, ka[i][r], part[i][r]);
                }
            }
#pragma unroll
            for (int i = 0; i < 2; ++i)
#pragma unroll
                for (int r = 0; r < 4; ++r) {
#pragma unroll
                    for (int m = 1; m <= 8; m <<= 1) part[i][r] += __shfl_xor(part[i][r], m, 64);
                }
            if (cidx == 0) {
#pragma unroll
                for (int i = 0; i < 2; ++i) {
                    float4 t = {part[i][0], part[i][1], part[i][2], part[i][3]};
                    *(float4*)&s_at[(4 * (2 * mh + i) + quad) * 16 + 4 * h] = t;
                }
            }
            BAR();
            if (g == 2) {   // mh=1 fragments: issued early so g==3's vmcnt(2) drains them
#pragma unroll
                for (int kt = 0; kt < 4; ++kt)
#pragma unroll
                    for (int i = 0; i < 2; ++i)
                        fr[kt][i] = *(const s8v*)(nrmb + cbase[2 + i] + kt * 32 + 8 * quad);
            }
            if (g < 6) {
                const int gn = g + 2;
#pragma unroll
                for (int jl = 0; jl < 2; ++jl) {
                    int j = 2 * wid + jl;
                    int jc = 8 * (gn & 3) + j;
                    glds1(Wk + (size_t)(((jc & 3) * 8) + (jc >> 2)) * 512, &wlds[g & 1][j * 512], lane);
                }
            }
        }
#pragma unroll
        for (int kt = 0; kt < 4; ++kt)
#pragma unroll
            for (int i = 0; i < 2; ++i)
                fr[kt][i] = *(const s8v*)(nrmb + cbase[i] + kt * 32 + 8 * quad);
#pragma unroll
        for (int jl = 0; jl < 2; ++jl) {
            int j = 2 * wid + jl;
            glds1(Wv + (size_t)(((j & 3) * 8) + (j >> 2)) * 512, &wlds[0][j * 512], lane);
        }
#pragma unroll
        for (int jl = 0; jl < 2; ++jl) {
            int j = 2 * wid + jl;
            glds1(Wv + (size_t)(((j & 3) * 8) + 2 + (j >> 2)) * 512, &wlds[1][j * 512], lane);
        }
        WFENCE();

        // ---- softmax in place (wave-private s_at) ----
        {
            int p = lane >> 2, h = lane & 3;
            float4 sc = *(float4*)&s_at[p * 16 + 4 * h];
            int pw = wu0 + p;
            float sim[4] = {sc.x, sc.y, sc.z, sc.w};
#pragma unroll
            for (int r = 0; r < 4; ++r) {
                int rxv = min((pw >> 1) + (r & 1), WD_ - 1);
                float cd = ((r >> 1) ? dyv1 : dyv0) - (float)abs(pw - 2 * rxv);
                sim[r] = sim[r] * 0.17677669529663687f + slopes[h] * cd;
            }
            float mx = fmaxf(fmaxf(sim[0], sim[1]), fmaxf(sim[2], sim[3]));
            float e0 = __expf(sim[0] - mx), e1 = __expf(sim[1] - mx);
            float e2 = __expf(sim[2] - mx), e3 = __expf(sim[3] - mx);
            float si = 1.f / (e0 + e1 + e2 + e3);
            float4 at = {e0 * si, e1 * si, e2 * si, e3 * si};
            *(float4*)&s_at[p * 16 + 4 * h] = at;
        }
        WFENCE();

        // ---- v GEMM + fused o = attn@v -> oT slot0 (streamed, paired writes) ----
#pragma unroll
        for (int g = 0; g < 8; ++g) {
            if (g < 7) { GW2(); } else { GW0(); }
            const int mh = g >> 2, gp = g & 3;
            float4 at0 = *(float4*)&s_at[(4 * (2 * mh + 0) + quad) * 16 + 4 * gp];
            float4 at1 = *(float4*)&s_at[(4 * (2 * mh + 1) + quad) * 16 + 4 * gp];
            float ov[2][2];
#pragma unroll
            for (int ntp = 0; ntp < 2; ++ntp) {
                const int nt = 2 * gp + ntp;
                float vbb = vbp[ly * C_ + 16 * nt + cidx];
                f4v va[2];
#pragma unroll
                for (int i = 0; i < 2; ++i) { f4v t = {vbb, vbb, vbb, vbb}; va[i] = t; }
#pragma unroll
                for (int kt = 0; kt < 4; ++kt) {
                    s8v w = *(const s8v*)&wlds[g & 1][(ntp * 4 + kt) * 512 + lane * 8];
                    va[0] = __builtin_amdgcn_mfma_f32_16x16x32_bf16(fr[kt][0], w, va[0], 0, 0, 0);
                    va[1] = __builtin_amdgcn_mfma_f32_16x16x32_bf16(fr[kt][1], w, va[1], 0, 0, 0);
                }
                ov[ntp][0] = at0.x * va[0][0] + at0.y * va[0][1] + at0.z * va[0][2] + at0.w * va[0][3];
                ov[ntp][1] = at1.x * va[1][0] + at1.y * va[1][1] + at1.z * va[1][2] + at1.w * va[1][3];
            }
#pragma unroll
            for (int i = 0; i < 2; ++i) {
                const int mt = 2 * mh + i;
                st2bf(arena + (4 * mt + quad) * 136 + 16 * (2 * gp) + cidx,
                      arena + (4 * mt + quad) * 136 + 16 * (2 * gp + 1) + cidx,
                      ov[0][i], ov[1][i]);
            }
            BAR();
            if (g == 2) {   // mh=1 fragments, early
#pragma unroll
                for (int kt = 0; kt < 4; ++kt)
#pragma unroll
                    for (int i = 0; i < 2; ++i)
                        fr[kt][i] = *(const s8v*)(nrmb + cbase[2 + i] + kt * 32 + 8 * quad);
            }
            if (g < 6) {
                const int gq = (g + 2) & 3;
#pragma unroll
                for (int jl = 0; jl < 2; ++jl) {
                    int j = 2 * wid + jl;
                    glds1(Wv + (size_t)(((j & 3) * 8) + 2 * gq + (j >> 2)) * 512, &wlds[g & 1][j * 512], lane);
                }
            }
        }
#pragma unroll
        for (int jl = 0; jl < 2; ++jl) {
            int j = 2 * wid + jl;
            glds1(Wo + (size_t)j * 512, &wlds[0][j * 512], lane);
        }
#pragma unroll
        for (int jl = 0; jl < 2; ++jl) {
            int j = 2 * wid + jl;
            glds1(Wo + (size_t)(8 + j) * 512, &wlds[1][j * 512], lane);
        }
        WFENCE();

        // ---- x += o @ Wo + ob (streamed) ----
        {
            s8v a_o[4];
#pragma unroll
            for (int kt = 0; kt < 4; ++kt)
                a_o[kt] = *(const s8v*)(arena + cidx * 136 + kt * 32 + 8 * quad);
            f4v oa[8];
#pragma unroll
            for (int nt = 0; nt < 8; ++nt) {
                float bvv = ob[ly * C_ + 16 * nt + cidx];
                f4v t = {bvv, bvv, bvv, bvv}; oa[nt] = t;
            }
#pragma unroll
            for (int g = 0; g < 4; ++g) {
                if (g < 3) { GW2(); } else { GW0(); }
#pragma unroll
                for (int nt = 0; nt < 8; ++nt) {
                    s8v w = *(const s8v*)&wlds[g & 1][nt * 512 + lane * 8];
                    oa[nt] = __builtin_amdgcn_mfma_f32_16x16x32_bf16(a_o[g], w, oa[nt], 0, 0, 0);
                }
                BAR();
                if (g < 2) {
#pragma unroll
                    for (int jl = 0; jl < 2; ++jl) {
                        int j = 2 * wid + jl;
                        glds1(Wo + (size_t)((g + 2) * 8 + j) * 512, &wlds[g & 1][j * 512], lane);
                    }
                }
            }
#pragma unroll
            for (int jl = 0; jl < 2; ++jl) {
                int j = 2 * wid + jl;
                glds1(W1 + (size_t)j * 512, &wlds[0][j * 512], lane);
            }
#pragma unroll
            for (int jl = 0; jl < 2; ++jl) {
                int j = 2 * wid + jl;
                glds1(W1 + (size_t)(32 + j) * 512, &wlds[1][j * 512], lane);
            }
#pragma unroll
            for (int nt = 0; nt < 8; ++nt)
#pragma unroll
                for (int r = 0; r < 4; ++r) xacc[nt][r] += oa[nt][r];
        }

        // ---- hn = LN(x,1e-6) -> slot0 ----
        {
            float mo[4], io[4];
#pragma unroll
            for (int r = 0; r < 4; ++r) {
                float s = 0.f, ss = 0.f;
#pragma unroll
                for (int nt = 0; nt < 8; ++nt) { float v = xacc[nt][r]; s += v; ss += v * v; }
#pragma unroll
                for (int m = 1; m <= 8; m <<= 1) { s += __shfl_xor(s, m, 64); ss += __shfl_xor(ss, m, 64); }
                float mn = s * (1.f / 128.f);
                mo[r] = mn; io[r] = rsqrtf(ss * (1.f / 128.f) - mn * mn + 1e-6f);
            }
#pragma unroll
            for (int nt = 0; nt < 8; ++nt)
#pragma unroll
                for (int r = 0; r < 4; r += 2)
                    st2bf(arena + (4 * quad + r) * 136 + 16 * nt + cidx,
                          arena + (4 * quad + r + 1) * 136 + 16 * nt + cidx,
                          (xacc[nt][r] - mo[r]) * io[r],
                          (xacc[nt][r + 1] - mo[r + 1]) * io[r + 1]);
        }
        WFENCE();
        s8v a_hn[4];
#pragma unroll
        for (int kt = 0; kt < 4; ++kt)
            a_hn[kt] = *(const s8v*)(arena + cidx * 136 + kt * 32 + 8 * quad);

        // ---- ffn: 4 chunks of 128 cols, both GEMMs streamed ----
        {
            f4v ga[8];
#pragma unroll
            for (int nt = 0; nt < 8; ++nt) {
                float bvv = f2b[ly * C_ + 16 * nt + cidx];
                f4v t = {bvv, bvv, bvv, bvv}; ga[nt] = t;
            }
#pragma unroll 1
            for (int c = 0; c < 4; ++c) {
                f4v fa[8];
#pragma unroll
                for (int nt = 0; nt < 8; ++nt) {
                    float bvv = f1b[ly * 512 + 128 * c + 16 * nt + cidx];
                    f4v t = {bvv, bvv, bvv, bvv}; fa[nt] = t;
                }
#pragma unroll
                for (int g = 0; g < 4; ++g) {
                    if (g < 3) { GW2(); } else { GW0(); }
#pragma unroll
                    for (int nt = 0; nt < 8; ++nt) {
                        s8v w = *(const s8v*)&wlds[g & 1][nt * 512 + lane * 8];
                        fa[nt] = __builtin_amdgcn_mfma_f32_16x16x32_bf16(a_hn[g], w, fa[nt], 0, 0, 0);
                    }
                    BAR();
                    if (g < 2) {
#pragma unroll
                        for (int jl = 0; jl < 2; ++jl) {
                            int j = 2 * wid + jl;
                            glds1(W1 + (size_t)((g + 2) * 32 + 8 * c + j) * 512, &wlds[g & 1][j * 512], lane);
                        }
                    }
                }
#pragma unroll
                for (int jl = 0; jl < 2; ++jl) {
                    int j = 2 * wid + jl;
                    glds1(W2 + (size_t)(32 * c + j) * 512, &wlds[0][j * 512], lane);
                }
#pragma unroll
                for (int jl = 0; jl < 2; ++jl) {
                    int j = 2 * wid + jl;
                    glds1(W2 + (size_t)(32 * c + 8 + j) * 512, &wlds[1][j * 512], lane);
                }
#pragma unroll
                for (int nt = 0; nt < 8; ++nt)
#pragma unroll
                    for (int r = 0; r < 4; r += 2)
                        st2bf(arena + SLOT + (4 * quad + r) * 136 + 16 * nt + cidx,
                              arena + SLOT + (4 * quad + r + 1) * 136 + 16 * nt + cidx,
                              gelu_tanh(fa[nt][r]), gelu_tanh(fa[nt][r + 1]));
                WFENCE();
#pragma unroll
                for (int g = 0; g < 4; ++g) {
                    if (g < 3) { GW2(); } else { GW0(); }
                    s8v a = *(const s8v*)(arena + SLOT + cidx * 136 + g * 32 + 8 * quad);
#pragma unroll
                    for (int nt = 0; nt < 8; ++nt) {
                        s8v w = *(const s8v*)&wlds[g & 1][nt * 512 + lane * 8];
                        ga[nt] = __builtin_amdgcn_mfma_f32_16x16x32_bf16(a, w, ga[nt], 0, 0, 0);
                    }
                    BAR();
                    if (g < 2) {
#pragma unroll
                        for (int jl = 0; jl < 2; ++jl) {
                            int j = 2 * wid + jl;
                            glds1(W2 + (size_t)(32 * c + (g + 2) * 8 + j) * 512, &wlds[g & 1][j * 512], lane);
                        }
                    }
                }
                if (c < 3) {
#pragma unroll
                    for (int jl = 0; jl < 2; ++jl) {
                        int j = 2 * wid + jl;
                        glds1(W1 + (size_t)(8 * (c + 1) + j) * 512, &wlds[0][j * 512], lane);
                    }
#pragma unroll
                    for (int jl = 0; jl < 2; ++jl) {
                        int j = 2 * wid + jl;
                        glds1(W1 + (size_t)(32 + 8 * (c + 1) + j) * 512, &wlds[1][j * 512], lane);
                    }
                }
            }
#pragma unroll
            for (int nt = 0; nt < 8; ++nt)
#pragma unroll
                for (int r = 0; r < 4; ++r) xacc[nt][r] += ga[nt][r];
        }
    } // layer loop

    // ================= head =================
    // XC staging: wave w owns 3 chunks (j = 3w..3w+2); waves 0,1 -> buf0
    // (kt 0,1), waves 2,3 -> buf1 (kt 2,3). Divergent-but-wave-uniform waits.
    const u16* Wxc = wsb + OFF_XC;
    const u16* Wcc = wsb + OFF_CC;
#pragma unroll
    for (int jl = 0; jl < 3; ++jl) {
        int j = 3 * wid + jl;
        glds1(Wxc + (size_t)((j / 3) * 24 + (j % 3)) * 512, &wlds[j / 6][(j % 6) * 512], lane);
    }
    {
        float mo[4], io[4];
#pragma unroll
        for (int r = 0; r < 4; ++r) {
            float s = 0.f, ss = 0.f;
#pragma unroll
            for (int nt = 0; nt < 8; ++nt) { float v = xacc[nt][r]; s += v; ss += v * v; }
#pragma unroll
            for (int m = 1; m <= 8; m <<= 1) { s += __shfl_xor(s, m, 64); ss += __shfl_xor(ss, m, 64); }
            float mn = s * (1.f / 128.f);
            mo[r] = mn; io[r] = rsqrtf(ss * (1.f / 128.f) - mn * mn + 1e-6f);
        }
#pragma unroll
        for (int nt = 0; nt < 8; ++nt)
#pragma unroll
            for (int r = 0; r < 4; r += 2)
                st2bf(arena + (4 * quad + r) * 136 + 16 * nt + cidx,
                      arena + (4 * quad + r + 1) * 136 + 16 * nt + cidx,
                      (xacc[nt][r] - mo[r]) * io[r],
                      (xacc[nt][r + 1] - mo[r + 1]) * io[r + 1]);
    }
    WFENCE();
    s8v a_xf[4];
#pragma unroll
    for (int kt = 0; kt < 4; ++kt)
        a_xf[kt] = *(const s8v*)(arena + cidx * 136 + kt * 32 + 8 * quad);

    float part[4][4];
#pragma unroll
    for (int mt = 0; mt < 4; ++mt)
#pragma unroll
        for (int r = 0; r < 4; ++r) part[mt][r] = 0.f;

#pragma unroll 1
    for (int it = 0; it < 8; ++it) {
        const int nbase = 6 * (it >> 1) + 3 * (it & 1);
        {
            f4v hx[3];
#pragma unroll
            for (int ntl = 0; ntl < 3; ++ntl) {
                float hb = o1b[16 * (nbase + ntl) + cidx];
                f4v t = {hb, hb, hb, hb}; hx[ntl] = t;
            }
            // half0 (buf0, kt 0-1): owners are waves 0,1
            if (wid < 2) { asm volatile("s_waitcnt vmcnt(0)" ::: "memory"); }
            BAR();
#pragma unroll
            for (int kt = 0; kt < 2; ++kt)
#pragma unroll
                for (int ntl = 0; ntl < 3; ++ntl) {
                    s8v w = *(const s8v*)&wlds[0][(kt * 3 + ntl) * 512 + lane * 8];
                    hx[ntl] = __builtin_amdgcn_mfma_f32_16x16x32_bf16(a_xf[kt], w, hx[ntl], 0, 0, 0);
                }
            // half1 (buf1, kt 2-3): owners are waves 2,3
            if (wid >= 2) { asm volatile("s_waitcnt vmcnt(0)" ::: "memory"); }
            BAR();
#pragma unroll
            for (int kt = 2; kt < 4; ++kt)
#pragma unroll
                for (int ntl = 0; ntl < 3; ++ntl) {
                    s8v w = *(const s8v*)&wlds[1][((kt - 2) * 3 + ntl) * 512 + lane * 8];
                    hx[ntl] = __builtin_amdgcn_mfma_f32_16x16x32_bf16(a_xf[kt], w, hx[ntl], 0, 0, 0);
                }
            BAR();
            if (it < 7) {
                const int nb2 = 6 * ((it + 1) >> 1) + 3 * ((it + 1) & 1);
#pragma unroll
                for (int jl = 0; jl < 3; ++jl) {
                    int j = 3 * wid + jl;
                    glds1(Wxc + (size_t)((j / 3) * 24 + nb2 + (j % 3)) * 512, &wlds[j / 6][(j % 6) * 512], lane);
                }
            }
#pragma unroll
            for (int ntl = 0; ntl < 3; ++ntl)
#pragma unroll
                for (int r = 0; r < 4; r += 2)
                    st2bf(arena + SLOT + (4 * quad + r) * 56 + 16 * ntl + cidx,
                          arena + SLOT + (4 * quad + r + 1) * 56 + 16 * ntl + cidx,
                          hx[ntl][r], hx[ntl][r + 1]);
        }
        WFENCE();

        f4v hc[3][4];
#pragma unroll
        for (int ntl = 0; ntl < 3; ++ntl)
#pragma unroll
            for (int mt = 0; mt < 4; ++mt) { f4v t = {0.f, 0.f, 0.f, 0.f}; hc[ntl][mt] = t; }
#pragma unroll 2
        for (int kt = 0; kt < 4; ++kt) {
            s8v frh[4];
#pragma unroll
            for (int mt = 0; mt < 4; ++mt)
                frh[mt] = *(const s8v*)(nrmb + cbase[mt] + kt * 32 + 8 * quad);
#pragma unroll
            for (int ntl = 0; ntl < 3; ++ntl) {
                s8v w = *(const s8v*)(Wcc + ((size_t)((kt * 24 + nbase + ntl) * 64 + lane)) * 8);
#pragma unroll
                for (int mt = 0; mt < 4; ++mt)
                    hc[ntl][mt] = __builtin_amdgcn_mfma_f32_16x16x32_bf16(frh[mt], w, hc[ntl][mt], 0, 0, 0);
            }
        }

#pragma unroll
        for (int ntl = 0; ntl < 3; ++ntl) {
            float w2v = o2w[16 * (nbase + ntl) + cidx];
#pragma unroll
            for (int mt = 0; mt < 4; ++mt)
#pragma unroll
                for (int r = 0; r < 4; ++r) {
                    float h1 = hc[ntl][mt][r] +
                               bfu(arena[SLOT + (4 * mt + quad) * 56 + 16 * ntl + cidx]);
                    part[mt][r] = fmaf(gelu_erf(h1), w2v, part[mt][r]);
                }
        }
        WFENCE();
    }

#pragma unroll
    for (int mt = 0; mt < 4; ++mt)
#pragma unroll
        for (int r = 0; r < 4; ++r) {
#pragma unroll
            for (int m = 1; m <= 8; m <<= 1) part[mt][r] += __shfl_xor(part[mt][r], m, 64);
            part[mt][r] += o2b[0];
        }
    if (cidx == 0) {
#pragma unroll
        for (int mt = 0; mt < 4; ++mt) {
            float4 t = {part[mt][0], part[mt][1], part[mt][2], part[mt][3]};
            *(float4*)&s_rs[(4 * mt + quad) * 4] = t;
        }
    }
    WFENCE();

    if (lane < 16) {
        int p = lane;
        float4 vv = *(float4*)&s_rs[4 * p];
        float mx = fmaxf(fmaxf(vv.x, vv.y), fmaxf(vv.z, vv.w));
        float e0 = __expf(vv.x - mx), e1 = __expf(vv.y - mx);
        float e2 = __expf(vv.z - mx), e3 = __expf(vv.w - mx);
        float si = 1.f / (e0 + e1 + e2 + e3);
        size_t base = ((size_t)(b * 4) * HU_ + hu) * WU_ + wu0 + p;
        out[base]                          = e0 * si;
        out[base + (size_t)HU_ * WU_]      = e1 * si;
        out[base + (size_t)2 * HU_ * WU_]  = e2 * si;
        out[base + (size_t)3 * HU_ * WU_]  = e3 * si;
    }
}

extern "C" void kernel_launch(void* const* d_in, const int* in_sizes, int n_in,
                              void* d_out, int out_size, void* d_ws, size_t ws_size,
                              hipStream_t stream) {
    const float* feat_map    = (const float*)d_in[0];
    const float* feat_map_up = (const float*)d_in[1];
    const float* ctx_ln_b    = (const float*)d_in[2];
    const float* q_w  = (const float*)d_in[3];
    const float* q_b  = (const float*)d_in[4];
    const float* k_w  = (const float*)d_in[5];
    const float* v_w  = (const float*)d_in[7];
    const float* v_b  = (const float*)d_in[8];
    const float* o_w  = (const float*)d_in[9];
    const float* o_b  = (const float*)d_in[10];
    const float* fc1_w = (const float*)d_in[11];
    const float* fc1_b = (const float*)d_in[12];
    const float* fc2_w = (const float*)d_in[13];
    const float* fc2_b = (const float*)d_in[14];
    const float* out1_w = (const float*)d_in[15];
    const float* out1_b = (const float*)d_in[16];
    const float* out2_w = (const float*)d_in[17];
    const float* out2_b = (const float*)d_in[18];
    const float* ctx_ln_g = (const float*)d_in[19];
    float* out = (float*)d_out;
    u16* ws = (u16*)d_ws;

    prologue_all<<<370, 256, 0, stream>>>(q_w, k_w, v_w, o_w, fc1_w, fc2_w, out1_w,
                                          ctx_ln_g, ctx_ln_b, v_b, feat_map, ws);

    fused_kernel<<<768, 256, 0, stream>>>(
        ws + OFF_NRM, feat_map_up, ws,
        q_b, o_b, fc1_b, fc2_b,
        out1_b, out2_w, out2_b, out);
}